// Round 1
// baseline (4969.363 us; speedup 1.0000x reference)
//
#include <hip/hip_runtime.h>
#include <hip/hip_bf16.h>

#define N_NODES 20000
#define KADJ 4
#define NEDGE 320000
#define IN_DIM_ 1024
#define H_IN_ 256
#define DDIM 128
#define GATE_H_ 128
#define TEMP_ 0.6f
#define M_CLAMP_ 20.0f

// ---------------- fp32 tiled GEMM: C = [relu](A[M,K] @ B[K,N] + bias) ----------------
// 64x64 tile, 256 threads, 4x4 per thread, BK=16. N must be multiple of 64, K of 16.
__global__ __launch_bounds__(256) void gemm_kernel(
    const float* __restrict__ A, const float* __restrict__ B,
    const float* __restrict__ bias, float* __restrict__ C,
    int M, int N, int K, int do_relu)
{
    __shared__ float sA[16][68];
    __shared__ float sB[16][64];
    int tid = threadIdx.x;
    int tx = tid & 15, ty = tid >> 4;
    int tileM = blockIdx.y * 64;
    int tileN = blockIdx.x * 64;
    int ar = tid >> 2;          // 0..63 row in tile
    int ac = (tid & 3) << 2;    // 0,4,8,12 k in tile
    int br = tid >> 4;          // 0..15 k in tile
    int bc = (tid & 15) << 2;   // 0..60 col in tile

    float acc[4][4];
#pragma unroll
    for (int i = 0; i < 4; i++)
#pragma unroll
        for (int j = 0; j < 4; j++) acc[i][j] = 0.f;

    for (int k0 = 0; k0 < K; k0 += 16) {
        float4 av = make_float4(0.f, 0.f, 0.f, 0.f);
        int gr = tileM + ar;
        if (gr < M) av = *reinterpret_cast<const float4*>(A + (size_t)gr * K + k0 + ac);
        sA[ac + 0][ar] = av.x; sA[ac + 1][ar] = av.y;
        sA[ac + 2][ar] = av.z; sA[ac + 3][ar] = av.w;
        float4 bv = *reinterpret_cast<const float4*>(B + (size_t)(k0 + br) * N + tileN + bc);
        *reinterpret_cast<float4*>(&sB[br][bc]) = bv;
        __syncthreads();
#pragma unroll
        for (int kk = 0; kk < 16; ++kk) {
            float a0 = sA[kk][ty * 4 + 0], a1 = sA[kk][ty * 4 + 1];
            float a2 = sA[kk][ty * 4 + 2], a3 = sA[kk][ty * 4 + 3];
            float b0 = sB[kk][tx * 4 + 0], b1 = sB[kk][tx * 4 + 1];
            float b2 = sB[kk][tx * 4 + 2], b3 = sB[kk][tx * 4 + 3];
            acc[0][0] += a0 * b0; acc[0][1] += a0 * b1; acc[0][2] += a0 * b2; acc[0][3] += a0 * b3;
            acc[1][0] += a1 * b0; acc[1][1] += a1 * b1; acc[1][2] += a1 * b2; acc[1][3] += a1 * b3;
            acc[2][0] += a2 * b0; acc[2][1] += a2 * b1; acc[2][2] += a2 * b2; acc[2][3] += a2 * b3;
            acc[3][0] += a3 * b0; acc[3][1] += a3 * b1; acc[3][2] += a3 * b2; acc[3][3] += a3 * b3;
        }
        __syncthreads();
    }
#pragma unroll
    for (int i = 0; i < 4; i++) {
        int row = tileM + ty * 4 + i;
        if (row >= M) continue;
        int col = tileN + tx * 4;
        float4 v;
        v.x = acc[i][0]; v.y = acc[i][1]; v.z = acc[i][2]; v.w = acc[i][3];
        if (bias) {
            v.x += bias[col]; v.y += bias[col + 1];
            v.z += bias[col + 2]; v.w += bias[col + 3];
        }
        if (do_relu) {
            v.x = fmaxf(v.x, 0.f); v.y = fmaxf(v.y, 0.f);
            v.z = fmaxf(v.z, 0.f); v.w = fmaxf(v.w, 0.f);
        }
        *reinterpret_cast<float4*>(C + (size_t)row * N + col) = v;
    }
}

// ---------------- edge scatter: M[r,k,:] += Z[c,:] (binary adjacency segment-sum) ----------------
// 32 threads per edge, float4 gather of Z, scalar fp32 atomics into M.
__global__ __launch_bounds__(256) void scatter_kernel(
    float* __restrict__ Mbuf, const float* __restrict__ Z,
    const int* __restrict__ rows, const int* __restrict__ cols)
{
    long long gid = (long long)blockIdx.x * 256 + threadIdx.x;
    int edge = (int)(gid >> 5);
    int lane = (int)(gid & 31);
    if (edge >= KADJ * NEDGE) return;
    int k = edge / NEDGE;
    int e = edge - k * NEDGE;
    int r = rows[(size_t)k * NEDGE + e];
    int c = cols[(size_t)k * NEDGE + e];
    float4 zv = *reinterpret_cast<const float4*>(Z + (size_t)c * DDIM + lane * 4);
    float* dst = Mbuf + ((size_t)r * KADJ + k) * DDIM + lane * 4;
    atomicAdd(dst + 0, zv.x);
    atomicAdd(dst + 1, zv.y);
    atomicAdd(dst + 2, zv.z);
    atomicAdd(dst + 3, zv.w);
}

// ---------------- gate: scores[n,k] = relu(GH[n] + clip(M[n,k])@Wg1m + logdeg*wld) . Wg2 + bg2 ----
__global__ __launch_bounds__(128) void gate_kernel(
    const float* __restrict__ Mbuf, const float* __restrict__ GH,
    const float* __restrict__ logdeg, const float* __restrict__ Wg1m,
    const float* __restrict__ wld, const float* __restrict__ Wg2,
    const float* __restrict__ bg2, float* __restrict__ scores)
{
    int n = blockIdx.x;
    int j = threadIdx.x;  // gate hidden unit
    __shared__ float sM[KADJ][DDIM];
#pragma unroll
    for (int k = 0; k < KADJ; k++) {
        float m = Mbuf[((size_t)n * KADJ + k) * DDIM + j];
        sM[k][j] = fminf(fmaxf(m, -M_CLAMP_), M_CLAMP_);
    }
    __syncthreads();
    float ghj = GH[(size_t)n * DDIM + j];   // already includes bg1
    float wldj = wld[j];
    float acc0 = ghj + logdeg[n * KADJ + 0] * wldj;
    float acc1 = ghj + logdeg[n * KADJ + 1] * wldj;
    float acc2 = ghj + logdeg[n * KADJ + 2] * wldj;
    float acc3 = ghj + logdeg[n * KADJ + 3] * wldj;
    for (int i = 0; i < DDIM; i++) {
        float w = Wg1m[i * GATE_H_ + j];
        acc0 += sM[0][i] * w;
        acc1 += sM[1][i] * w;
        acc2 += sM[2][i] * w;
        acc3 += sM[3][i] * w;
    }
    float g = Wg2[j];
    __shared__ float rbuf[KADJ][DDIM];
    rbuf[0][j] = fmaxf(acc0, 0.f) * g;
    rbuf[1][j] = fmaxf(acc1, 0.f) * g;
    rbuf[2][j] = fmaxf(acc2, 0.f) * g;
    rbuf[3][j] = fmaxf(acc3, 0.f) * g;
    __syncthreads();
    for (int s = 64; s > 0; s >>= 1) {
        if (j < s) {
#pragma unroll
            for (int k = 0; k < KADJ; k++) rbuf[k][j] += rbuf[k][j + s];
        }
        __syncthreads();
    }
    if (j < KADJ) scores[(size_t)n * KADJ + j] = rbuf[j][0] + bg2[0];
}

// ---------------- alpha: softmax(scores/T) * mask, renorm, clamp 1e-8, renorm ----------------
__global__ __launch_bounds__(256) void alpha_kernel(
    const float* __restrict__ scores, const float* __restrict__ mask,
    float* __restrict__ alpha, int N)
{
    int n = blockIdx.x * 256 + threadIdx.x;
    if (n >= N) return;
    float s[KADJ], a[KADJ];
    float mx = -1e30f;
#pragma unroll
    for (int k = 0; k < KADJ; k++) {
        s[k] = scores[(size_t)n * KADJ + k] * (1.0f / TEMP_);
        mx = fmaxf(mx, s[k]);
    }
    float sum = 0.f;
#pragma unroll
    for (int k = 0; k < KADJ; k++) { a[k] = expf(s[k] - mx); sum += a[k]; }
#pragma unroll
    for (int k = 0; k < KADJ; k++) a[k] = (a[k] / sum) * mask[(size_t)n * KADJ + k];
    float s2 = 0.f;
#pragma unroll
    for (int k = 0; k < KADJ; k++) s2 += a[k];
    float inv = 1.f / fmaxf(s2, 1e-12f);
#pragma unroll
    for (int k = 0; k < KADJ; k++) a[k] = fmaxf(a[k] * inv, 1e-8f);
    s2 = 0.f;
#pragma unroll
    for (int k = 0; k < KADJ; k++) s2 += a[k];
    inv = 1.f / fmaxf(s2, 1e-12f);
#pragma unroll
    for (int k = 0; k < KADJ; k++) alpha[(size_t)n * KADJ + k] = a[k] * inv;
}

// ---------------- fused: Y[n,:] = H[n,:] + sum_k alpha[n,k]*clip(M[n,k,:]) ----------------
__global__ __launch_bounds__(256) void fuse_kernel(
    const float* __restrict__ Mbuf, const float* __restrict__ alpha,
    const float* __restrict__ H, float* __restrict__ Y, int N)
{
    int idx = blockIdx.x * 256 + threadIdx.x;
    int n = idx >> 7, d = idx & 127;
    if (n >= N) return;
    float y = H[idx];
#pragma unroll
    for (int k = 0; k < KADJ; k++) {
        float m = Mbuf[((size_t)n * KADJ + k) * DDIM + d];
        m = fminf(fmaxf(m, -M_CLAMP_), M_CLAMP_);
        y += alpha[(size_t)n * KADJ + k] * m;
    }
    Y[idx] = y;
}

// ---------------- pairnorm reduction: red[0..127]=colsum, red[128]=sum of squares ----------------
__global__ __launch_bounds__(256) void reduce_kernel(
    const float* __restrict__ Y, float* __restrict__ red, int N)
{
    int tid = threadIdx.x;
    int d = tid & 127;
    int half = tid >> 7;
    float cs = 0.f, sq = 0.f;
    for (int n = blockIdx.x * 2 + half; n < N; n += gridDim.x * 2) {
        float v = Y[(size_t)n * DDIM + d];
        cs += v; sq += v * v;
    }
    __shared__ float scs[256], ssq[256];
    scs[tid] = cs; ssq[tid] = sq;
    __syncthreads();
    if (tid < 128) scs[tid] += scs[tid + 128];
    for (int s = 128; s > 0; s >>= 1) {
        if (tid < s) ssq[tid] += ssq[tid + s];
        __syncthreads();
    }
    if (tid < 128) atomicAdd(&red[tid], scs[tid]);
    if (tid == 0) atomicAdd(&red[128], ssq[0]);
}

// ---------------- pairnorm apply: H = relu((Y - mu) / (sqrt(mean ||y-mu||^2) + 1e-6)) ----------
__global__ __launch_bounds__(256) void pairnorm_kernel(
    const float* __restrict__ Y, const float* __restrict__ red,
    float* __restrict__ Hout, int N)
{
    int tid = threadIdx.x;
    int d = tid & 127;
    float invN = 1.0f / (float)N;
    float mu = red[d] * invN;
    __shared__ float smu2[128];
    if (tid < 128) smu2[tid] = mu * mu;
    __syncthreads();
    for (int s = 64; s > 0; s >>= 1) {
        if (tid < s) smu2[tid] += smu2[tid + s];
        __syncthreads();
    }
    float summu2 = smu2[0];
    float var = red[128] * invN - summu2;   // mean_n sum_d (y-mu)^2
    float norm = sqrtf(fmaxf(var, 0.f)) + 1e-6f;
    float inv = 1.0f / norm;
    int n = blockIdx.x * 2 + (tid >> 7);
    if (n < N) {
        float v = (Y[(size_t)n * DDIM + d] - mu) * inv;
        Hout[(size_t)n * DDIM + d] = fmaxf(v, 0.f);
    }
}

// ---------------- logits: out[n] = h[n,:] . Wh2 + bh2 (one wave per node) ----------------
__global__ __launch_bounds__(256) void logits_kernel(
    const float* __restrict__ h, const float* __restrict__ Wh2,
    const float* __restrict__ bh2, float* __restrict__ out, int N)
{
    int gid = blockIdx.x * 256 + threadIdx.x;
    int n = gid >> 6;
    int lane = gid & 63;
    if (n >= N) return;
    float2 hv = *reinterpret_cast<const float2*>(h + (size_t)n * DDIM + lane * 2);
    float2 wv = *reinterpret_cast<const float2*>(Wh2 + lane * 2);
    float v = hv.x * wv.x + hv.y * wv.y;
#pragma unroll
    for (int off = 32; off > 0; off >>= 1) v += __shfl_down(v, off);
    if (lane == 0) out[n] = v + bh2[0];
}

extern "C" void kernel_launch(void* const* d_in, const int* in_sizes, int n_in,
                              void* d_out, int out_size, void* d_ws, size_t ws_size,
                              hipStream_t stream)
{
    const float* X      = (const float*)d_in[0];
    const int*   rows   = (const int*)d_in[1];
    const int*   cols   = (const int*)d_in[2];
    const float* mask   = (const float*)d_in[3];
    const float* logdeg = (const float*)d_in[4];
    const float* W_in0  = (const float*)d_in[5];
    const float* b_in0  = (const float*)d_in[6];
    const float* W_in1  = (const float*)d_in[7];
    const float* b_in1  = (const float*)d_in[8];
    const float* W_in2  = (const float*)d_in[9];
    const float* b_in2  = (const float*)d_in[10];
    const float* Wmsg[2] = {(const float*)d_in[11], (const float*)d_in[16]};
    const float* Wg1[2]  = {(const float*)d_in[12], (const float*)d_in[17]};
    const float* bg1[2]  = {(const float*)d_in[13], (const float*)d_in[18]};
    const float* Wg2[2]  = {(const float*)d_in[14], (const float*)d_in[19]};
    const float* bg2[2]  = {(const float*)d_in[15], (const float*)d_in[20]};
    const float* Wh1 = (const float*)d_in[21];
    const float* bh1 = (const float*)d_in[22];
    const float* Wh2 = (const float*)d_in[23];
    const float* bh2 = (const float*)d_in[24];

    // workspace layout (floats). Total 23,040,129 floats = 92.2 MB.
    float* ws = (float*)d_ws;
    float* H0     = ws;                 // 5.12M floats (encoder)  | reused: Z (2.56M) + GH (2.56M)
    float* Zbuf   = ws;
    float* GH     = ws + 2560000;
    float* H1     = ws + 5120000;       // 5.12M floats (encoder)  | reused: Y (2.56M) / hhead
    float* Ybuf   = ws + 5120000;
    float* hhead  = ws + 5120000;
    float* scores = ws + 7680000;       // 80000
    float* red    = ws + 7760000;       // 129
    float* H      = ws + 10240000;      // 2.56M floats
    float* Mbuf   = ws + 12800000;      // 10.24M floats
    float* logits = (float*)d_out;
    float* alpha_out = (float*)d_out + N_NODES;

    dim3 blk(256);
    int gy = (N_NODES + 63) / 64;   // 313

    // encoder: H = relu(relu(relu(X W0+b0) W1+b1) W2+b2)
    gemm_kernel<<<dim3(H_IN_ / 64, gy), blk, 0, stream>>>(X, W_in0, b_in0, H0, N_NODES, H_IN_, IN_DIM_, 1);
    gemm_kernel<<<dim3(H_IN_ / 64, gy), blk, 0, stream>>>(H0, W_in1, b_in1, H1, N_NODES, H_IN_, H_IN_, 1);
    gemm_kernel<<<dim3(DDIM / 64, gy), blk, 0, stream>>>(H1, W_in2, b_in2, H, N_NODES, DDIM, H_IN_, 1);

    for (int b = 0; b < 2; b++) {
        // Z = H @ Wmsg
        gemm_kernel<<<dim3(DDIM / 64, gy), blk, 0, stream>>>(H, Wmsg[b], nullptr, Zbuf, N_NODES, DDIM, DDIM, 0);
        // M = segment_sum(Z[cols] by rows), per k
        hipMemsetAsync(Mbuf, 0, (size_t)N_NODES * KADJ * DDIM * sizeof(float), stream);
        scatter_kernel<<<(KADJ * NEDGE * 32) / 256, blk, 0, stream>>>(Mbuf, Zbuf, rows, cols);
        // GH = H @ Wg1[0:128,:] + bg1  (shared across k)
        gemm_kernel<<<dim3(GATE_H_ / 64, gy), blk, 0, stream>>>(H, Wg1[b], bg1[b], GH, N_NODES, GATE_H_, DDIM, 0);
        // scores
        gate_kernel<<<N_NODES, 128, 0, stream>>>(Mbuf, GH, logdeg,
                                                 Wg1[b] + 128 * GATE_H_, Wg1[b] + 256 * GATE_H_,
                                                 Wg2[b], bg2[b], scores);
        // alpha -> directly into d_out
        float* alph = alpha_out + (size_t)b * N_NODES * KADJ;
        alpha_kernel<<<(N_NODES + 255) / 256, blk, 0, stream>>>(scores, mask, alph, N_NODES);
        // Y = H + sum_k alpha*clip(M)
        fuse_kernel<<<(N_NODES * DDIM) / 256, blk, 0, stream>>>(Mbuf, alph, H, Ybuf, N_NODES);
        // pairnorm -> new H (with relu)
        hipMemsetAsync(red, 0, 129 * sizeof(float), stream);
        reduce_kernel<<<512, blk, 0, stream>>>(Ybuf, red, N_NODES);
        pairnorm_kernel<<<(N_NODES + 1) / 2, blk, 0, stream>>>(Ybuf, red, H, N_NODES);
    }

    // head
    gemm_kernel<<<dim3(DDIM / 64, gy), blk, 0, stream>>>(H, Wh1, bh1, hhead, N_NODES, DDIM, DDIM, 1);
    logits_kernel<<<(N_NODES * 64 + 255) / 256, blk, 0, stream>>>(hhead, Wh2, bh2, logits, N_NODES);
}

// Round 2
// 1129.604 us; speedup vs baseline: 4.3992x; 4.3992x over previous
//
#include <hip/hip_runtime.h>
#include <hip/hip_bf16.h>

#define N_NODES 20000
#define KADJ 4
#define NEDGE 320000
#define IN_DIM_ 1024
#define H_IN_ 256
#define DDIM 128
#define GATE_H_ 128
#define TEMP_ 0.6f
#define M_CLAMP_ 20.0f

// ---------------- fp32 tiled GEMM: C = [relu](A[M,K] @ B[K,N] + bias) ----------------
// 64x64 tile, 256 threads, 4x4 per thread, BK=16. N must be multiple of 64, K of 16.
__global__ __launch_bounds__(256) void gemm_kernel(
    const float* __restrict__ A, const float* __restrict__ B,
    const float* __restrict__ bias, float* __restrict__ C,
    int M, int N, int K, int do_relu)
{
    __shared__ float sA[16][68];
    __shared__ float sB[16][64];
    int tid = threadIdx.x;
    int tx = tid & 15, ty = tid >> 4;
    int tileM = blockIdx.y * 64;
    int tileN = blockIdx.x * 64;
    int ar = tid >> 2;          // 0..63 row in tile
    int ac = (tid & 3) << 2;    // 0,4,8,12 k in tile
    int br = tid >> 4;          // 0..15 k in tile
    int bc = (tid & 15) << 2;   // 0..60 col in tile

    float acc[4][4];
#pragma unroll
    for (int i = 0; i < 4; i++)
#pragma unroll
        for (int j = 0; j < 4; j++) acc[i][j] = 0.f;

    for (int k0 = 0; k0 < K; k0 += 16) {
        float4 av = make_float4(0.f, 0.f, 0.f, 0.f);
        int gr = tileM + ar;
        if (gr < M) av = *reinterpret_cast<const float4*>(A + (size_t)gr * K + k0 + ac);
        sA[ac + 0][ar] = av.x; sA[ac + 1][ar] = av.y;
        sA[ac + 2][ar] = av.z; sA[ac + 3][ar] = av.w;
        float4 bv = *reinterpret_cast<const float4*>(B + (size_t)(k0 + br) * N + tileN + bc);
        *reinterpret_cast<float4*>(&sB[br][bc]) = bv;
        __syncthreads();
#pragma unroll
        for (int kk = 0; kk < 16; ++kk) {
            float a0 = sA[kk][ty * 4 + 0], a1 = sA[kk][ty * 4 + 1];
            float a2 = sA[kk][ty * 4 + 2], a3 = sA[kk][ty * 4 + 3];
            float b0 = sB[kk][tx * 4 + 0], b1 = sB[kk][tx * 4 + 1];
            float b2 = sB[kk][tx * 4 + 2], b3 = sB[kk][tx * 4 + 3];
            acc[0][0] += a0 * b0; acc[0][1] += a0 * b1; acc[0][2] += a0 * b2; acc[0][3] += a0 * b3;
            acc[1][0] += a1 * b0; acc[1][1] += a1 * b1; acc[1][2] += a1 * b2; acc[1][3] += a1 * b3;
            acc[2][0] += a2 * b0; acc[2][1] += a2 * b1; acc[2][2] += a2 * b2; acc[2][3] += a2 * b3;
            acc[3][0] += a3 * b0; acc[3][1] += a3 * b1; acc[3][2] += a3 * b2; acc[3][3] += a3 * b3;
        }
        __syncthreads();
    }
#pragma unroll
    for (int i = 0; i < 4; i++) {
        int row = tileM + ty * 4 + i;
        if (row >= M) continue;
        int col = tileN + tx * 4;
        float4 v;
        v.x = acc[i][0]; v.y = acc[i][1]; v.z = acc[i][2]; v.w = acc[i][3];
        if (bias) {
            v.x += bias[col]; v.y += bias[col + 1];
            v.z += bias[col + 2]; v.w += bias[col + 3];
        }
        if (do_relu) {
            v.x = fmaxf(v.x, 0.f); v.y = fmaxf(v.y, 0.f);
            v.z = fmaxf(v.z, 0.f); v.w = fmaxf(v.w, 0.f);
        }
        *reinterpret_cast<float4*>(C + (size_t)row * N + col) = v;
    }
}

// ================= CSR build (once per launch; rows/cols shared by both blocks) ==========
// cnt[k*N+r] = #edges with row r in adjacency k
__global__ __launch_bounds__(256) void hist_kernel(
    const int* __restrict__ rows, int* __restrict__ cnt)
{
    int gid = blockIdx.x * 256 + threadIdx.x;
    if (gid >= KADJ * NEDGE) return;
    int k = gid / NEDGE;
    int r = rows[gid];
    atomicAdd(&cnt[k * N_NODES + r], 1);
}

// exclusive scan of cnt[0..79999] -> offs; cnt becomes running cursor; offs[80000]=total.
// Global scan gives per-k bases automatically (counts per k sum to NEDGE).
__global__ __launch_bounds__(1024) void scan_kernel(int* __restrict__ cnt, int* __restrict__ offs)
{
    __shared__ int ssum[1024];
    const int TOTAL = KADJ * N_NODES;  // 80000
    const int CH = 80;                 // 1024*80 >= 80000
    int t = threadIdx.x;
    int lo = t * CH, hi = min(lo + CH, TOTAL);
    int s = 0;
    for (int i = lo; i < hi; i++) s += cnt[i];
    ssum[t] = s;
    __syncthreads();
    for (int d = 1; d < 1024; d <<= 1) {
        int v = (t >= d) ? ssum[t - d] : 0;
        __syncthreads();
        ssum[t] += v;
        __syncthreads();
    }
    int run = (t == 0) ? 0 : ssum[t - 1];
    for (int i = lo; i < hi; i++) {
        int cv = cnt[i];
        offs[i] = run;
        cnt[i] = run;  // cursor for fill phase
        run += cv;
    }
    if (t == 0) offs[TOTAL] = KADJ * NEDGE;
}

// edst[pos] = col, edges bucketed by (k,row)
__global__ __launch_bounds__(256) void fill_kernel(
    const int* __restrict__ rows, const int* __restrict__ cols,
    int* __restrict__ cur, int* __restrict__ edst)
{
    int gid = blockIdx.x * 256 + threadIdx.x;
    if (gid >= KADJ * NEDGE) return;
    int k = gid / NEDGE;
    int r = rows[gid];
    int c = cols[gid];
    int pos = atomicAdd(&cur[k * N_NODES + r], 1);
    edst[pos] = c;
}

// ---------------- gather: M[r,k,:] = clip(sum_{e in csr(k,r)} Z[col_e,:])  (NO atomics) ----------
// one wave per (k,r) pair; lane holds float2; avg degree ~16.
__global__ __launch_bounds__(256) void gather_kernel(
    const int* __restrict__ offs, const int* __restrict__ edst,
    const float* __restrict__ Z, float* __restrict__ Mbuf)
{
    int q = blockIdx.x * 4 + (threadIdx.x >> 6);   // q = k*N + r
    int lane = threadIdx.x & 63;
    int k = q / N_NODES;
    int r = q - k * N_NODES;
    int start = offs[q];
    int end = offs[q + 1];
    float accx = 0.f, accy = 0.f;
    int i = start;
    for (; i + 1 < end; i += 2) {
        int c0 = edst[i], c1 = edst[i + 1];
        float2 z0 = *reinterpret_cast<const float2*>(Z + (size_t)c0 * DDIM + lane * 2);
        float2 z1 = *reinterpret_cast<const float2*>(Z + (size_t)c1 * DDIM + lane * 2);
        accx += z0.x; accy += z0.y;
        accx += z1.x; accy += z1.y;
    }
    if (i < end) {
        int c = edst[i];
        float2 z = *reinterpret_cast<const float2*>(Z + (size_t)c * DDIM + lane * 2);
        accx += z.x; accy += z.y;
    }
    float2 out;
    out.x = fminf(fmaxf(accx, -M_CLAMP_), M_CLAMP_);
    out.y = fminf(fmaxf(accy, -M_CLAMP_), M_CLAMP_);
    *reinterpret_cast<float2*>(Mbuf + ((size_t)r * KADJ + k) * DDIM + lane * 2) = out;
}

// ---------------- gate: scores[n,k] = relu(GH[n] + M[n,k]@Wg1m + logdeg*wld) . Wg2 + bg2 ----
// M arrives pre-clipped from gather.
__global__ __launch_bounds__(128) void gate_kernel(
    const float* __restrict__ Mbuf, const float* __restrict__ GH,
    const float* __restrict__ logdeg, const float* __restrict__ Wg1m,
    const float* __restrict__ wld, const float* __restrict__ Wg2,
    const float* __restrict__ bg2, float* __restrict__ scores)
{
    int n = blockIdx.x;
    int j = threadIdx.x;  // gate hidden unit
    __shared__ float sM[KADJ][DDIM];
#pragma unroll
    for (int k = 0; k < KADJ; k++) {
        sM[k][j] = Mbuf[((size_t)n * KADJ + k) * DDIM + j];
    }
    __syncthreads();
    float ghj = GH[(size_t)n * DDIM + j];   // already includes bg1
    float wldj = wld[j];
    float acc0 = ghj + logdeg[n * KADJ + 0] * wldj;
    float acc1 = ghj + logdeg[n * KADJ + 1] * wldj;
    float acc2 = ghj + logdeg[n * KADJ + 2] * wldj;
    float acc3 = ghj + logdeg[n * KADJ + 3] * wldj;
    for (int i = 0; i < DDIM; i++) {
        float w = Wg1m[i * GATE_H_ + j];
        acc0 += sM[0][i] * w;
        acc1 += sM[1][i] * w;
        acc2 += sM[2][i] * w;
        acc3 += sM[3][i] * w;
    }
    float g = Wg2[j];
    __shared__ float rbuf[KADJ][DDIM];
    rbuf[0][j] = fmaxf(acc0, 0.f) * g;
    rbuf[1][j] = fmaxf(acc1, 0.f) * g;
    rbuf[2][j] = fmaxf(acc2, 0.f) * g;
    rbuf[3][j] = fmaxf(acc3, 0.f) * g;
    __syncthreads();
    for (int s = 64; s > 0; s >>= 1) {
        if (j < s) {
#pragma unroll
            for (int k = 0; k < KADJ; k++) rbuf[k][j] += rbuf[k][j + s];
        }
        __syncthreads();
    }
    if (j < KADJ) scores[(size_t)n * KADJ + j] = rbuf[j][0] + bg2[0];
}

// ---------------- alpha: softmax(scores/T) * mask, renorm, clamp 1e-8, renorm ----------------
__global__ __launch_bounds__(256) void alpha_kernel(
    const float* __restrict__ scores, const float* __restrict__ mask,
    float* __restrict__ alpha, int N)
{
    int n = blockIdx.x * 256 + threadIdx.x;
    if (n >= N) return;
    float s[KADJ], a[KADJ];
    float mx = -1e30f;
#pragma unroll
    for (int k = 0; k < KADJ; k++) {
        s[k] = scores[(size_t)n * KADJ + k] * (1.0f / TEMP_);
        mx = fmaxf(mx, s[k]);
    }
    float sum = 0.f;
#pragma unroll
    for (int k = 0; k < KADJ; k++) { a[k] = expf(s[k] - mx); sum += a[k]; }
#pragma unroll
    for (int k = 0; k < KADJ; k++) a[k] = (a[k] / sum) * mask[(size_t)n * KADJ + k];
    float s2 = 0.f;
#pragma unroll
    for (int k = 0; k < KADJ; k++) s2 += a[k];
    float inv = 1.f / fmaxf(s2, 1e-12f);
#pragma unroll
    for (int k = 0; k < KADJ; k++) a[k] = fmaxf(a[k] * inv, 1e-8f);
    s2 = 0.f;
#pragma unroll
    for (int k = 0; k < KADJ; k++) s2 += a[k];
    inv = 1.f / fmaxf(s2, 1e-12f);
#pragma unroll
    for (int k = 0; k < KADJ; k++) alpha[(size_t)n * KADJ + k] = a[k] * inv;
}

// ---------------- fused: Y[n,:] = H[n,:] + sum_k alpha[n,k]*M[n,k,:] (M pre-clipped) --------
__global__ __launch_bounds__(256) void fuse_kernel(
    const float* __restrict__ Mbuf, const float* __restrict__ alpha,
    const float* __restrict__ H, float* __restrict__ Y, int N)
{
    int idx = blockIdx.x * 256 + threadIdx.x;
    int n = idx >> 7, d = idx & 127;
    if (n >= N) return;
    float y = H[idx];
#pragma unroll
    for (int k = 0; k < KADJ; k++) {
        y += alpha[(size_t)n * KADJ + k] * Mbuf[((size_t)n * KADJ + k) * DDIM + d];
    }
    Y[idx] = y;
}

// ---------------- pairnorm reduction: red[0..127]=colsum, red[128]=sum of squares ----------------
__global__ __launch_bounds__(256) void reduce_kernel(
    const float* __restrict__ Y, float* __restrict__ red, int N)
{
    int tid = threadIdx.x;
    int d = tid & 127;
    int half = tid >> 7;
    float cs = 0.f, sq = 0.f;
    for (int n = blockIdx.x * 2 + half; n < N; n += gridDim.x * 2) {
        float v = Y[(size_t)n * DDIM + d];
        cs += v; sq += v * v;
    }
    __shared__ float scs[256], ssq[256];
    scs[tid] = cs; ssq[tid] = sq;
    __syncthreads();
    if (tid < 128) scs[tid] += scs[tid + 128];
    for (int s = 128; s > 0; s >>= 1) {
        if (tid < s) ssq[tid] += ssq[tid + s];
        __syncthreads();
    }
    if (tid < 128) atomicAdd(&red[tid], scs[tid]);
    if (tid == 0) atomicAdd(&red[128], ssq[0]);
}

// ---------------- pairnorm apply: H = relu((Y - mu) / (sqrt(mean ||y-mu||^2) + 1e-6)) ----------
__global__ __launch_bounds__(256) void pairnorm_kernel(
    const float* __restrict__ Y, const float* __restrict__ red,
    float* __restrict__ Hout, int N)
{
    int tid = threadIdx.x;
    int d = tid & 127;
    float invN = 1.0f / (float)N;
    float mu = red[d] * invN;
    __shared__ float smu2[128];
    if (tid < 128) smu2[tid] = mu * mu;
    __syncthreads();
    for (int s = 64; s > 0; s >>= 1) {
        if (tid < s) smu2[tid] += smu2[tid + s];
        __syncthreads();
    }
    float summu2 = smu2[0];
    float var = red[128] * invN - summu2;   // mean_n sum_d (y-mu)^2
    float norm = sqrtf(fmaxf(var, 0.f)) + 1e-6f;
    float inv = 1.0f / norm;
    int n = blockIdx.x * 2 + (tid >> 7);
    if (n < N) {
        float v = (Y[(size_t)n * DDIM + d] - mu) * inv;
        Hout[(size_t)n * DDIM + d] = fmaxf(v, 0.f);
    }
}

// ---------------- logits: out[n] = h[n,:] . Wh2 + bh2 (one wave per node) ----------------
__global__ __launch_bounds__(256) void logits_kernel(
    const float* __restrict__ h, const float* __restrict__ Wh2,
    const float* __restrict__ bh2, float* __restrict__ out, int N)
{
    int gid = blockIdx.x * 256 + threadIdx.x;
    int n = gid >> 6;
    int lane = gid & 63;
    if (n >= N) return;
    float2 hv = *reinterpret_cast<const float2*>(h + (size_t)n * DDIM + lane * 2);
    float2 wv = *reinterpret_cast<const float2*>(Wh2 + lane * 2);
    float v = hv.x * wv.x + hv.y * wv.y;
#pragma unroll
    for (int off = 32; off > 0; off >>= 1) v += __shfl_down(v, off);
    if (lane == 0) out[n] = v + bh2[0];
}

extern "C" void kernel_launch(void* const* d_in, const int* in_sizes, int n_in,
                              void* d_out, int out_size, void* d_ws, size_t ws_size,
                              hipStream_t stream)
{
    const float* X      = (const float*)d_in[0];
    const int*   rows   = (const int*)d_in[1];
    const int*   cols   = (const int*)d_in[2];
    const float* mask   = (const float*)d_in[3];
    const float* logdeg = (const float*)d_in[4];
    const float* W_in0  = (const float*)d_in[5];
    const float* b_in0  = (const float*)d_in[6];
    const float* W_in1  = (const float*)d_in[7];
    const float* b_in1  = (const float*)d_in[8];
    const float* W_in2  = (const float*)d_in[9];
    const float* b_in2  = (const float*)d_in[10];
    const float* Wmsg[2] = {(const float*)d_in[11], (const float*)d_in[16]};
    const float* Wg1[2]  = {(const float*)d_in[12], (const float*)d_in[17]};
    const float* bg1[2]  = {(const float*)d_in[13], (const float*)d_in[18]};
    const float* Wg2[2]  = {(const float*)d_in[14], (const float*)d_in[19]};
    const float* bg2[2]  = {(const float*)d_in[15], (const float*)d_in[20]};
    const float* Wh1 = (const float*)d_in[21];
    const float* bh1 = (const float*)d_in[22];
    const float* Wh2 = (const float*)d_in[23];
    const float* bh2 = (const float*)d_in[24];

    // workspace layout (float slots). Total ~22.0M floats = 88 MB (fits prior 92.2 MB use).
    float* ws = (float*)d_ws;
    float* Mbuf   = ws;                   // 10.24M  | encoder overlays: H0 at 0 (5.12M), H1 at +5.12M
    float* H0     = ws;
    float* H1     = ws + 5120000;
    float* H      = ws + 10240000;        // 2.56M
    float* Zbuf   = ws + 12800000;        // 2.56M
    float* GH     = ws + 15360000;        // 2.56M
    float* Ybuf   = ws + 17920000;        // 2.56M (also hhead)
    float* hhead  = ws + 17920000;
    float* scores = ws + 20480000;        // 80000
    float* red    = ws + 20560000;        // 129 (pad to 256)
    int*   cnt    = (int*)(ws + 20560256);  // 80000 ints (cursor after scan)
    int*   offs   = (int*)(ws + 20640256);  // 80001 ints (pad to 80064)
    int*   edst   = (int*)(ws + 20720320);  // 1.28M ints
    float* logits = (float*)d_out;
    float* alpha_out = (float*)d_out + N_NODES;

    dim3 blk(256);
    int gy = (N_NODES + 63) / 64;   // 313
    int egrid = (KADJ * NEDGE + 255) / 256;  // 5000

    // ---- CSR build (once; shared by both blocks) ----
    hipMemsetAsync(cnt, 0, KADJ * N_NODES * sizeof(int), stream);
    hist_kernel<<<egrid, blk, 0, stream>>>(rows, cnt);
    scan_kernel<<<1, 1024, 0, stream>>>(cnt, offs);
    fill_kernel<<<egrid, blk, 0, stream>>>(rows, cols, cnt, edst);

    // ---- encoder: H = relu(relu(relu(X W0+b0) W1+b1) W2+b2) ----
    gemm_kernel<<<dim3(H_IN_ / 64, gy), blk, 0, stream>>>(X, W_in0, b_in0, H0, N_NODES, H_IN_, IN_DIM_, 1);
    gemm_kernel<<<dim3(H_IN_ / 64, gy), blk, 0, stream>>>(H0, W_in1, b_in1, H1, N_NODES, H_IN_, H_IN_, 1);
    gemm_kernel<<<dim3(DDIM / 64, gy), blk, 0, stream>>>(H1, W_in2, b_in2, H, N_NODES, DDIM, H_IN_, 1);

    for (int b = 0; b < 2; b++) {
        // Z = H @ Wmsg
        gemm_kernel<<<dim3(DDIM / 64, gy), blk, 0, stream>>>(H, Wmsg[b], nullptr, Zbuf, N_NODES, DDIM, DDIM, 0);
        // M[r,k,:] = clip(sum Z[c]) via CSR gather (writes every slot; no memset, no atomics)
        gather_kernel<<<(KADJ * N_NODES) / 4, blk, 0, stream>>>(offs, edst, Zbuf, Mbuf);
        // GH = H @ Wg1[0:128,:] + bg1  (shared across k)
        gemm_kernel<<<dim3(GATE_H_ / 64, gy), blk, 0, stream>>>(H, Wg1[b], bg1[b], GH, N_NODES, GATE_H_, DDIM, 0);
        // scores
        gate_kernel<<<N_NODES, 128, 0, stream>>>(Mbuf, GH, logdeg,
                                                 Wg1[b] + 128 * GATE_H_, Wg1[b] + 256 * GATE_H_,
                                                 Wg2[b], bg2[b], scores);
        // alpha -> directly into d_out
        float* alph = alpha_out + (size_t)b * N_NODES * KADJ;
        alpha_kernel<<<(N_NODES + 255) / 256, blk, 0, stream>>>(scores, mask, alph, N_NODES);
        // Y = H + sum_k alpha*M
        fuse_kernel<<<(N_NODES * DDIM) / 256, blk, 0, stream>>>(Mbuf, alph, H, Ybuf, N_NODES);
        // pairnorm -> new H (with relu)
        hipMemsetAsync(red, 0, 129 * sizeof(float), stream);
        reduce_kernel<<<512, blk, 0, stream>>>(Ybuf, red, N_NODES);
        pairnorm_kernel<<<(N_NODES + 1) / 2, blk, 0, stream>>>(Ybuf, red, H, N_NODES);
    }

    // head
    gemm_kernel<<<dim3(DDIM / 64, gy), blk, 0, stream>>>(H, Wh1, bh1, hhead, N_NODES, DDIM, DDIM, 1);
    logits_kernel<<<(N_NODES * 64 + 255) / 256, blk, 0, stream>>>(hhead, Wh2, bh2, logits, N_NODES);
}

// Round 3
// 860.761 us; speedup vs baseline: 5.7732x; 1.3123x over previous
//
#include <hip/hip_runtime.h>
#include <hip/hip_bf16.h>

#define N_NODES 20000
#define KADJ 4
#define NEDGE 320000
#define IN_DIM_ 1024
#define H_IN_ 256
#define DDIM 128
#define GATE_H_ 128
#define TEMP_ 0.6f
#define M_CLAMP_ 20.0f
#define CSR_TOTAL (KADJ * N_NODES)          // 80000
#define SCAN_NB ((CSR_TOTAL + 255) / 256)   // 313

typedef __attribute__((ext_vector_type(8))) short frag_ab;      // 8 bf16
typedef __attribute__((ext_vector_type(4))) float frag_cd;      // 4 fp32
typedef __attribute__((ext_vector_type(8))) unsigned short us8;

__device__ inline unsigned short f2bf(float f) {
    unsigned int u = __float_as_uint(f);
    u += 0x7FFFu + ((u >> 16) & 1);   // RNE
    return (unsigned short)(u >> 16);
}

// ============== bf16 MFMA GEMM: C = [relu](A[M,K]_fp32 @ (Bt[N,K]_bf16)^T + bias) ==============
// 128x128 tile, 256 threads = 4 waves, wave computes 64x64 via 4x4 frags of 16x16x32.
// A converted fp32->bf16 during LDS staging. BK=32 (one MFMA K-step per stage).
__global__ __launch_bounds__(256) void mfma_gemm_kernel(
    const float* __restrict__ A, const unsigned short* __restrict__ Bt,
    const float* __restrict__ bias, float* __restrict__ C,
    int M, int N, int K, int do_relu)
{
    __shared__ unsigned short sA[128][40];   // +8 pad: 80B row stride -> 2-way-max bank alias (free)
    __shared__ unsigned short sB[128][40];
    int tid = threadIdx.x;
    int tileM = blockIdx.y * 128, tileN = blockIdx.x * 128;
    int w = tid >> 6, lane = tid & 63;
    int wr = (w & 1) * 64, wc = (w >> 1) * 64;
    int fm = lane & 15;      // frag row (A) / col (B) / col (C)
    int fq = lane >> 4;      // quad: k = fq*8+j (A/B), row = fq*4+r (C/D)
    int sr = tid >> 1;       // staging row 0..127
    int sh = tid & 1;        // staging k-half (16 elems)

    frag_cd acc[4][4] = {};

    for (int k0 = 0; k0 < K; k0 += 32) {
        // ---- stage A (fp32 -> bf16) ----
        {
            int gr = tileM + sr;
            float fv[16];
            if (gr < M) {
                const float4* ap = (const float4*)(A + (size_t)gr * K + k0 + sh * 16);
                float4 f0 = ap[0], f1 = ap[1], f2 = ap[2], f3 = ap[3];
                fv[0]=f0.x; fv[1]=f0.y; fv[2]=f0.z; fv[3]=f0.w;
                fv[4]=f1.x; fv[5]=f1.y; fv[6]=f1.z; fv[7]=f1.w;
                fv[8]=f2.x; fv[9]=f2.y; fv[10]=f2.z; fv[11]=f2.w;
                fv[12]=f3.x; fv[13]=f3.y; fv[14]=f3.z; fv[15]=f3.w;
            } else {
#pragma unroll
                for (int i = 0; i < 16; i++) fv[i] = 0.f;
            }
            us8 lo, hi;
#pragma unroll
            for (int i = 0; i < 8; i++) { lo[i] = f2bf(fv[i]); hi[i] = f2bf(fv[8 + i]); }
            *(us8*)&sA[sr][sh * 16] = lo;
            *(us8*)&sA[sr][sh * 16 + 8] = hi;
        }
        // ---- stage B (already bf16, [N][K]) ----
        {
            const us8* bp = (const us8*)(Bt + (size_t)(tileN + sr) * K + k0 + sh * 16);
            *(us8*)&sB[sr][sh * 16] = bp[0];
            *(us8*)&sB[sr][sh * 16 + 8] = bp[1];
        }
        __syncthreads();
        frag_ab af[4], bfv[4];
#pragma unroll
        for (int i = 0; i < 4; i++) af[i] = *(const frag_ab*)&sA[wr + i * 16 + fm][fq * 8];
#pragma unroll
        for (int j = 0; j < 4; j++) bfv[j] = *(const frag_ab*)&sB[wc + j * 16 + fm][fq * 8];
#pragma unroll
        for (int i = 0; i < 4; i++)
#pragma unroll
            for (int j = 0; j < 4; j++)
                acc[i][j] = __builtin_amdgcn_mfma_f32_16x16x32_bf16(af[i], bfv[j], acc[i][j], 0, 0, 0);
        __syncthreads();
    }
#pragma unroll
    for (int i = 0; i < 4; i++) {
        int row = tileM + wr + i * 16 + fq * 4;
#pragma unroll
        for (int r = 0; r < 4; r++) {
            if (row + r < M) {
#pragma unroll
                for (int j = 0; j < 4; j++) {
                    int col = tileN + wc + j * 16 + fm;
                    float v = acc[i][j][r];
                    if (bias) v += bias[col];
                    if (do_relu) v = fmaxf(v, 0.f);
                    C[(size_t)(row + r) * N + col] = v;
                }
            }
        }
    }
}

// ============== weight transpose+convert: Wt[n][k] = bf16(W[k][n]); K,N multiples of 32 ==========
__global__ __launch_bounds__(256) void transpose_bf16_kernel(
    const float* __restrict__ W, unsigned short* __restrict__ Wt, int K, int N)
{
    __shared__ float tile[32][33];
    int tx = threadIdx.x & 31, ty4 = (threadIdx.x >> 5) * 4;
    int n0 = blockIdx.x * 32, k0 = blockIdx.y * 32;
#pragma unroll
    for (int i = 0; i < 4; i++)
        tile[ty4 + i][tx] = W[(size_t)(k0 + ty4 + i) * N + n0 + tx];
    __syncthreads();
#pragma unroll
    for (int i = 0; i < 4; i++)
        Wt[(size_t)(n0 + ty4 + i) * K + k0 + tx] = f2bf(tile[tx][ty4 + i]);
}

// ================= CSR build (once per launch; rows/cols shared by both blocks) ==========
__global__ __launch_bounds__(256) void hist_kernel(
    const int* __restrict__ rows, int* __restrict__ cnt)
{
    int gid = blockIdx.x * 256 + threadIdx.x;
    if (gid >= KADJ * NEDGE) return;
    int k = gid / NEDGE;
    atomicAdd(&cnt[k * N_NODES + rows[gid]], 1);
}

// multi-block exclusive scan of cnt[0..79999] -> offs (3 phases)
__global__ __launch_bounds__(256) void scan1_kernel(
    const int* __restrict__ cnt, int* __restrict__ offs, int* __restrict__ bsum)
{
    __shared__ int s[256];
    int t = threadIdx.x, i = blockIdx.x * 256 + t;
    int v = (i < CSR_TOTAL) ? cnt[i] : 0;
    s[t] = v; __syncthreads();
    for (int d = 1; d < 256; d <<= 1) {
        int u = (t >= d) ? s[t - d] : 0; __syncthreads();
        s[t] += u; __syncthreads();
    }
    if (i < CSR_TOTAL) offs[i] = s[t] - v;
    if (t == 255) bsum[blockIdx.x] = s[255];
}

__global__ __launch_bounds__(512) void scan2_kernel(
    const int* __restrict__ bsum, int* __restrict__ bbase)
{
    __shared__ int s[512];
    int t = threadIdx.x;
    int v = (t < SCAN_NB) ? bsum[t] : 0;
    s[t] = v; __syncthreads();
    for (int d = 1; d < 512; d <<= 1) {
        int u = (t >= d) ? s[t - d] : 0; __syncthreads();
        s[t] += u; __syncthreads();
    }
    if (t < SCAN_NB) bbase[t] = s[t] - v;
}

__global__ __launch_bounds__(256) void scan3_kernel(
    int* __restrict__ offs, const int* __restrict__ bbase, int* __restrict__ cur)
{
    int i = blockIdx.x * 256 + threadIdx.x;
    if (i < CSR_TOTAL) {
        int o = offs[i] + bbase[blockIdx.x];
        offs[i] = o;
        cur[i] = o;
    }
    if (i == 0) offs[CSR_TOTAL] = KADJ * NEDGE;
}

__global__ __launch_bounds__(256) void fill_kernel(
    const int* __restrict__ rows, const int* __restrict__ cols,
    int* __restrict__ cur, int* __restrict__ edst)
{
    int gid = blockIdx.x * 256 + threadIdx.x;
    if (gid >= KADJ * NEDGE) return;
    int k = gid / NEDGE;
    int pos = atomicAdd(&cur[k * N_NODES + rows[gid]], 1);
    edst[pos] = cols[gid];
}

// ---------------- gather: M[r,k,:] = clip(sum_{e in csr(k,r)} Z[col_e,:])  (NO atomics) ----------
__global__ __launch_bounds__(256) void gather_kernel(
    const int* __restrict__ offs, const int* __restrict__ edst,
    const float* __restrict__ Z, float* __restrict__ Mbuf)
{
    int q = blockIdx.x * 4 + (threadIdx.x >> 6);   // q = k*N + r
    int lane = threadIdx.x & 63;
    int k = q / N_NODES;
    int r = q - k * N_NODES;
    int start = offs[q];
    int end = offs[q + 1];
    float accx = 0.f, accy = 0.f;
    int i = start;
    for (; i + 1 < end; i += 2) {
        int c0 = edst[i], c1 = edst[i + 1];
        float2 z0 = *reinterpret_cast<const float2*>(Z + (size_t)c0 * DDIM + lane * 2);
        float2 z1 = *reinterpret_cast<const float2*>(Z + (size_t)c1 * DDIM + lane * 2);
        accx += z0.x; accy += z0.y;
        accx += z1.x; accy += z1.y;
    }
    if (i < end) {
        int c = edst[i];
        float2 z = *reinterpret_cast<const float2*>(Z + (size_t)c * DDIM + lane * 2);
        accx += z.x; accy += z.y;
    }
    float2 out;
    out.x = fminf(fmaxf(accx, -M_CLAMP_), M_CLAMP_);
    out.y = fminf(fmaxf(accy, -M_CLAMP_), M_CLAMP_);
    *reinterpret_cast<float2*>(Mbuf + ((size_t)r * KADJ + k) * DDIM + lane * 2) = out;
}

// ---------------- gate: scores[n,k] = relu(GH[n] + M[n,k]@Wg1m + logdeg*wld) . Wg2 + bg2 ----
__global__ __launch_bounds__(128) void gate_kernel(
    const float* __restrict__ Mbuf, const float* __restrict__ GH,
    const float* __restrict__ logdeg, const float* __restrict__ Wg1m,
    const float* __restrict__ wld, const float* __restrict__ Wg2,
    const float* __restrict__ bg2, float* __restrict__ scores)
{
    int n = blockIdx.x;
    int j = threadIdx.x;
    __shared__ float sM[KADJ][DDIM];
#pragma unroll
    for (int k = 0; k < KADJ; k++)
        sM[k][j] = Mbuf[((size_t)n * KADJ + k) * DDIM + j];
    __syncthreads();
    float ghj = GH[(size_t)n * DDIM + j];
    float wldj = wld[j];
    float acc0 = ghj + logdeg[n * KADJ + 0] * wldj;
    float acc1 = ghj + logdeg[n * KADJ + 1] * wldj;
    float acc2 = ghj + logdeg[n * KADJ + 2] * wldj;
    float acc3 = ghj + logdeg[n * KADJ + 3] * wldj;
    for (int i = 0; i < DDIM; i++) {
        float w = Wg1m[i * GATE_H_ + j];
        acc0 += sM[0][i] * w;
        acc1 += sM[1][i] * w;
        acc2 += sM[2][i] * w;
        acc3 += sM[3][i] * w;
    }
    float g = Wg2[j];
    __shared__ float rbuf[KADJ][DDIM];
    rbuf[0][j] = fmaxf(acc0, 0.f) * g;
    rbuf[1][j] = fmaxf(acc1, 0.f) * g;
    rbuf[2][j] = fmaxf(acc2, 0.f) * g;
    rbuf[3][j] = fmaxf(acc3, 0.f) * g;
    __syncthreads();
    for (int s = 64; s > 0; s >>= 1) {
        if (j < s) {
#pragma unroll
            for (int k = 0; k < KADJ; k++) rbuf[k][j] += rbuf[k][j + s];
        }
        __syncthreads();
    }
    if (j < KADJ) scores[(size_t)n * KADJ + j] = rbuf[j][0] + bg2[0];
}

// ---------------- alpha ----------------
__global__ __launch_bounds__(256) void alpha_kernel(
    const float* __restrict__ scores, const float* __restrict__ mask,
    float* __restrict__ alpha, int N)
{
    int n = blockIdx.x * 256 + threadIdx.x;
    if (n >= N) return;
    float s[KADJ], a[KADJ];
    float mx = -1e30f;
#pragma unroll
    for (int k = 0; k < KADJ; k++) {
        s[k] = scores[(size_t)n * KADJ + k] * (1.0f / TEMP_);
        mx = fmaxf(mx, s[k]);
    }
    float sum = 0.f;
#pragma unroll
    for (int k = 0; k < KADJ; k++) { a[k] = expf(s[k] - mx); sum += a[k]; }
#pragma unroll
    for (int k = 0; k < KADJ; k++) a[k] = (a[k] / sum) * mask[(size_t)n * KADJ + k];
    float s2 = 0.f;
#pragma unroll
    for (int k = 0; k < KADJ; k++) s2 += a[k];
    float inv = 1.f / fmaxf(s2, 1e-12f);
#pragma unroll
    for (int k = 0; k < KADJ; k++) a[k] = fmaxf(a[k] * inv, 1e-8f);
    s2 = 0.f;
#pragma unroll
    for (int k = 0; k < KADJ; k++) s2 += a[k];
    inv = 1.f / fmaxf(s2, 1e-12f);
#pragma unroll
    for (int k = 0; k < KADJ; k++) alpha[(size_t)n * KADJ + k] = a[k] * inv;
}

// ---------------- fused: Y = H + sum_k alpha*M (M pre-clipped) --------
__global__ __launch_bounds__(256) void fuse_kernel(
    const float* __restrict__ Mbuf, const float* __restrict__ alpha,
    const float* __restrict__ H, float* __restrict__ Y, int N)
{
    int idx = blockIdx.x * 256 + threadIdx.x;
    int n = idx >> 7, d = idx & 127;
    if (n >= N) return;
    float y = H[idx];
#pragma unroll
    for (int k = 0; k < KADJ; k++)
        y += alpha[(size_t)n * KADJ + k] * Mbuf[((size_t)n * KADJ + k) * DDIM + d];
    Y[idx] = y;
}

// ---------------- pairnorm reduction ----------------
__global__ __launch_bounds__(256) void reduce_kernel(
    const float* __restrict__ Y, float* __restrict__ red, int N)
{
    int tid = threadIdx.x;
    int d = tid & 127;
    int half = tid >> 7;
    float cs = 0.f, sq = 0.f;
    for (int n = blockIdx.x * 2 + half; n < N; n += gridDim.x * 2) {
        float v = Y[(size_t)n * DDIM + d];
        cs += v; sq += v * v;
    }
    __shared__ float scs[256], ssq[256];
    scs[tid] = cs; ssq[tid] = sq;
    __syncthreads();
    if (tid < 128) scs[tid] += scs[tid + 128];
    for (int s = 128; s > 0; s >>= 1) {
        if (tid < s) ssq[tid] += ssq[tid + s];
        __syncthreads();
    }
    if (tid < 128) atomicAdd(&red[tid], scs[tid]);
    if (tid == 0) atomicAdd(&red[128], ssq[0]);
}

// ---------------- pairnorm apply ----------
__global__ __launch_bounds__(256) void pairnorm_kernel(
    const float* __restrict__ Y, const float* __restrict__ red,
    float* __restrict__ Hout, int N)
{
    int tid = threadIdx.x;
    int d = tid & 127;
    float invN = 1.0f / (float)N;
    float mu = red[d] * invN;
    __shared__ float smu2[128];
    if (tid < 128) smu2[tid] = mu * mu;
    __syncthreads();
    for (int s = 64; s > 0; s >>= 1) {
        if (tid < s) smu2[tid] += smu2[tid + s];
        __syncthreads();
    }
    float summu2 = smu2[0];
    float var = red[128] * invN - summu2;
    float norm = sqrtf(fmaxf(var, 0.f)) + 1e-6f;
    float inv = 1.0f / norm;
    int n = blockIdx.x * 2 + (tid >> 7);
    if (n < N) {
        float v = (Y[(size_t)n * DDIM + d] - mu) * inv;
        Hout[(size_t)n * DDIM + d] = fmaxf(v, 0.f);
    }
}

// ---------------- logits ----------------
__global__ __launch_bounds__(256) void logits_kernel(
    const float* __restrict__ h, const float* __restrict__ Wh2,
    const float* __restrict__ bh2, float* __restrict__ out, int N)
{
    int gid = blockIdx.x * 256 + threadIdx.x;
    int n = gid >> 6;
    int lane = gid & 63;
    if (n >= N) return;
    float2 hv = *reinterpret_cast<const float2*>(h + (size_t)n * DDIM + lane * 2);
    float2 wv = *reinterpret_cast<const float2*>(Wh2 + lane * 2);
    float v = hv.x * wv.x + hv.y * wv.y;
#pragma unroll
    for (int off = 32; off > 0; off >>= 1) v += __shfl_down(v, off);
    if (lane == 0) out[n] = v + bh2[0];
}

extern "C" void kernel_launch(void* const* d_in, const int* in_sizes, int n_in,
                              void* d_out, int out_size, void* d_ws, size_t ws_size,
                              hipStream_t stream)
{
    const float* X      = (const float*)d_in[0];
    const int*   rows   = (const int*)d_in[1];
    const int*   cols   = (const int*)d_in[2];
    const float* mask   = (const float*)d_in[3];
    const float* logdeg = (const float*)d_in[4];
    const float* W_in0  = (const float*)d_in[5];
    const float* b_in0  = (const float*)d_in[6];
    const float* W_in1  = (const float*)d_in[7];
    const float* b_in1  = (const float*)d_in[8];
    const float* W_in2  = (const float*)d_in[9];
    const float* b_in2  = (const float*)d_in[10];
    const float* Wmsg[2] = {(const float*)d_in[11], (const float*)d_in[16]};
    const float* Wg1[2]  = {(const float*)d_in[12], (const float*)d_in[17]};
    const float* bg1[2]  = {(const float*)d_in[13], (const float*)d_in[18]};
    const float* Wg2[2]  = {(const float*)d_in[14], (const float*)d_in[19]};
    const float* bg2[2]  = {(const float*)d_in[15], (const float*)d_in[20]};
    const float* Wh1 = (const float*)d_in[21];
    const float* bh1 = (const float*)d_in[22];
    const float* Wh2 = (const float*)d_in[23];
    const float* bh2 = (const float*)d_in[24];

    // workspace layout (float slots). Total ~22.23M floats = 88.9 MB.
    float* ws = (float*)d_ws;
    float* Mbuf   = ws;                   // 10.24M | encoder overlays: H0 (5.12M), H1 (+5.12M)
    float* H0     = ws;
    float* H1     = ws + 5120000;
    float* H      = ws + 10240000;        // 2.56M
    float* Zbuf   = ws + 12800000;        // 2.56M
    float* GH     = ws + 15360000;        // 2.56M
    float* Ybuf   = ws + 17920000;        // 2.56M (also hhead)
    float* hhead  = ws + 17920000;
    float* scores = ws + 20480000;        // 80000
    float* red    = ws + 20560000;        // 256
    int*   cnt    = (int*)(ws + 20560256);  // 80000 (cursor after scan3)
    int*   offs   = (int*)(ws + 20640256);  // 80064
    int*   edst   = (int*)(ws + 20720320);  // 1.28M
    int*   bsum   = (int*)(ws + 22000320);  // 320
    int*   bbase  = (int*)(ws + 22000640);  // 320
    unsigned short* w0t  = (unsigned short*)(ws + 22000960);  // 256x1024
    unsigned short* w1t  = (unsigned short*)(ws + 22132032);  // 256x256
    unsigned short* w2t  = (unsigned short*)(ws + 22164800);  // 128x256
    unsigned short* wmt[2] = {(unsigned short*)(ws + 22181184), (unsigned short*)(ws + 22189376)}; // 128x128
    unsigned short* wgt[2] = {(unsigned short*)(ws + 22197568), (unsigned short*)(ws + 22205760)}; // 128x128
    unsigned short* wh1t = (unsigned short*)(ws + 22213952);  // 128x128
    float* logits = (float*)d_out;
    float* alpha_out = (float*)d_out + N_NODES;

    dim3 blk(256);
    int egrid = (KADJ * NEDGE + 255) / 256;   // 5000
    int gM = (N_NODES + 127) / 128;           // 157

    // ---- CSR build ----
    hipMemsetAsync(cnt, 0, CSR_TOTAL * sizeof(int), stream);
    hist_kernel<<<egrid, blk, 0, stream>>>(rows, cnt);
    scan1_kernel<<<SCAN_NB, blk, 0, stream>>>(cnt, offs, bsum);
    scan2_kernel<<<1, 512, 0, stream>>>(bsum, bbase);
    scan3_kernel<<<SCAN_NB, blk, 0, stream>>>(offs, bbase, cnt);
    fill_kernel<<<egrid, blk, 0, stream>>>(rows, cols, cnt, edst);

    // ---- weight transpose+convert (fp32 [K][N] -> bf16 [N][K]) ----
    transpose_bf16_kernel<<<dim3(H_IN_/32, IN_DIM_/32), blk, 0, stream>>>(W_in0, w0t, IN_DIM_, H_IN_);
    transpose_bf16_kernel<<<dim3(H_IN_/32, H_IN_/32), blk, 0, stream>>>(W_in1, w1t, H_IN_, H_IN_);
    transpose_bf16_kernel<<<dim3(DDIM/32, H_IN_/32), blk, 0, stream>>>(W_in2, w2t, H_IN_, DDIM);
    for (int b = 0; b < 2; b++) {
        transpose_bf16_kernel<<<dim3(DDIM/32, DDIM/32), blk, 0, stream>>>(Wmsg[b], wmt[b], DDIM, DDIM);
        transpose_bf16_kernel<<<dim3(GATE_H_/32, DDIM/32), blk, 0, stream>>>(Wg1[b], wgt[b], DDIM, GATE_H_);
    }
    transpose_bf16_kernel<<<dim3(DDIM/32, DDIM/32), blk, 0, stream>>>(Wh1, wh1t, DDIM, DDIM);

    // ---- encoder ----
    mfma_gemm_kernel<<<dim3(H_IN_/128, gM), blk, 0, stream>>>(X, w0t, b_in0, H0, N_NODES, H_IN_, IN_DIM_, 1);
    mfma_gemm_kernel<<<dim3(H_IN_/128, gM), blk, 0, stream>>>(H0, w1t, b_in1, H1, N_NODES, H_IN_, H_IN_, 1);
    mfma_gemm_kernel<<<dim3(DDIM/128, gM), blk, 0, stream>>>(H1, w2t, b_in2, H, N_NODES, DDIM, H_IN_, 1);

    for (int b = 0; b < 2; b++) {
        mfma_gemm_kernel<<<dim3(DDIM/128, gM), blk, 0, stream>>>(H, wmt[b], nullptr, Zbuf, N_NODES, DDIM, DDIM, 0);
        gather_kernel<<<(KADJ * N_NODES) / 4, blk, 0, stream>>>(offs, edst, Zbuf, Mbuf);
        mfma_gemm_kernel<<<dim3(GATE_H_/128, gM), blk, 0, stream>>>(H, wgt[b], bg1[b], GH, N_NODES, GATE_H_, DDIM, 0);
        gate_kernel<<<N_NODES, 128, 0, stream>>>(Mbuf, GH, logdeg,
                                                 Wg1[b] + 128 * GATE_H_, Wg1[b] + 256 * GATE_H_,
                                                 Wg2[b], bg2[b], scores);
        float* alph = alpha_out + (size_t)b * N_NODES * KADJ;
        alpha_kernel<<<(N_NODES + 255) / 256, blk, 0, stream>>>(scores, mask, alph, N_NODES);
        fuse_kernel<<<(N_NODES * DDIM) / 256, blk, 0, stream>>>(Mbuf, alph, H, Ybuf, N_NODES);
        hipMemsetAsync(red, 0, 129 * sizeof(float), stream);
        reduce_kernel<<<512, blk, 0, stream>>>(Ybuf, red, N_NODES);
        pairnorm_kernel<<<(N_NODES + 1) / 2, blk, 0, stream>>>(Ybuf, red, H, N_NODES);
    }

    // head
    mfma_gemm_kernel<<<dim3(DDIM/128, gM), blk, 0, stream>>>(H, wh1t, bh1, hhead, N_NODES, DDIM, DDIM, 1);
    logits_kernel<<<(N_NODES * 64 + 255) / 256, blk, 0, stream>>>(hhead, Wh2, bh2, logits, N_NODES);
}

// Round 4
// 808.655 us; speedup vs baseline: 6.1452x; 1.0644x over previous
//
#include <hip/hip_runtime.h>
#include <hip/hip_bf16.h>

#define N_NODES 20000
#define KADJ 4
#define NEDGE 320000
#define IN_DIM_ 1024
#define H_IN_ 256
#define DDIM 128
#define GATE_H_ 128
#define TEMP_ 0.6f
#define M_CLAMP_ 20.0f
#define CSR_TOTAL (KADJ * N_NODES)          // 80000
#define SCAN_NB ((CSR_TOTAL + 255) / 256)   // 313

typedef __attribute__((ext_vector_type(8))) short frag_ab;      // 8 bf16
typedef __attribute__((ext_vector_type(4))) float frag_cd;      // 4 fp32
typedef __attribute__((ext_vector_type(8))) unsigned short us8;

__device__ inline unsigned short f2bf(float f) {
    unsigned int u = __float_as_uint(f);
    u += 0x7FFFu + ((u >> 16) & 1);   // RNE
    return (unsigned short)(u >> 16);
}
__device__ inline float bflo(unsigned int p) { return __uint_as_float(p << 16); }
__device__ inline float bfhi(unsigned int p) { return __uint_as_float(p & 0xffff0000u); }

// ============== bf16 MFMA GEMM: C = [relu](A[M,K]_fp32 @ (Bt[N,K]_bf16)^T + bias) ==============
// 128x128 tile, 256 threads = 4 waves, wave computes 64x64 via 4x4 frags of 16x16x32.
// A converted fp32->bf16 during LDS staging. out_bf16: store C as bf16 (ushort).
__global__ __launch_bounds__(256) void mfma_gemm_kernel(
    const float* __restrict__ A, const unsigned short* __restrict__ Bt,
    const float* __restrict__ bias, void* __restrict__ C,
    int M, int N, int K, int do_relu, int out_bf16)
{
    __shared__ unsigned short sA[128][40];   // +8 pad
    __shared__ unsigned short sB[128][40];
    int tid = threadIdx.x;
    int tileM = blockIdx.y * 128, tileN = blockIdx.x * 128;
    int w = tid >> 6, lane = tid & 63;
    int wr = (w & 1) * 64, wc = (w >> 1) * 64;
    int fm = lane & 15;      // frag row (A) / col (B) / col (C)
    int fq = lane >> 4;      // quad: k = fq*8+j (A/B), row = fq*4+r (C/D)
    int sr = tid >> 1;       // staging row 0..127
    int sh = tid & 1;        // staging k-half (16 elems)

    frag_cd acc[4][4] = {};

    for (int k0 = 0; k0 < K; k0 += 32) {
        {
            int gr = tileM + sr;
            float fv[16];
            if (gr < M) {
                const float4* ap = (const float4*)(A + (size_t)gr * K + k0 + sh * 16);
                float4 f0 = ap[0], f1 = ap[1], f2 = ap[2], f3 = ap[3];
                fv[0]=f0.x; fv[1]=f0.y; fv[2]=f0.z; fv[3]=f0.w;
                fv[4]=f1.x; fv[5]=f1.y; fv[6]=f1.z; fv[7]=f1.w;
                fv[8]=f2.x; fv[9]=f2.y; fv[10]=f2.z; fv[11]=f2.w;
                fv[12]=f3.x; fv[13]=f3.y; fv[14]=f3.z; fv[15]=f3.w;
            } else {
#pragma unroll
                for (int i = 0; i < 16; i++) fv[i] = 0.f;
            }
            us8 lo, hi;
#pragma unroll
            for (int i = 0; i < 8; i++) { lo[i] = f2bf(fv[i]); hi[i] = f2bf(fv[8 + i]); }
            *(us8*)&sA[sr][sh * 16] = lo;
            *(us8*)&sA[sr][sh * 16 + 8] = hi;
        }
        {
            const us8* bp = (const us8*)(Bt + (size_t)(tileN + sr) * K + k0 + sh * 16);
            *(us8*)&sB[sr][sh * 16] = bp[0];
            *(us8*)&sB[sr][sh * 16 + 8] = bp[1];
        }
        __syncthreads();
        frag_ab af[4], bfv[4];
#pragma unroll
        for (int i = 0; i < 4; i++) af[i] = *(const frag_ab*)&sA[wr + i * 16 + fm][fq * 8];
#pragma unroll
        for (int j = 0; j < 4; j++) bfv[j] = *(const frag_ab*)&sB[wc + j * 16 + fm][fq * 8];
#pragma unroll
        for (int i = 0; i < 4; i++)
#pragma unroll
            for (int j = 0; j < 4; j++)
                acc[i][j] = __builtin_amdgcn_mfma_f32_16x16x32_bf16(af[i], bfv[j], acc[i][j], 0, 0, 0);
        __syncthreads();
    }
#pragma unroll
    for (int i = 0; i < 4; i++) {
        int row = tileM + wr + i * 16 + fq * 4;
#pragma unroll
        for (int r = 0; r < 4; r++) {
            if (row + r < M) {
#pragma unroll
                for (int j = 0; j < 4; j++) {
                    int col = tileN + wc + j * 16 + fm;
                    float v = acc[i][j][r];
                    if (bias) v += bias[col];
                    if (do_relu) v = fmaxf(v, 0.f);
                    if (out_bf16)
                        ((unsigned short*)C)[(size_t)(row + r) * N + col] = f2bf(v);
                    else
                        ((float*)C)[(size_t)(row + r) * N + col] = v;
                }
            }
        }
    }
}

// ============== all weight transposes in ONE launch: Wt[n][k] = bf16(W[k][n]) ==========
struct TD { const float* src; unsigned short* dst; int K; int N; };
struct TD8 { TD d[8]; };

__global__ __launch_bounds__(256) void transpose_all_kernel(TD8 descs)
{
    TD t = descs.d[blockIdx.z];
    int n0 = blockIdx.x * 32, k0 = blockIdx.y * 32;
    if (n0 >= t.N || k0 >= t.K) return;
    __shared__ float tile[32][33];
    int tx = threadIdx.x & 31, ty4 = (threadIdx.x >> 5) * 4;
#pragma unroll
    for (int i = 0; i < 4; i++)
        tile[ty4 + i][tx] = t.src[(size_t)(k0 + ty4 + i) * t.N + n0 + tx];
    __syncthreads();
#pragma unroll
    for (int i = 0; i < 4; i++)
        t.dst[(size_t)(n0 + ty4 + i) * t.K + k0 + tx] = f2bf(tile[tx][ty4 + i]);
}

// ================= CSR build (once per launch) ==========
__global__ __launch_bounds__(256) void hist_kernel(
    const int* __restrict__ rows, int* __restrict__ cnt)
{
    int gid = blockIdx.x * 256 + threadIdx.x;
    if (gid >= KADJ * NEDGE) return;
    int k = gid / NEDGE;
    atomicAdd(&cnt[k * N_NODES + rows[gid]], 1);
}

__global__ __launch_bounds__(256) void scan1_kernel(
    const int* __restrict__ cnt, int* __restrict__ offs, int* __restrict__ bsum)
{
    __shared__ int s[256];
    int t = threadIdx.x, i = blockIdx.x * 256 + t;
    int v = (i < CSR_TOTAL) ? cnt[i] : 0;
    s[t] = v; __syncthreads();
    for (int d = 1; d < 256; d <<= 1) {
        int u = (t >= d) ? s[t - d] : 0; __syncthreads();
        s[t] += u; __syncthreads();
    }
    if (i < CSR_TOTAL) offs[i] = s[t] - v;
    if (t == 255) bsum[blockIdx.x] = s[255];
}

__global__ __launch_bounds__(512) void scan2_kernel(
    const int* __restrict__ bsum, int* __restrict__ bbase)
{
    __shared__ int s[512];
    int t = threadIdx.x;
    int v = (t < SCAN_NB) ? bsum[t] : 0;
    s[t] = v; __syncthreads();
    for (int d = 1; d < 512; d <<= 1) {
        int u = (t >= d) ? s[t - d] : 0; __syncthreads();
        s[t] += u; __syncthreads();
    }
    if (t < SCAN_NB) bbase[t] = s[t] - v;
}

__global__ __launch_bounds__(256) void scan3_kernel(
    int* __restrict__ offs, const int* __restrict__ bbase, int* __restrict__ cur)
{
    int i = blockIdx.x * 256 + threadIdx.x;
    if (i < CSR_TOTAL) {
        int o = offs[i] + bbase[blockIdx.x];
        offs[i] = o;
        cur[i] = o;
    }
    if (i == 0) offs[CSR_TOTAL] = KADJ * NEDGE;
}

__global__ __launch_bounds__(256) void fill_kernel(
    const int* __restrict__ rows, const int* __restrict__ cols,
    int* __restrict__ cur, int* __restrict__ edst)
{
    int gid = blockIdx.x * 256 + threadIdx.x;
    if (gid >= KADJ * NEDGE) return;
    int k = gid / NEDGE;
    int pos = atomicAdd(&cur[k * N_NODES + rows[gid]], 1);
    edst[pos] = cols[gid];
}

// ---------------- gather: M[r,k,:] = clip(sum Zb[col_e,:]) ; Zb is bf16 ----------
__global__ __launch_bounds__(256) void gather_kernel(
    const int* __restrict__ offs, const int* __restrict__ edst,
    const unsigned short* __restrict__ Zb, float* __restrict__ Mbuf)
{
    int q = blockIdx.x * 4 + (threadIdx.x >> 6);   // q = k*N + r
    int lane = threadIdx.x & 63;
    int k = q / N_NODES;
    int r = q - k * N_NODES;
    int start = offs[q];
    int end = offs[q + 1];
    float ax = 0.f, ay = 0.f;
    int i = start;
    for (; i + 3 < end; i += 4) {
        int c0 = edst[i], c1 = edst[i + 1], c2 = edst[i + 2], c3 = edst[i + 3];
        unsigned int p0 = *(const unsigned int*)(Zb + (size_t)c0 * DDIM + lane * 2);
        unsigned int p1 = *(const unsigned int*)(Zb + (size_t)c1 * DDIM + lane * 2);
        unsigned int p2 = *(const unsigned int*)(Zb + (size_t)c2 * DDIM + lane * 2);
        unsigned int p3 = *(const unsigned int*)(Zb + (size_t)c3 * DDIM + lane * 2);
        ax += bflo(p0) + bflo(p1) + bflo(p2) + bflo(p3);
        ay += bfhi(p0) + bfhi(p1) + bfhi(p2) + bfhi(p3);
    }
    for (; i < end; i++) {
        unsigned int p = *(const unsigned int*)(Zb + (size_t)edst[i] * DDIM + lane * 2);
        ax += bflo(p); ay += bfhi(p);
    }
    float2 out;
    out.x = fminf(fmaxf(ax, -M_CLAMP_), M_CLAMP_);
    out.y = fminf(fmaxf(ay, -M_CLAMP_), M_CLAMP_);
    *reinterpret_cast<float2*>(Mbuf + ((size_t)r * KADJ + k) * DDIM + lane * 2) = out;
}

// ---------------- gate: scores[n,k] = relu(GH[n] + M[n,k]@Wg1m + logdeg*wld) . Wg2 + bg2 ----
__global__ __launch_bounds__(128) void gate_kernel(
    const float* __restrict__ Mbuf, const float* __restrict__ GH,
    const float* __restrict__ logdeg, const float* __restrict__ Wg1m,
    const float* __restrict__ wld, const float* __restrict__ Wg2,
    const float* __restrict__ bg2, float* __restrict__ scores)
{
    int n = blockIdx.x;
    int j = threadIdx.x;
    __shared__ float sM[KADJ][DDIM];
#pragma unroll
    for (int k = 0; k < KADJ; k++)
        sM[k][j] = Mbuf[((size_t)n * KADJ + k) * DDIM + j];
    __syncthreads();
    float ghj = GH[(size_t)n * DDIM + j];
    float wldj = wld[j];
    float acc0 = ghj + logdeg[n * KADJ + 0] * wldj;
    float acc1 = ghj + logdeg[n * KADJ + 1] * wldj;
    float acc2 = ghj + logdeg[n * KADJ + 2] * wldj;
    float acc3 = ghj + logdeg[n * KADJ + 3] * wldj;
    for (int i = 0; i < DDIM; i++) {
        float w = Wg1m[i * GATE_H_ + j];
        acc0 += sM[0][i] * w;
        acc1 += sM[1][i] * w;
        acc2 += sM[2][i] * w;
        acc3 += sM[3][i] * w;
    }
    float g = Wg2[j];
    __shared__ float rbuf[KADJ][DDIM];
    rbuf[0][j] = fmaxf(acc0, 0.f) * g;
    rbuf[1][j] = fmaxf(acc1, 0.f) * g;
    rbuf[2][j] = fmaxf(acc2, 0.f) * g;
    rbuf[3][j] = fmaxf(acc3, 0.f) * g;
    __syncthreads();
    for (int s = 64; s > 0; s >>= 1) {
        if (j < s) {
#pragma unroll
            for (int k = 0; k < KADJ; k++) rbuf[k][j] += rbuf[k][j + s];
        }
        __syncthreads();
    }
    if (j < KADJ) scores[(size_t)n * KADJ + j] = rbuf[j][0] + bg2[0];
}

// ------- fused alpha + Y: per-thread softmax (redundant, cheap); writes Y and alpha_out -------
__global__ __launch_bounds__(256) void fuse_kernel(
    const float* __restrict__ Mbuf, const float* __restrict__ scores,
    const float* __restrict__ mask, const float* __restrict__ H,
    float* __restrict__ Y, float* __restrict__ alpha_out, int N)
{
    int idx = blockIdx.x * 256 + threadIdx.x;
    int n = idx >> 7, d = idx & 127;
    if (n >= N) return;
    float a[KADJ];
    float mx = -1e30f;
#pragma unroll
    for (int k = 0; k < KADJ; k++) {
        a[k] = scores[(size_t)n * KADJ + k] * (1.0f / TEMP_);
        mx = fmaxf(mx, a[k]);
    }
    float sum = 0.f;
#pragma unroll
    for (int k = 0; k < KADJ; k++) { a[k] = expf(a[k] - mx); sum += a[k]; }
#pragma unroll
    for (int k = 0; k < KADJ; k++) a[k] = (a[k] / sum) * mask[(size_t)n * KADJ + k];
    float s2 = 0.f;
#pragma unroll
    for (int k = 0; k < KADJ; k++) s2 += a[k];
    float inv = 1.f / fmaxf(s2, 1e-12f);
#pragma unroll
    for (int k = 0; k < KADJ; k++) a[k] = fmaxf(a[k] * inv, 1e-8f);
    s2 = 0.f;
#pragma unroll
    for (int k = 0; k < KADJ; k++) s2 += a[k];
    inv = 1.f / fmaxf(s2, 1e-12f);
#pragma unroll
    for (int k = 0; k < KADJ; k++) a[k] *= inv;

    float y = H[idx];
#pragma unroll
    for (int k = 0; k < KADJ; k++)
        y += a[k] * Mbuf[((size_t)n * KADJ + k) * DDIM + d];
    Y[idx] = y;
    if (d < KADJ) alpha_out[(size_t)n * KADJ + d] = a[d];
}

// ---------------- pairnorm reduction ----------------
__global__ __launch_bounds__(256) void reduce_kernel(
    const float* __restrict__ Y, float* __restrict__ red, int N)
{
    int tid = threadIdx.x;
    int d = tid & 127;
    int half = tid >> 7;
    float cs = 0.f, sq = 0.f;
    for (int n = blockIdx.x * 2 + half; n < N; n += gridDim.x * 2) {
        float v = Y[(size_t)n * DDIM + d];
        cs += v; sq += v * v;
    }
    __shared__ float scs[256], ssq[256];
    scs[tid] = cs; ssq[tid] = sq;
    __syncthreads();
    if (tid < 128) scs[tid] += scs[tid + 128];
    for (int s = 128; s > 0; s >>= 1) {
        if (tid < s) ssq[tid] += ssq[tid + s];
        __syncthreads();
    }
    if (tid < 128) atomicAdd(&red[tid], scs[tid]);
    if (tid == 0) atomicAdd(&red[128], ssq[0]);
}

// ---------------- pairnorm apply ----------
__global__ __launch_bounds__(256) void pairnorm_kernel(
    const float* __restrict__ Y, const float* __restrict__ red,
    float* __restrict__ Hout, int N)
{
    int tid = threadIdx.x;
    int d = tid & 127;
    float invN = 1.0f / (float)N;
    float mu = red[d] * invN;
    __shared__ float smu2[128];
    if (tid < 128) smu2[tid] = mu * mu;
    __syncthreads();
    for (int s = 64; s > 0; s >>= 1) {
        if (tid < s) smu2[tid] += smu2[tid + s];
        __syncthreads();
    }
    float summu2 = smu2[0];
    float var = red[128] * invN - summu2;
    float norm = sqrtf(fmaxf(var, 0.f)) + 1e-6f;
    float inv = 1.0f / norm;
    int n = blockIdx.x * 2 + (tid >> 7);
    if (n < N) {
        float v = (Y[(size_t)n * DDIM + d] - mu) * inv;
        Hout[(size_t)n * DDIM + d] = fmaxf(v, 0.f);
    }
}

// ---------------- logits ----------------
__global__ __launch_bounds__(256) void logits_kernel(
    const float* __restrict__ h, const float* __restrict__ Wh2,
    const float* __restrict__ bh2, float* __restrict__ out, int N)
{
    int gid = blockIdx.x * 256 + threadIdx.x;
    int n = gid >> 6;
    int lane = gid & 63;
    if (n >= N) return;
    float2 hv = *reinterpret_cast<const float2*>(h + (size_t)n * DDIM + lane * 2);
    float2 wv = *reinterpret_cast<const float2*>(Wh2 + lane * 2);
    float v = hv.x * wv.x + hv.y * wv.y;
#pragma unroll
    for (int off = 32; off > 0; off >>= 1) v += __shfl_down(v, off);
    if (lane == 0) out[n] = v + bh2[0];
}

extern "C" void kernel_launch(void* const* d_in, const int* in_sizes, int n_in,
                              void* d_out, int out_size, void* d_ws, size_t ws_size,
                              hipStream_t stream)
{
    const float* X      = (const float*)d_in[0];
    const int*   rows   = (const int*)d_in[1];
    const int*   cols   = (const int*)d_in[2];
    const float* mask   = (const float*)d_in[3];
    const float* logdeg = (const float*)d_in[4];
    const float* W_in0  = (const float*)d_in[5];
    const float* b_in0  = (const float*)d_in[6];
    const float* W_in1  = (const float*)d_in[7];
    const float* b_in1  = (const float*)d_in[8];
    const float* W_in2  = (const float*)d_in[9];
    const float* b_in2  = (const float*)d_in[10];
    const float* Wmsg[2] = {(const float*)d_in[11], (const float*)d_in[16]};
    const float* Wg1[2]  = {(const float*)d_in[12], (const float*)d_in[17]};
    const float* bg1[2]  = {(const float*)d_in[13], (const float*)d_in[18]};
    const float* Wg2[2]  = {(const float*)d_in[14], (const float*)d_in[19]};
    const float* bg2[2]  = {(const float*)d_in[15], (const float*)d_in[20]};
    const float* Wh1 = (const float*)d_in[21];
    const float* bh1 = (const float*)d_in[22];
    const float* Wh2 = (const float*)d_in[23];
    const float* bh2 = (const float*)d_in[24];

    // workspace layout (float slots). ~89 MB.
    float* ws = (float*)d_ws;
    float* Mbuf   = ws;                   // 10.24M | encoder overlays: H0 (5.12M), H1 (+5.12M)
    float* H0     = ws;
    float* H1     = ws + 5120000;
    float* H      = ws + 10240000;        // 2.56M
    unsigned short* Zb = (unsigned short*)(ws + 12800000);  // 2.56M ushort (bf16 Z)
    float* GH     = ws + 15360000;        // 2.56M
    float* Ybuf   = ws + 17920000;        // 2.56M (also hhead)
    float* hhead  = ws + 17920000;
    float* scores = ws + 20480000;        // 80000
    float* red    = ws + 20560000;        // 256
    int*   cnt    = (int*)(ws + 20560256);  // 80000 (cursor after scan3)
    int*   offs   = (int*)(ws + 20640256);  // 80064
    int*   edst   = (int*)(ws + 20720320);  // 1.28M
    int*   bsum   = (int*)(ws + 22000320);  // 320
    int*   bbase  = (int*)(ws + 22000640);  // 320
    unsigned short* w0t  = (unsigned short*)(ws + 22000960);  // 256x1024
    unsigned short* w1t  = (unsigned short*)(ws + 22132032);  // 256x256
    unsigned short* w2t  = (unsigned short*)(ws + 22164800);  // 128x256
    unsigned short* wmt[2] = {(unsigned short*)(ws + 22181184), (unsigned short*)(ws + 22189376)};
    unsigned short* wgt[2] = {(unsigned short*)(ws + 22197568), (unsigned short*)(ws + 22205760)};
    unsigned short* wh1t = (unsigned short*)(ws + 22213952);
    float* logits = (float*)d_out;
    float* alpha_out = (float*)d_out + N_NODES;

    dim3 blk(256);
    int egrid = (KADJ * NEDGE + 255) / 256;   // 5000
    int gM = (N_NODES + 127) / 128;           // 157

    // ---- CSR build ----
    hipMemsetAsync(cnt, 0, CSR_TOTAL * sizeof(int), stream);
    hist_kernel<<<egrid, blk, 0, stream>>>(rows, cnt);
    scan1_kernel<<<SCAN_NB, blk, 0, stream>>>(cnt, offs, bsum);
    scan2_kernel<<<1, 512, 0, stream>>>(bsum, bbase);
    scan3_kernel<<<SCAN_NB, blk, 0, stream>>>(offs, bbase, cnt);
    fill_kernel<<<egrid, blk, 0, stream>>>(rows, cols, cnt, edst);

    // ---- all weight transposes in one launch ----
    TD8 descs;
    descs.d[0] = {W_in0, w0t, IN_DIM_, H_IN_};
    descs.d[1] = {W_in1, w1t, H_IN_, H_IN_};
    descs.d[2] = {W_in2, w2t, H_IN_, DDIM};
    descs.d[3] = {Wmsg[0], wmt[0], DDIM, DDIM};
    descs.d[4] = {Wmsg[1], wmt[1], DDIM, DDIM};
    descs.d[5] = {Wg1[0], wgt[0], DDIM, GATE_H_};
    descs.d[6] = {Wg1[1], wgt[1], DDIM, GATE_H_};
    descs.d[7] = {Wh1, wh1t, DDIM, DDIM};
    transpose_all_kernel<<<dim3(8, 32, 8), blk, 0, stream>>>(descs);

    // ---- encoder ----
    mfma_gemm_kernel<<<dim3(H_IN_/128, gM), blk, 0, stream>>>(X, w0t, b_in0, H0, N_NODES, H_IN_, IN_DIM_, 1, 0);
    mfma_gemm_kernel<<<dim3(H_IN_/128, gM), blk, 0, stream>>>(H0, w1t, b_in1, H1, N_NODES, H_IN_, H_IN_, 1, 0);
    mfma_gemm_kernel<<<dim3(DDIM/128, gM), blk, 0, stream>>>(H1, w2t, b_in2, H, N_NODES, DDIM, H_IN_, 1, 0);

    for (int b = 0; b < 2; b++) {
        // Z = H @ Wmsg, stored bf16 for the gather
        mfma_gemm_kernel<<<dim3(DDIM/128, gM), blk, 0, stream>>>(H, wmt[b], nullptr, Zb, N_NODES, DDIM, DDIM, 0, 1);
        gather_kernel<<<(KADJ * N_NODES) / 4, blk, 0, stream>>>(offs, edst, Zb, Mbuf);
        mfma_gemm_kernel<<<dim3(GATE_H_/128, gM), blk, 0, stream>>>(H, wgt[b], bg1[b], GH, N_NODES, GATE_H_, DDIM, 0, 0);
        gate_kernel<<<N_NODES, 128, 0, stream>>>(Mbuf, GH, logdeg,
                                                 Wg1[b] + 128 * GATE_H_, Wg1[b] + 256 * GATE_H_,
                                                 Wg2[b], bg2[b], scores);
        float* alph = alpha_out + (size_t)b * N_NODES * KADJ;
        fuse_kernel<<<(N_NODES * DDIM) / 256, blk, 0, stream>>>(Mbuf, scores, mask, H, Ybuf, alph, N_NODES);
        hipMemsetAsync(red, 0, 129 * sizeof(float), stream);
        reduce_kernel<<<512, blk, 0, stream>>>(Ybuf, red, N_NODES);
        pairnorm_kernel<<<(N_NODES + 1) / 2, blk, 0, stream>>>(Ybuf, red, H, N_NODES);
    }

    // head
    mfma_gemm_kernel<<<dim3(DDIM/128, gM), blk, 0, stream>>>(H, wh1t, bh1, hhead, N_NODES, DDIM, DDIM, 1, 0);
    logits_kernel<<<(N_NODES * 64 + 255) / 256, blk, 0, stream>>>(hhead, Wh2, bh2, logits, N_NODES);
}

// Round 5
// 756.938 us; speedup vs baseline: 6.5651x; 1.0683x over previous
//
#include <hip/hip_runtime.h>
#include <hip/hip_bf16.h>

#define N_NODES 20000
#define KADJ 4
#define NEDGE 320000
#define ETOTAL (KADJ * NEDGE)               // 1,280,000
#define IN_DIM_ 1024
#define H_IN_ 256
#define DDIM 128
#define GATE_H_ 128
#define TEMP_ 0.6f
#define M_CLAMP_ 20.0f
#define CSR_TOTAL (KADJ * N_NODES)          // 80000
#define SCAN_NB ((CSR_TOTAL + 255) / 256)   // 313
#define NCOARSE 128
#define QPER (CSR_TOTAL / NCOARSE)          // 625
#define TILE_A 4096
#define BINA_NB ((ETOTAL + TILE_A - 1) / TILE_A)  // 313

typedef __attribute__((ext_vector_type(8))) short frag_ab;      // 8 bf16
typedef __attribute__((ext_vector_type(4))) float frag_cd;      // 4 fp32
typedef __attribute__((ext_vector_type(8))) unsigned short us8;

__device__ inline unsigned short f2bf(float f) {
    unsigned int u = __float_as_uint(f);
    u += 0x7FFFu + ((u >> 16) & 1);   // RNE
    return (unsigned short)(u >> 16);
}
__device__ inline float bflo(unsigned int p) { return __uint_as_float(p << 16); }
__device__ inline float bfhi(unsigned int p) { return __uint_as_float(p & 0xffff0000u); }

// ============== bf16 MFMA GEMM: C = [relu](A[M,K]_fp32 @ (Bt[N,K]_bf16)^T + bias) ==============
__global__ __launch_bounds__(256) void mfma_gemm_kernel(
    const float* __restrict__ A, const unsigned short* __restrict__ Bt,
    const float* __restrict__ bias, void* __restrict__ C,
    int M, int N, int K, int do_relu, int out_bf16)
{
    __shared__ unsigned short sA[128][40];   // +8 pad
    __shared__ unsigned short sB[128][40];
    int tid = threadIdx.x;
    int tileM = blockIdx.y * 128, tileN = blockIdx.x * 128;
    int w = tid >> 6, lane = tid & 63;
    int wr = (w & 1) * 64, wc = (w >> 1) * 64;
    int fm = lane & 15;
    int fq = lane >> 4;
    int sr = tid >> 1;
    int sh = tid & 1;

    frag_cd acc[4][4] = {};

    for (int k0 = 0; k0 < K; k0 += 32) {
        {
            int gr = tileM + sr;
            float fv[16];
            if (gr < M) {
                const float4* ap = (const float4*)(A + (size_t)gr * K + k0 + sh * 16);
                float4 f0 = ap[0], f1 = ap[1], f2 = ap[2], f3 = ap[3];
                fv[0]=f0.x; fv[1]=f0.y; fv[2]=f0.z; fv[3]=f0.w;
                fv[4]=f1.x; fv[5]=f1.y; fv[6]=f1.z; fv[7]=f1.w;
                fv[8]=f2.x; fv[9]=f2.y; fv[10]=f2.z; fv[11]=f2.w;
                fv[12]=f3.x; fv[13]=f3.y; fv[14]=f3.z; fv[15]=f3.w;
            } else {
#pragma unroll
                for (int i = 0; i < 16; i++) fv[i] = 0.f;
            }
            us8 lo, hi;
#pragma unroll
            for (int i = 0; i < 8; i++) { lo[i] = f2bf(fv[i]); hi[i] = f2bf(fv[8 + i]); }
            *(us8*)&sA[sr][sh * 16] = lo;
            *(us8*)&sA[sr][sh * 16 + 8] = hi;
        }
        {
            const us8* bp = (const us8*)(Bt + (size_t)(tileN + sr) * K + k0 + sh * 16);
            *(us8*)&sB[sr][sh * 16] = bp[0];
            *(us8*)&sB[sr][sh * 16 + 8] = bp[1];
        }
        __syncthreads();
        frag_ab af[4], bfv[4];
#pragma unroll
        for (int i = 0; i < 4; i++) af[i] = *(const frag_ab*)&sA[wr + i * 16 + fm][fq * 8];
#pragma unroll
        for (int j = 0; j < 4; j++) bfv[j] = *(const frag_ab*)&sB[wc + j * 16 + fm][fq * 8];
#pragma unroll
        for (int i = 0; i < 4; i++)
#pragma unroll
            for (int j = 0; j < 4; j++)
                acc[i][j] = __builtin_amdgcn_mfma_f32_16x16x32_bf16(af[i], bfv[j], acc[i][j], 0, 0, 0);
        __syncthreads();
    }
#pragma unroll
    for (int i = 0; i < 4; i++) {
        int row = tileM + wr + i * 16 + fq * 4;
#pragma unroll
        for (int r = 0; r < 4; r++) {
            if (row + r < M) {
#pragma unroll
                for (int j = 0; j < 4; j++) {
                    int col = tileN + wc + j * 16 + fm;
                    float v = acc[i][j][r];
                    if (bias) v += bias[col];
                    if (do_relu) v = fmaxf(v, 0.f);
                    if (out_bf16)
                        ((unsigned short*)C)[(size_t)(row + r) * N + col] = f2bf(v);
                    else
                        ((float*)C)[(size_t)(row + r) * N + col] = v;
                }
            }
        }
    }
}

// ============== all weight transposes in ONE launch ==========
struct TD { const float* src; unsigned short* dst; int K; int N; };
struct TD8 { TD d[8]; };

__global__ __launch_bounds__(256) void transpose_all_kernel(TD8 descs)
{
    TD t = descs.d[blockIdx.z];
    int n0 = blockIdx.x * 32, k0 = blockIdx.y * 32;
    if (n0 >= t.N || k0 >= t.K) return;
    __shared__ float tile[32][33];
    int tx = threadIdx.x & 31, ty4 = (threadIdx.x >> 5) * 4;
#pragma unroll
    for (int i = 0; i < 4; i++)
        tile[ty4 + i][tx] = t.src[(size_t)(k0 + ty4 + i) * t.N + n0 + tx];
    __syncthreads();
#pragma unroll
    for (int i = 0; i < 4; i++)
        t.dst[(size_t)(n0 + ty4 + i) * t.K + k0 + tx] = f2bf(tile[tx][ty4 + i]);
}

// ================= CSR build ==========
__global__ __launch_bounds__(256) void hist_kernel(
    const int* __restrict__ rows, int* __restrict__ cnt)
{
    int gid = blockIdx.x * 256 + threadIdx.x;
    if (gid >= ETOTAL) return;
    int k = gid / NEDGE;
    atomicAdd(&cnt[k * N_NODES + rows[gid]], 1);
}

__global__ __launch_bounds__(256) void scan1_kernel(
    const int* __restrict__ cnt, int* __restrict__ offs, int* __restrict__ bsum)
{
    __shared__ int s[256];
    int t = threadIdx.x, i = blockIdx.x * 256 + t;
    int v = (i < CSR_TOTAL) ? cnt[i] : 0;
    s[t] = v; __syncthreads();
    for (int d = 1; d < 256; d <<= 1) {
        int u = (t >= d) ? s[t - d] : 0; __syncthreads();
        s[t] += u; __syncthreads();
    }
    if (i < CSR_TOTAL) offs[i] = s[t] - v;
    if (t == 255) bsum[blockIdx.x] = s[255];
}

__global__ __launch_bounds__(512) void scan2_kernel(
    const int* __restrict__ bsum, int* __restrict__ bbase)
{
    __shared__ int s[512];
    int t = threadIdx.x;
    int v = (t < SCAN_NB) ? bsum[t] : 0;
    s[t] = v; __syncthreads();
    for (int d = 1; d < 512; d <<= 1) {
        int u = (t >= d) ? s[t - d] : 0; __syncthreads();
        s[t] += u; __syncthreads();
    }
    if (t < SCAN_NB) bbase[t] = s[t] - v;
}

__global__ __launch_bounds__(256) void scan3_kernel(
    int* __restrict__ offs, const int* __restrict__ bbase)
{
    int i = blockIdx.x * 256 + threadIdx.x;
    if (i < CSR_TOTAL) offs[i] += bbase[blockIdx.x];
    if (i == 0) offs[CSR_TOTAL] = ETOTAL;
}

// cur[b] = base of coarse bucket b in the edge array
__global__ __launch_bounds__(128) void init_cur_kernel(
    const int* __restrict__ offs, int* __restrict__ cur)
{
    int t = threadIdx.x;
    if (t < NCOARSE) cur[t] = offs[t * QPER];
}

// ---- binA: bucket-ordered staging of (q,c) pairs into 128 coarse buckets ----
// Per 4096-edge tile: LDS hist over coarse buckets -> LDS scan -> LDS scatter ->
// linear write-out (runs of ~32 edges per bucket => near-full-line stores).
__global__ __launch_bounds__(256) void binA_kernel(
    const int* __restrict__ rows, const int* __restrict__ cols,
    int* __restrict__ cur, uint2* __restrict__ staging)
{
    __shared__ int hist[NCOARSE], hscan[NCOARSE], lcur[NCOARSE], gbase[NCOARSE];
    __shared__ uint2 pairs[TILE_A];
    int tid = threadIdx.x;
    int base = blockIdx.x * TILE_A;
    int cnt_t = min(TILE_A, ETOTAL - base);

    for (int i = tid; i < NCOARSE; i += 256) hist[i] = 0;
    __syncthreads();

    unsigned int q[16], c[16];
    bool valid[16];
#pragma unroll
    for (int i = 0; i < 16; i++) {
        int loc = i * 256 + tid;
        valid[i] = loc < cnt_t;
        if (valid[i]) {
            int e = base + loc;
            int k = e / NEDGE;
            unsigned int qq = (unsigned int)(k * N_NODES + rows[e]);
            q[i] = qq;
            c[i] = (unsigned int)cols[e];
            atomicAdd(&hist[qq / QPER], 1);
        }
    }
    __syncthreads();
    // inclusive scan over NCOARSE, then convert to exclusive
    if (tid < NCOARSE) hscan[tid] = hist[tid];
    __syncthreads();
    for (int d = 1; d < NCOARSE; d <<= 1) {
        int v = (tid >= d && tid < NCOARSE) ? hscan[tid - d] : 0;
        __syncthreads();
        if (tid < NCOARSE) hscan[tid] += v;
        __syncthreads();
    }
    if (tid < NCOARSE) {
        int ex = hscan[tid] - hist[tid];
        hscan[tid] = ex;
        lcur[tid] = ex;
        gbase[tid] = hist[tid] ? atomicAdd(&cur[tid], hist[tid]) : 0;
    }
    __syncthreads();
#pragma unroll
    for (int i = 0; i < 16; i++) {
        if (valid[i]) {
            int b = q[i] / QPER;
            int p = atomicAdd(&lcur[b], 1);
            pairs[p] = make_uint2(q[i], c[i]);
        }
    }
    __syncthreads();
    for (int i = tid; i < cnt_t; i += 256) {
        uint2 pr = pairs[i];
        int b = pr.x / QPER;
        staging[gbase[b] + (i - hscan[b])] = pr;
    }
}

// ---- binB: block b owns q in [b*QPER,(b+1)*QPER); exact placement via offs + LDS cursor ----
// All edst writes land in one block-owned region => lines stay dirty in one L2 (no ping-pong).
__global__ __launch_bounds__(256) void binB_kernel(
    const uint2* __restrict__ staging, const int* __restrict__ offs,
    int* __restrict__ edst)
{
    __shared__ int lcur[QPER];
    int tid = threadIdx.x;
    int b = blockIdx.x;
    for (int i = tid; i < QPER; i += 256) lcur[i] = 0;
    __syncthreads();
    int q0 = b * QPER;
    int start = offs[q0], end = offs[q0 + QPER];
    for (int i = start + tid; i < end; i += 256) {
        uint2 p = staging[i];
        int pos = atomicAdd(&lcur[p.x - q0], 1);
        edst[offs[p.x] + pos] = (int)p.y;
    }
}

// ---------------- gather: M[r,k,:] = clip(sum Zb[col_e,:]) ; Zb is bf16 ----------
__global__ __launch_bounds__(256) void gather_kernel(
    const int* __restrict__ offs, const int* __restrict__ edst,
    const unsigned short* __restrict__ Zb, float* __restrict__ Mbuf)
{
    int q = blockIdx.x * 4 + (threadIdx.x >> 6);   // q = k*N + r
    int lane = threadIdx.x & 63;
    int k = q / N_NODES;
    int r = q - k * N_NODES;
    int start = offs[q];
    int end = offs[q + 1];
    float ax = 0.f, ay = 0.f;
    int i = start;
    for (; i + 3 < end; i += 4) {
        int c0 = edst[i], c1 = edst[i + 1], c2 = edst[i + 2], c3 = edst[i + 3];
        unsigned int p0 = *(const unsigned int*)(Zb + (size_t)c0 * DDIM + lane * 2);
        unsigned int p1 = *(const unsigned int*)(Zb + (size_t)c1 * DDIM + lane * 2);
        unsigned int p2 = *(const unsigned int*)(Zb + (size_t)c2 * DDIM + lane * 2);
        unsigned int p3 = *(const unsigned int*)(Zb + (size_t)c3 * DDIM + lane * 2);
        ax += bflo(p0) + bflo(p1) + bflo(p2) + bflo(p3);
        ay += bfhi(p0) + bfhi(p1) + bfhi(p2) + bfhi(p3);
    }
    for (; i < end; i++) {
        unsigned int p = *(const unsigned int*)(Zb + (size_t)edst[i] * DDIM + lane * 2);
        ax += bflo(p); ay += bfhi(p);
    }
    float2 out;
    out.x = fminf(fmaxf(ax, -M_CLAMP_), M_CLAMP_);
    out.y = fminf(fmaxf(ay, -M_CLAMP_), M_CLAMP_);
    *reinterpret_cast<float2*>(Mbuf + ((size_t)r * KADJ + k) * DDIM + lane * 2) = out;
}

// ---------------- gate ----
__global__ __launch_bounds__(128) void gate_kernel(
    const float* __restrict__ Mbuf, const float* __restrict__ GH,
    const float* __restrict__ logdeg, const float* __restrict__ Wg1m,
    const float* __restrict__ wld, const float* __restrict__ Wg2,
    const float* __restrict__ bg2, float* __restrict__ scores)
{
    int n = blockIdx.x;
    int j = threadIdx.x;
    __shared__ float sM[KADJ][DDIM];
#pragma unroll
    for (int k = 0; k < KADJ; k++)
        sM[k][j] = Mbuf[((size_t)n * KADJ + k) * DDIM + j];
    __syncthreads();
    float ghj = GH[(size_t)n * DDIM + j];
    float wldj = wld[j];
    float acc0 = ghj + logdeg[n * KADJ + 0] * wldj;
    float acc1 = ghj + logdeg[n * KADJ + 1] * wldj;
    float acc2 = ghj + logdeg[n * KADJ + 2] * wldj;
    float acc3 = ghj + logdeg[n * KADJ + 3] * wldj;
    for (int i = 0; i < DDIM; i++) {
        float w = Wg1m[i * GATE_H_ + j];
        acc0 += sM[0][i] * w;
        acc1 += sM[1][i] * w;
        acc2 += sM[2][i] * w;
        acc3 += sM[3][i] * w;
    }
    float g = Wg2[j];
    __shared__ float rbuf[KADJ][DDIM];
    rbuf[0][j] = fmaxf(acc0, 0.f) * g;
    rbuf[1][j] = fmaxf(acc1, 0.f) * g;
    rbuf[2][j] = fmaxf(acc2, 0.f) * g;
    rbuf[3][j] = fmaxf(acc3, 0.f) * g;
    __syncthreads();
    for (int s = 64; s > 0; s >>= 1) {
        if (j < s) {
#pragma unroll
            for (int k = 0; k < KADJ; k++) rbuf[k][j] += rbuf[k][j + s];
        }
        __syncthreads();
    }
    if (j < KADJ) scores[(size_t)n * KADJ + j] = rbuf[j][0] + bg2[0];
}

// ------- fused alpha + Y -------
__global__ __launch_bounds__(256) void fuse_kernel(
    const float* __restrict__ Mbuf, const float* __restrict__ scores,
    const float* __restrict__ mask, const float* __restrict__ H,
    float* __restrict__ Y, float* __restrict__ alpha_out, int N)
{
    int idx = blockIdx.x * 256 + threadIdx.x;
    int n = idx >> 7, d = idx & 127;
    if (n >= N) return;
    float a[KADJ];
    float mx = -1e30f;
#pragma unroll
    for (int k = 0; k < KADJ; k++) {
        a[k] = scores[(size_t)n * KADJ + k] * (1.0f / TEMP_);
        mx = fmaxf(mx, a[k]);
    }
    float sum = 0.f;
#pragma unroll
    for (int k = 0; k < KADJ; k++) { a[k] = expf(a[k] - mx); sum += a[k]; }
#pragma unroll
    for (int k = 0; k < KADJ; k++) a[k] = (a[k] / sum) * mask[(size_t)n * KADJ + k];
    float s2 = 0.f;
#pragma unroll
    for (int k = 0; k < KADJ; k++) s2 += a[k];
    float inv = 1.f / fmaxf(s2, 1e-12f);
#pragma unroll
    for (int k = 0; k < KADJ; k++) a[k] = fmaxf(a[k] * inv, 1e-8f);
    s2 = 0.f;
#pragma unroll
    for (int k = 0; k < KADJ; k++) s2 += a[k];
    inv = 1.f / fmaxf(s2, 1e-12f);
#pragma unroll
    for (int k = 0; k < KADJ; k++) a[k] *= inv;

    float y = H[idx];
#pragma unroll
    for (int k = 0; k < KADJ; k++)
        y += a[k] * Mbuf[((size_t)n * KADJ + k) * DDIM + d];
    Y[idx] = y;
    if (d < KADJ) alpha_out[(size_t)n * KADJ + d] = a[d];
}

// ---------------- pairnorm reduction ----------------
__global__ __launch_bounds__(256) void reduce_kernel(
    const float* __restrict__ Y, float* __restrict__ red, int N)
{
    int tid = threadIdx.x;
    int d = tid & 127;
    int half = tid >> 7;
    float cs = 0.f, sq = 0.f;
    for (int n = blockIdx.x * 2 + half; n < N; n += gridDim.x * 2) {
        float v = Y[(size_t)n * DDIM + d];
        cs += v; sq += v * v;
    }
    __shared__ float scs[256], ssq[256];
    scs[tid] = cs; ssq[tid] = sq;
    __syncthreads();
    if (tid < 128) scs[tid] += scs[tid + 128];
    for (int s = 128; s > 0; s >>= 1) {
        if (tid < s) ssq[tid] += ssq[tid + s];
        __syncthreads();
    }
    if (tid < 128) atomicAdd(&red[tid], scs[tid]);
    if (tid == 0) atomicAdd(&red[128], ssq[0]);
}

// ---------------- pairnorm apply ----------
__global__ __launch_bounds__(256) void pairnorm_kernel(
    const float* __restrict__ Y, const float* __restrict__ red,
    float* __restrict__ Hout, int N)
{
    int tid = threadIdx.x;
    int d = tid & 127;
    float invN = 1.0f / (float)N;
    float mu = red[d] * invN;
    __shared__ float smu2[128];
    if (tid < 128) smu2[tid] = mu * mu;
    __syncthreads();
    for (int s = 64; s > 0; s >>= 1) {
        if (tid < s) smu2[tid] += smu2[tid + s];
        __syncthreads();
    }
    float summu2 = smu2[0];
    float var = red[128] * invN - summu2;
    float norm = sqrtf(fmaxf(var, 0.f)) + 1e-6f;
    float inv = 1.0f / norm;
    int n = blockIdx.x * 2 + (tid >> 7);
    if (n < N) {
        float v = (Y[(size_t)n * DDIM + d] - mu) * inv;
        Hout[(size_t)n * DDIM + d] = fmaxf(v, 0.f);
    }
}

// ---------------- logits ----------------
__global__ __launch_bounds__(256) void logits_kernel(
    const float* __restrict__ h, const float* __restrict__ Wh2,
    const float* __restrict__ bh2, float* __restrict__ out, int N)
{
    int gid = blockIdx.x * 256 + threadIdx.x;
    int n = gid >> 6;
    int lane = gid & 63;
    if (n >= N) return;
    float2 hv = *reinterpret_cast<const float2*>(h + (size_t)n * DDIM + lane * 2);
    float2 wv = *reinterpret_cast<const float2*>(Wh2 + lane * 2);
    float v = hv.x * wv.x + hv.y * wv.y;
#pragma unroll
    for (int off = 32; off > 0; off >>= 1) v += __shfl_down(v, off);
    if (lane == 0) out[n] = v + bh2[0];
}

extern "C" void kernel_launch(void* const* d_in, const int* in_sizes, int n_in,
                              void* d_out, int out_size, void* d_ws, size_t ws_size,
                              hipStream_t stream)
{
    const float* X      = (const float*)d_in[0];
    const int*   rows   = (const int*)d_in[1];
    const int*   cols   = (const int*)d_in[2];
    const float* mask   = (const float*)d_in[3];
    const float* logdeg = (const float*)d_in[4];
    const float* W_in0  = (const float*)d_in[5];
    const float* b_in0  = (const float*)d_in[6];
    const float* W_in1  = (const float*)d_in[7];
    const float* b_in1  = (const float*)d_in[8];
    const float* W_in2  = (const float*)d_in[9];
    const float* b_in2  = (const float*)d_in[10];
    const float* Wmsg[2] = {(const float*)d_in[11], (const float*)d_in[16]};
    const float* Wg1[2]  = {(const float*)d_in[12], (const float*)d_in[17]};
    const float* bg1[2]  = {(const float*)d_in[13], (const float*)d_in[18]};
    const float* Wg2[2]  = {(const float*)d_in[14], (const float*)d_in[19]};
    const float* bg2[2]  = {(const float*)d_in[15], (const float*)d_in[20]};
    const float* Wh1 = (const float*)d_in[21];
    const float* bh1 = (const float*)d_in[22];
    const float* Wh2 = (const float*)d_in[23];
    const float* bh2 = (const float*)d_in[24];

    // workspace layout (float slots). ~89 MB.
    float* ws = (float*)d_ws;
    float* Mbuf   = ws;                   // 10.24M | encoder overlays: H0 (5.12M), H1 (+5.12M)
    float* H0     = ws;
    float* H1     = ws + 5120000;
    float* H      = ws + 10240000;        // 2.56M floats = 10.24MB
    uint2* staging = (uint2*)(ws + 10240000);  // aliases H: used only during CSR build (before encoder)
    unsigned short* Zb = (unsigned short*)(ws + 12800000);  // 2.56M ushort (bf16 Z)
    float* GH     = ws + 15360000;        // 2.56M
    float* Ybuf   = ws + 17920000;        // 2.56M (also hhead)
    float* hhead  = ws + 17920000;
    float* scores = ws + 20480000;        // 80000
    float* red    = ws + 20560000;        // 256
    int*   cnt    = (int*)(ws + 20560256);  // 80000
    int*   offs   = (int*)(ws + 20640256);  // 80064
    int*   edst   = (int*)(ws + 20720320);  // 1.28M
    int*   bsum   = (int*)(ws + 22000320);  // 320
    int*   bbase  = (int*)(ws + 22000640);  // 320
    int*   cur    = (int*)(ws + 22000960);  // 128 coarse-bucket cursors
    unsigned short* w0t  = (unsigned short*)(ws + 22001280);  // 256x1024
    unsigned short* w1t  = (unsigned short*)(ws + 22132352);  // 256x256
    unsigned short* w2t  = (unsigned short*)(ws + 22165120);  // 128x256
    unsigned short* wmt[2] = {(unsigned short*)(ws + 22181504), (unsigned short*)(ws + 22189696)};
    unsigned short* wgt[2] = {(unsigned short*)(ws + 22197888), (unsigned short*)(ws + 22206080)};
    unsigned short* wh1t = (unsigned short*)(ws + 22214272);
    float* logits = (float*)d_out;
    float* alpha_out = (float*)d_out + N_NODES;

    dim3 blk(256);
    int egrid = (ETOTAL + 255) / 256;   // 5000
    int gM = (N_NODES + 127) / 128;     // 157

    // ---- CSR build: hist -> scan -> coarse bin (binA) -> owned placement (binB) ----
    hipMemsetAsync(cnt, 0, CSR_TOTAL * sizeof(int), stream);
    hist_kernel<<<egrid, blk, 0, stream>>>(rows, cnt);
    scan1_kernel<<<SCAN_NB, blk, 0, stream>>>(cnt, offs, bsum);
    scan2_kernel<<<1, 512, 0, stream>>>(bsum, bbase);
    scan3_kernel<<<SCAN_NB, blk, 0, stream>>>(offs, bbase);
    init_cur_kernel<<<1, 128, 0, stream>>>(offs, cur);
    binA_kernel<<<BINA_NB, blk, 0, stream>>>(rows, cols, cur, staging);
    binB_kernel<<<NCOARSE, blk, 0, stream>>>(staging, offs, edst);

    // ---- all weight transposes in one launch ----
    TD8 descs;
    descs.d[0] = {W_in0, w0t, IN_DIM_, H_IN_};
    descs.d[1] = {W_in1, w1t, H_IN_, H_IN_};
    descs.d[2] = {W_in2, w2t, H_IN_, DDIM};
    descs.d[3] = {Wmsg[0], wmt[0], DDIM, DDIM};
    descs.d[4] = {Wmsg[1], wmt[1], DDIM, DDIM};
    descs.d[5] = {Wg1[0], wgt[0], DDIM, GATE_H_};
    descs.d[6] = {Wg1[1], wgt[1], DDIM, GATE_H_};
    descs.d[7] = {Wh1, wh1t, DDIM, DDIM};
    transpose_all_kernel<<<dim3(8, 32, 8), blk, 0, stream>>>(descs);

    // ---- encoder ----
    mfma_gemm_kernel<<<dim3(H_IN_/128, gM), blk, 0, stream>>>(X, w0t, b_in0, H0, N_NODES, H_IN_, IN_DIM_, 1, 0);
    mfma_gemm_kernel<<<dim3(H_IN_/128, gM), blk, 0, stream>>>(H0, w1t, b_in1, H1, N_NODES, H_IN_, H_IN_, 1, 0);
    mfma_gemm_kernel<<<dim3(DDIM/128, gM), blk, 0, stream>>>(H1, w2t, b_in2, H, N_NODES, DDIM, H_IN_, 1, 0);

    for (int b = 0; b < 2; b++) {
        mfma_gemm_kernel<<<dim3(DDIM/128, gM), blk, 0, stream>>>(H, wmt[b], nullptr, Zb, N_NODES, DDIM, DDIM, 0, 1);
        gather_kernel<<<(KADJ * N_NODES) / 4, blk, 0, stream>>>(offs, edst, Zb, Mbuf);
        mfma_gemm_kernel<<<dim3(GATE_H_/128, gM), blk, 0, stream>>>(H, wgt[b], bg1[b], GH, N_NODES, GATE_H_, DDIM, 0, 0);
        gate_kernel<<<N_NODES, 128, 0, stream>>>(Mbuf, GH, logdeg,
                                                 Wg1[b] + 128 * GATE_H_, Wg1[b] + 256 * GATE_H_,
                                                 Wg2[b], bg2[b], scores);
        float* alph = alpha_out + (size_t)b * N_NODES * KADJ;
        fuse_kernel<<<(N_NODES * DDIM) / 256, blk, 0, stream>>>(Mbuf, scores, mask, H, Ybuf, alph, N_NODES);
        hipMemsetAsync(red, 0, 129 * sizeof(float), stream);
        reduce_kernel<<<512, blk, 0, stream>>>(Ybuf, red, N_NODES);
        pairnorm_kernel<<<(N_NODES + 1) / 2, blk, 0, stream>>>(Ybuf, red, H, N_NODES);
    }

    // head
    mfma_gemm_kernel<<<dim3(DDIM/128, gM), blk, 0, stream>>>(H, wh1t, bh1, hhead, N_NODES, DDIM, DDIM, 1, 0);
    logits_kernel<<<(N_NODES * 64 + 255) / 256, blk, 0, stream>>>(hhead, Wh2, bh2, logits, N_NODES);
}

// Round 6
// 627.063 us; speedup vs baseline: 7.9248x; 1.2071x over previous
//
#include <hip/hip_runtime.h>
#include <hip/hip_bf16.h>

#define N_NODES 20000
#define KADJ 4
#define NEDGE 320000
#define ETOTAL (KADJ * NEDGE)               // 1,280,000
#define IN_DIM_ 1024
#define H_IN_ 256
#define DDIM 128
#define GATE_H_ 128
#define TEMP_ 0.6f
#define M_CLAMP_ 20.0f
#define CSR_TOTAL (KADJ * N_NODES)          // 80000
#define SCAN_NB ((CSR_TOTAL + 255) / 256)   // 313
#define NCOARSE 128
#define QPER (CSR_TOTAL / NCOARSE)          // 625
#define TILE_A 4096
#define BINA_NB ((ETOTAL + TILE_A - 1) / TILE_A)  // 313

typedef __attribute__((ext_vector_type(8))) short frag_ab;      // 8 bf16
typedef __attribute__((ext_vector_type(4))) float frag_cd;      // 4 fp32
typedef __attribute__((ext_vector_type(8))) unsigned short us8;

__device__ inline unsigned short f2bf(float f) {
    unsigned int u = __float_as_uint(f);
    u += 0x7FFFu + ((u >> 16) & 1);   // RNE
    return (unsigned short)(u >> 16);
}
__device__ inline float bflo(unsigned int p) { return __uint_as_float(p << 16); }
__device__ inline float bfhi(unsigned int p) { return __uint_as_float(p & 0xffff0000u); }

// async 16B global->LDS (wave-uniform LDS base + lane*16)
__device__ __forceinline__ void gld16(const unsigned short* g, unsigned short* l) {
    __builtin_amdgcn_global_load_lds(
        (const __attribute__((address_space(1))) void*)g,
        (__attribute__((address_space(3))) void*)l, 16, 0, 0);
}

// ---- X fp32 -> bf16 streaming cast ----
__global__ __launch_bounds__(256) void cast_bf16_kernel(
    const float* __restrict__ X, unsigned short* __restrict__ Xb, int n)
{
    int i = (blockIdx.x * 256 + threadIdx.x) * 8;
    if (i >= n) return;
    float4 a = *(const float4*)(X + i), b = *(const float4*)(X + i + 4);
    us8 o;
    o[0] = f2bf(a.x); o[1] = f2bf(a.y); o[2] = f2bf(a.z); o[3] = f2bf(a.w);
    o[4] = f2bf(b.x); o[5] = f2bf(b.y); o[6] = f2bf(b.z); o[7] = f2bf(b.w);
    *(us8*)(Xb + i) = o;
}

// ============== async bf16 MFMA GEMM: C = [relu](A[M,K]_bf16 @ (Bt[N,K]_bf16)^T + bias) =========
// 128x128 tile, BK=64, global_load_lds staging with XOR granule swizzle.
// LDS slot (row, gs) holds global granule gs^(row&7); frag read uses slot (g^(r&7)).
__global__ __launch_bounds__(256) void gemm_async_kernel(
    const unsigned short* __restrict__ A, const unsigned short* __restrict__ Bt,
    const float* __restrict__ bias, float* __restrict__ Cf, unsigned short* __restrict__ Cb,
    int M, int N, int K, int do_relu)
{
    __shared__ unsigned short sA[128 * 64];
    __shared__ unsigned short sB[128 * 64];
    int tid = threadIdx.x;
    int tileM = blockIdx.y * 128, tileN = blockIdx.x * 128;
    int w = tid >> 6, lane = tid & 63;
    int wr = (w & 1) * 64, wc = (w >> 1) * 64;
    int fm = lane & 15, fq = lane >> 4;
    int crow = lane >> 3;              // row within 8-row chunk
    int gsw = (lane & 7) ^ crow;       // global granule this lane fetches

    frag_cd acc[4][4] = {};

    for (int k0 = 0; k0 < K; k0 += 64) {
#pragma unroll
        for (int t = 0; t < 4; t++) {
            int chunk = w * 4 + t;
            int row = chunk * 8 + crow;
            const unsigned short* ga = A + (size_t)(tileM + row) * K + k0 + gsw * 8;
            if (tileM + row < M) gld16(ga, &sA[chunk * 512]);
            const unsigned short* gb = Bt + (size_t)(tileN + row) * K + k0 + gsw * 8;
            gld16(gb, &sB[chunk * 512]);
        }
        __syncthreads();
#pragma unroll
        for (int s = 0; s < 2; s++) {
            int sw = ((s * 4 + fq) ^ (fm & 7)) * 8;
            frag_ab af[4], bf[4];
#pragma unroll
            for (int i = 0; i < 4; i++) af[i] = *(const frag_ab*)&sA[(wr + i * 16 + fm) * 64 + sw];
#pragma unroll
            for (int j = 0; j < 4; j++) bf[j] = *(const frag_ab*)&sB[(wc + j * 16 + fm) * 64 + sw];
#pragma unroll
            for (int i = 0; i < 4; i++)
#pragma unroll
                for (int j = 0; j < 4; j++)
                    acc[i][j] = __builtin_amdgcn_mfma_f32_16x16x32_bf16(af[i], bf[j], acc[i][j], 0, 0, 0);
        }
        __syncthreads();
    }
#pragma unroll
    for (int i = 0; i < 4; i++) {
        int row = tileM + wr + i * 16 + fq * 4;
#pragma unroll
        for (int r = 0; r < 4; r++) {
            if (row + r < M) {
#pragma unroll
                for (int j = 0; j < 4; j++) {
                    int col = tileN + wc + j * 16 + fm;
                    float v = acc[i][j][r];
                    if (bias) v += bias[col];
                    if (do_relu) v = fmaxf(v, 0.f);
                    if (Cf) Cf[(size_t)(row + r) * N + col] = v;
                    if (Cb) Cb[(size_t)(row + r) * N + col] = f2bf(v);
                }
            }
        }
    }
}

// ============== gate GEMM: scores[q] = relu(Mb[q]@Wg1m + GH[q>>2] + logdeg[q]*wld) . Wg2 + bg2 ===
// M=80000 (=625 tiles exactly), K=128, N=128 (single tile col). Same staging as gemm_async.
__global__ __launch_bounds__(256) void gate_gemm_kernel(
    const unsigned short* __restrict__ Mb, const unsigned short* __restrict__ Bt,
    const float* __restrict__ GH, const float* __restrict__ logdeg,
    const float* __restrict__ wld, const float* __restrict__ Wg2,
    const float* __restrict__ bg2, float* __restrict__ scores)
{
    __shared__ unsigned short sA[128 * 64];
    __shared__ unsigned short sB[128 * 64];
    __shared__ float sred[2][128];
    int tid = threadIdx.x;
    int tile0 = blockIdx.x * 128;
    int w = tid >> 6, lane = tid & 63;
    int wr = (w & 1) * 64, wc = (w >> 1) * 64;
    int fm = lane & 15, fq = lane >> 4;
    int crow = lane >> 3;
    int gsw = (lane & 7) ^ crow;

    frag_cd acc[4][4] = {};

    for (int k0 = 0; k0 < DDIM; k0 += 64) {
#pragma unroll
        for (int t = 0; t < 4; t++) {
            int chunk = w * 4 + t;
            int row = chunk * 8 + crow;
            gld16(Mb + (size_t)(tile0 + row) * DDIM + k0 + gsw * 8, &sA[chunk * 512]);
            gld16(Bt + (size_t)row * DDIM + k0 + gsw * 8, &sB[chunk * 512]);
        }
        __syncthreads();
#pragma unroll
        for (int s = 0; s < 2; s++) {
            int sw = ((s * 4 + fq) ^ (fm & 7)) * 8;
            frag_ab af[4], bf[4];
#pragma unroll
            for (int i = 0; i < 4; i++) af[i] = *(const frag_ab*)&sA[(wr + i * 16 + fm) * 64 + sw];
#pragma unroll
            for (int j = 0; j < 4; j++) bf[j] = *(const frag_ab*)&sB[(wc + j * 16 + fm) * 64 + sw];
#pragma unroll
            for (int i = 0; i < 4; i++)
#pragma unroll
                for (int j = 0; j < 4; j++)
                    acc[i][j] = __builtin_amdgcn_mfma_f32_16x16x32_bf16(af[i], bf[j], acc[i][j], 0, 0, 0);
        }
        __syncthreads();
    }
    // epilogue: add GH + logdeg*wld, relu, dot Wg2, block-reduce to scores
    float wg2v[4], wldv[4];
#pragma unroll
    for (int j = 0; j < 4; j++) {
        int c = wc + j * 16 + fm;
        wg2v[j] = Wg2[c];
        wldv[j] = wld[c];
    }
    float part[4][4];
#pragma unroll
    for (int i = 0; i < 4; i++) {
#pragma unroll
        for (int r = 0; r < 4; r++) {
            int q = tile0 + wr + i * 16 + fq * 4 + r;
            int n = q >> 2;
            float ld = logdeg[q];
            float p = 0.f;
#pragma unroll
            for (int j = 0; j < 4; j++) {
                int c = wc + j * 16 + fm;
                float v = acc[i][j][r] + GH[(size_t)n * GATE_H_ + c] + ld * wldv[j];
                p += fmaxf(v, 0.f) * wg2v[j];
            }
            part[i][r] = p;
        }
    }
#pragma unroll
    for (int m = 1; m < 16; m <<= 1)
#pragma unroll
        for (int i = 0; i < 4; i++)
#pragma unroll
            for (int r = 0; r < 4; r++)
                part[i][r] += __shfl_xor(part[i][r], m, 64);
    if (fm == 0) {
#pragma unroll
        for (int i = 0; i < 4; i++)
#pragma unroll
            for (int r = 0; r < 4; r++)
                sred[w >> 1][wr + i * 16 + fq * 4 + r] = part[i][r];
    }
    __syncthreads();
    if (tid < 128) scores[tile0 + tid] = sred[0][tid] + sred[1][tid] + bg2[0];
}

// ============== all weight transposes in ONE launch ==========
struct TD { const float* src; unsigned short* dst; int K; int N; };
struct TD10 { TD d[10]; };

__global__ __launch_bounds__(256) void transpose_all_kernel(TD10 descs)
{
    TD t = descs.d[blockIdx.z];
    int n0 = blockIdx.x * 32, k0 = blockIdx.y * 32;
    if (n0 >= t.N || k0 >= t.K) return;
    __shared__ float tile[32][33];
    int tx = threadIdx.x & 31, ty4 = (threadIdx.x >> 5) * 4;
#pragma unroll
    for (int i = 0; i < 4; i++)
        tile[ty4 + i][tx] = t.src[(size_t)(k0 + ty4 + i) * t.N + n0 + tx];
    __syncthreads();
#pragma unroll
    for (int i = 0; i < 4; i++)
        t.dst[(size_t)(n0 + ty4 + i) * t.K + k0 + tx] = f2bf(tile[tx][ty4 + i]);
}

// ================= CSR build ==========
__global__ __launch_bounds__(256) void hist_kernel(
    const int* __restrict__ rows, int* __restrict__ cnt)
{
    int gid = blockIdx.x * 256 + threadIdx.x;
    if (gid >= ETOTAL) return;
    int k = gid / NEDGE;
    atomicAdd(&cnt[k * N_NODES + rows[gid]], 1);
}

__global__ __launch_bounds__(256) void scan1_kernel(
    const int* __restrict__ cnt, int* __restrict__ offs, int* __restrict__ bsum)
{
    __shared__ int s[256];
    int t = threadIdx.x, i = blockIdx.x * 256 + t;
    int v = (i < CSR_TOTAL) ? cnt[i] : 0;
    s[t] = v; __syncthreads();
    for (int d = 1; d < 256; d <<= 1) {
        int u = (t >= d) ? s[t - d] : 0; __syncthreads();
        s[t] += u; __syncthreads();
    }
    if (i < CSR_TOTAL) offs[i] = s[t] - v;
    if (t == 255) bsum[blockIdx.x] = s[255];
}

__global__ __launch_bounds__(512) void scan2_kernel(
    const int* __restrict__ bsum, int* __restrict__ bbase)
{
    __shared__ int s[512];
    int t = threadIdx.x;
    int v = (t < SCAN_NB) ? bsum[t] : 0;
    s[t] = v; __syncthreads();
    for (int d = 1; d < 512; d <<= 1) {
        int u = (t >= d) ? s[t - d] : 0; __syncthreads();
        s[t] += u; __syncthreads();
    }
    if (t < SCAN_NB) bbase[t] = s[t] - v;
}

__global__ __launch_bounds__(256) void scan3_kernel(
    int* __restrict__ offs, const int* __restrict__ bbase)
{
    int i = blockIdx.x * 256 + threadIdx.x;
    if (i < CSR_TOTAL) offs[i] += bbase[blockIdx.x];
    if (i == 0) offs[CSR_TOTAL] = ETOTAL;
}

__global__ __launch_bounds__(128) void init_cur_kernel(
    const int* __restrict__ offs, int* __restrict__ cur)
{
    int t = threadIdx.x;
    if (t < NCOARSE) cur[t] = offs[t * QPER];
}

// ---- binA: bucket-ordered staging of (q,c) pairs into 128 coarse buckets ----
__global__ __launch_bounds__(256) void binA_kernel(
    const int* __restrict__ rows, const int* __restrict__ cols,
    int* __restrict__ cur, uint2* __restrict__ staging)
{
    __shared__ int hist[NCOARSE], hscan[NCOARSE], lcur[NCOARSE], gbase[NCOARSE];
    __shared__ uint2 pairs[TILE_A];
    int tid = threadIdx.x;
    int base = blockIdx.x * TILE_A;
    int cnt_t = min(TILE_A, ETOTAL - base);

    for (int i = tid; i < NCOARSE; i += 256) hist[i] = 0;
    __syncthreads();

    unsigned int q[16], c[16];
    bool valid[16];
#pragma unroll
    for (int i = 0; i < 16; i++) {
        int loc = i * 256 + tid;
        valid[i] = loc < cnt_t;
        if (valid[i]) {
            int e = base + loc;
            int k = e / NEDGE;
            unsigned int qq = (unsigned int)(k * N_NODES + rows[e]);
            q[i] = qq;
            c[i] = (unsigned int)cols[e];
            atomicAdd(&hist[qq / QPER], 1);
        }
    }
    __syncthreads();
    if (tid < NCOARSE) hscan[tid] = hist[tid];
    __syncthreads();
    for (int d = 1; d < NCOARSE; d <<= 1) {
        int v = (tid >= d && tid < NCOARSE) ? hscan[tid - d] : 0;
        __syncthreads();
        if (tid < NCOARSE) hscan[tid] += v;
        __syncthreads();
    }
    if (tid < NCOARSE) {
        int ex = hscan[tid] - hist[tid];
        hscan[tid] = ex;
        lcur[tid] = ex;
        gbase[tid] = hist[tid] ? atomicAdd(&cur[tid], hist[tid]) : 0;
    }
    __syncthreads();
#pragma unroll
    for (int i = 0; i < 16; i++) {
        if (valid[i]) {
            int b = q[i] / QPER;
            int p = atomicAdd(&lcur[b], 1);
            pairs[p] = make_uint2(q[i], c[i]);
        }
    }
    __syncthreads();
    for (int i = tid; i < cnt_t; i += 256) {
        uint2 pr = pairs[i];
        int b = pr.x / QPER;
        staging[gbase[b] + (i - hscan[b])] = pr;
    }
}

// ---- binB: block b owns q in [b*QPER,(b+1)*QPER) ----
__global__ __launch_bounds__(256) void binB_kernel(
    const uint2* __restrict__ staging, const int* __restrict__ offs,
    int* __restrict__ edst)
{
    __shared__ int lcur[QPER];
    int tid = threadIdx.x;
    int b = blockIdx.x;
    for (int i = tid; i < QPER; i += 256) lcur[i] = 0;
    __syncthreads();
    int q0 = b * QPER;
    int start = offs[q0], end = offs[q0 + QPER];
    for (int i = start + tid; i < end; i += 256) {
        uint2 p = staging[i];
        int pos = atomicAdd(&lcur[p.x - q0], 1);
        edst[offs[p.x] + pos] = (int)p.y;
    }
}

// ---------------- gather: Mb[q,:] = bf16(clip(sum Zb[col_e,:])) ----------
__global__ __launch_bounds__(256) void gather_kernel(
    const int* __restrict__ offs, const int* __restrict__ edst,
    const unsigned short* __restrict__ Zb, unsigned short* __restrict__ Mb)
{
    int q = blockIdx.x * 4 + (threadIdx.x >> 6);   // q = k*N + r
    int lane = threadIdx.x & 63;
    int k = q / N_NODES;
    int r = q - k * N_NODES;
    int start = offs[q];
    int end = offs[q + 1];
    float ax = 0.f, ay = 0.f;
    int i = start;
    for (; i + 3 < end; i += 4) {
        int c0 = edst[i], c1 = edst[i + 1], c2 = edst[i + 2], c3 = edst[i + 3];
        unsigned int p0 = *(const unsigned int*)(Zb + (size_t)c0 * DDIM + lane * 2);
        unsigned int p1 = *(const unsigned int*)(Zb + (size_t)c1 * DDIM + lane * 2);
        unsigned int p2 = *(const unsigned int*)(Zb + (size_t)c2 * DDIM + lane * 2);
        unsigned int p3 = *(const unsigned int*)(Zb + (size_t)c3 * DDIM + lane * 2);
        ax += bflo(p0) + bflo(p1) + bflo(p2) + bflo(p3);
        ay += bfhi(p0) + bfhi(p1) + bfhi(p2) + bfhi(p3);
    }
    for (; i < end; i++) {
        unsigned int p = *(const unsigned int*)(Zb + (size_t)edst[i] * DDIM + lane * 2);
        ax += bflo(p); ay += bfhi(p);
    }
    ax = fminf(fmaxf(ax, -M_CLAMP_), M_CLAMP_);
    ay = fminf(fmaxf(ay, -M_CLAMP_), M_CLAMP_);
    unsigned int pk = (unsigned int)f2bf(ax) | ((unsigned int)f2bf(ay) << 16);
    // Mb row index = r*KADJ + k
    *(unsigned int*)(Mb + ((size_t)r * KADJ + k) * DDIM + lane * 2) = pk;
}

// ------- fused alpha + Y: Y = H + sum_k alpha*Mb; 2 elems/thread -------
__global__ __launch_bounds__(256) void fuse_kernel(
    const unsigned short* __restrict__ Mb, const float* __restrict__ scores,
    const float* __restrict__ mask, const float* __restrict__ H,
    float* __restrict__ Y, float* __restrict__ alpha_out, int N)
{
    int gid = blockIdx.x * 256 + threadIdx.x;
    int n = gid >> 6, dd = (gid & 63) * 2;
    if (n >= N) return;
    float a[KADJ];
    float mx = -1e30f;
#pragma unroll
    for (int k = 0; k < KADJ; k++) {
        a[k] = scores[(size_t)n * KADJ + k] * (1.0f / TEMP_);
        mx = fmaxf(mx, a[k]);
    }
    float sum = 0.f;
#pragma unroll
    for (int k = 0; k < KADJ; k++) { a[k] = expf(a[k] - mx); sum += a[k]; }
#pragma unroll
    for (int k = 0; k < KADJ; k++) a[k] = (a[k] / sum) * mask[(size_t)n * KADJ + k];
    float s2 = 0.f;
#pragma unroll
    for (int k = 0; k < KADJ; k++) s2 += a[k];
    float inv = 1.f / fmaxf(s2, 1e-12f);
#pragma unroll
    for (int k = 0; k < KADJ; k++) a[k] = fmaxf(a[k] * inv, 1e-8f);
    s2 = 0.f;
#pragma unroll
    for (int k = 0; k < KADJ; k++) s2 += a[k];
    inv = 1.f / fmaxf(s2, 1e-12f);
#pragma unroll
    for (int k = 0; k < KADJ; k++) a[k] *= inv;

    float2 h = *(const float2*)(H + (size_t)n * DDIM + dd);
    float yx = h.x, yy = h.y;
#pragma unroll
    for (int k = 0; k < KADJ; k++) {
        unsigned int u = *(const unsigned int*)(Mb + ((size_t)n * KADJ + k) * DDIM + dd);
        yx += a[k] * bflo(u);
        yy += a[k] * bfhi(u);
    }
    *(float2*)(Y + (size_t)n * DDIM + dd) = make_float2(yx, yy);
    int j = gid & 63;
    if (j < KADJ) alpha_out[(size_t)n * KADJ + j] = a[j];
}

// ---------------- pairnorm reduction ----------------
__global__ __launch_bounds__(256) void reduce_kernel(
    const float* __restrict__ Y, float* __restrict__ red, int N)
{
    int tid = threadIdx.x;
    int d = tid & 127;
    int half = tid >> 7;
    float cs = 0.f, sq = 0.f;
    for (int n = blockIdx.x * 2 + half; n < N; n += gridDim.x * 2) {
        float v = Y[(size_t)n * DDIM + d];
        cs += v; sq += v * v;
    }
    __shared__ float scs[256], ssq[256];
    scs[tid] = cs; ssq[tid] = sq;
    __syncthreads();
    if (tid < 128) scs[tid] += scs[tid + 128];
    for (int s = 128; s > 0; s >>= 1) {
        if (tid < s) ssq[tid] += ssq[tid + s];
        __syncthreads();
    }
    if (tid < 128) atomicAdd(&red[tid], scs[tid]);
    if (tid == 0) atomicAdd(&red[128], ssq[0]);
}

// ---------------- pairnorm apply: writes H fp32 + Hb bf16 ----------
__global__ __launch_bounds__(256) void pairnorm_kernel(
    const float* __restrict__ Y, const float* __restrict__ red,
    float* __restrict__ Hout, unsigned short* __restrict__ Hb, int N)
{
    int tid = threadIdx.x;
    int d = tid & 127;
    float invN = 1.0f / (float)N;
    float mu = red[d] * invN;
    __shared__ float smu2[128];
    if (tid < 128) smu2[tid] = mu * mu;
    __syncthreads();
    for (int s = 64; s > 0; s >>= 1) {
        if (tid < s) smu2[tid] += smu2[tid + s];
        __syncthreads();
    }
    float summu2 = smu2[0];
    float var = red[128] * invN - summu2;
    float norm = sqrtf(fmaxf(var, 0.f)) + 1e-6f;
    float inv = 1.0f / norm;
    int n = blockIdx.x * 2 + (tid >> 7);
    if (n < N) {
        float v = (Y[(size_t)n * DDIM + d] - mu) * inv;
        v = fmaxf(v, 0.f);
        Hout[(size_t)n * DDIM + d] = v;
        Hb[(size_t)n * DDIM + d] = f2bf(v);
    }
}

// ---------------- logits ----------------
__global__ __launch_bounds__(256) void logits_kernel(
    const float* __restrict__ h, const float* __restrict__ Wh2,
    const float* __restrict__ bh2, float* __restrict__ out, int N)
{
    int gid = blockIdx.x * 256 + threadIdx.x;
    int n = gid >> 6;
    int lane = gid & 63;
    if (n >= N) return;
    float2 hv = *reinterpret_cast<const float2*>(h + (size_t)n * DDIM + lane * 2);
    float2 wv = *reinterpret_cast<const float2*>(Wh2 + lane * 2);
    float v = hv.x * wv.x + hv.y * wv.y;
#pragma unroll
    for (int off = 32; off > 0; off >>= 1) v += __shfl_down(v, off);
    if (lane == 0) out[n] = v + bh2[0];
}

extern "C" void kernel_launch(void* const* d_in, const int* in_sizes, int n_in,
                              void* d_out, int out_size, void* d_ws, size_t ws_size,
                              hipStream_t stream)
{
    const float* X      = (const float*)d_in[0];
    const int*   rows   = (const int*)d_in[1];
    const int*   cols   = (const int*)d_in[2];
    const float* mask   = (const float*)d_in[3];
    const float* logdeg = (const float*)d_in[4];
    const float* W_in0  = (const float*)d_in[5];
    const float* b_in0  = (const float*)d_in[6];
    const float* W_in1  = (const float*)d_in[7];
    const float* b_in1  = (const float*)d_in[8];
    const float* W_in2  = (const float*)d_in[9];
    const float* b_in2  = (const float*)d_in[10];
    const float* Wmsg[2] = {(const float*)d_in[11], (const float*)d_in[16]};
    const float* Wg1[2]  = {(const float*)d_in[12], (const float*)d_in[17]};
    const float* bg1[2]  = {(const float*)d_in[13], (const float*)d_in[18]};
    const float* Wg2[2]  = {(const float*)d_in[14], (const float*)d_in[19]};
    const float* bg2[2]  = {(const float*)d_in[15], (const float*)d_in[20]};
    const float* Wh1 = (const float*)d_in[21];
    const float* bh1 = (const float*)d_in[22];
    const float* Wh2 = (const float*)d_in[23];
    const float* bh2 = (const float*)d_in[24];

    // workspace layout (float slots), total ~83.5 MB:
    // R1 [0,10.24M): encoder Xb (10.24M) | loop: Mb bf16 (5.12M) + Ybuf/hhead (2.56M @5.12M) + GH (2.56M @7.68M)
    // R2 [10.24M,15.36M): CSR staging (2.56M) -> H0b (2.56M @10.24M), H1b (2.56M @12.8M) -> Zb (1.28M @12.8M)
    float* ws = (float*)d_ws;
    unsigned short* Xb  = (unsigned short*)ws;
    unsigned short* Mb  = (unsigned short*)ws;
    float* Ybuf  = ws + 5120000;
    float* hhead = ws + 5120000;
    float* GH    = ws + 7680000;
    uint2* staging = (uint2*)(ws + 10240000);
    unsigned short* H0b = (unsigned short*)(ws + 10240000);
    unsigned short* H1b = (unsigned short*)(ws + 12800000);
    unsigned short* Zb  = (unsigned short*)(ws + 12800000);
    float* H     = ws + 15360000;         // 2.56M
    unsigned short* Hb = (unsigned short*)(ws + 17920000);  // 1.28M slots
    int*   cnt    = (int*)(ws + 19200000);  // 80000 | scores overlays (written after CSR done)
    float* scores = ws + 19200000;
    int*   offs   = (int*)(ws + 19280128);  // 80064
    int*   edst   = (int*)(ws + 19360256);  // 1.28M
    float* red    = ws + 20640256;          // 256
    int*   bsum   = (int*)(ws + 20640512);  // 320
    int*   bbase  = (int*)(ws + 20640832);  // 320
    int*   cur    = (int*)(ws + 20641152);  // 128
    unsigned short* w0t  = (unsigned short*)(ws + 20641280);  // 131072 slots
    unsigned short* w1t  = (unsigned short*)(ws + 20772352);  // 32768
    unsigned short* w2t  = (unsigned short*)(ws + 20805120);  // 16384
    unsigned short* wmt[2]  = {(unsigned short*)(ws + 20821504), (unsigned short*)(ws + 20829696)};
    unsigned short* wgt[2]  = {(unsigned short*)(ws + 20837888), (unsigned short*)(ws + 20846080)};
    unsigned short* wgmt[2] = {(unsigned short*)(ws + 20854272), (unsigned short*)(ws + 20862464)};
    unsigned short* wh1t = (unsigned short*)(ws + 20870656);
    float* logits = (float*)d_out;
    float* alpha_out = (float*)d_out + N_NODES;

    dim3 blk(256);
    int egrid = (ETOTAL + 255) / 256;   // 5000
    int gM = (N_NODES + 127) / 128;     // 157

    // ---- CSR build ----
    hipMemsetAsync(cnt, 0, CSR_TOTAL * sizeof(int), stream);
    hist_kernel<<<egrid, blk, 0, stream>>>(rows, cnt);
    scan1_kernel<<<SCAN_NB, blk, 0, stream>>>(cnt, offs, bsum);
    scan2_kernel<<<1, 512, 0, stream>>>(bsum, bbase);
    scan3_kernel<<<SCAN_NB, blk, 0, stream>>>(offs, bbase);
    init_cur_kernel<<<1, 128, 0, stream>>>(offs, cur);
    binA_kernel<<<BINA_NB, blk, 0, stream>>>(rows, cols, cur, staging);
    binB_kernel<<<NCOARSE, blk, 0, stream>>>(staging, offs, edst);

    // ---- weight transposes + X cast ----
    TD10 descs;
    descs.d[0] = {W_in0, w0t, IN_DIM_, H_IN_};
    descs.d[1] = {W_in1, w1t, H_IN_, H_IN_};
    descs.d[2] = {W_in2, w2t, H_IN_, DDIM};
    descs.d[3] = {Wmsg[0], wmt[0], DDIM, DDIM};
    descs.d[4] = {Wmsg[1], wmt[1], DDIM, DDIM};
    descs.d[5] = {Wg1[0], wgt[0], DDIM, GATE_H_};
    descs.d[6] = {Wg1[1], wgt[1], DDIM, GATE_H_};
    descs.d[7] = {Wg1[0] + DDIM * GATE_H_, wgmt[0], DDIM, GATE_H_};
    descs.d[8] = {Wg1[1] + DDIM * GATE_H_, wgmt[1], DDIM, GATE_H_};
    descs.d[9] = {Wh1, wh1t, DDIM, DDIM};
    transpose_all_kernel<<<dim3(8, 32, 10), blk, 0, stream>>>(descs);
    cast_bf16_kernel<<<N_NODES * IN_DIM_ / 8 / 256, blk, 0, stream>>>(X, Xb, N_NODES * IN_DIM_);

    // ---- encoder ----
    gemm_async_kernel<<<dim3(2, gM), blk, 0, stream>>>(Xb, w0t, b_in0, nullptr, H0b, N_NODES, H_IN_, IN_DIM_, 1);
    gemm_async_kernel<<<dim3(2, gM), blk, 0, stream>>>(H0b, w1t, b_in1, nullptr, H1b, N_NODES, H_IN_, H_IN_, 1);
    gemm_async_kernel<<<dim3(1, gM), blk, 0, stream>>>(H1b, w2t, b_in2, H, Hb, N_NODES, DDIM, H_IN_, 1);

    for (int b = 0; b < 2; b++) {
        gemm_async_kernel<<<dim3(1, gM), blk, 0, stream>>>(Hb, wmt[b], nullptr, nullptr, Zb, N_NODES, DDIM, DDIM, 0);
        gather_kernel<<<CSR_TOTAL / 4, blk, 0, stream>>>(offs, edst, Zb, Mb);
        gemm_async_kernel<<<dim3(1, gM), blk, 0, stream>>>(Hb, wgt[b], bg1[b], GH, nullptr, N_NODES, GATE_H_, DDIM, 0);
        gate_gemm_kernel<<<CSR_TOTAL / 128, blk, 0, stream>>>(Mb, wgmt[b], GH, logdeg,
                                                              Wg1[b] + 256 * GATE_H_, Wg2[b], bg2[b], scores);
        float* alph = alpha_out + (size_t)b * N_NODES * KADJ;
        fuse_kernel<<<(N_NODES * 64) / 256, blk, 0, stream>>>(Mb, scores, mask, H, Ybuf, alph, N_NODES);
        hipMemsetAsync(red, 0, 129 * sizeof(float), stream);
        reduce_kernel<<<512, blk, 0, stream>>>(Ybuf, red, N_NODES);
        pairnorm_kernel<<<(N_NODES + 1) / 2, blk, 0, stream>>>(Ybuf, red, H, Hb, N_NODES);
    }

    // head
    gemm_async_kernel<<<dim3(1, gM), blk, 0, stream>>>(Hb, wh1t, bh1, hhead, nullptr, N_NODES, DDIM, DDIM, 1);
    logits_kernel<<<(N_NODES * 64 + 255) / 256, blk, 0, stream>>>(hhead, Wh2, bh2, logits, N_NODES);
}

// Round 8
// 567.675 us; speedup vs baseline: 8.7539x; 1.1046x over previous
//
#include <hip/hip_runtime.h>
#include <hip/hip_bf16.h>

#define N_NODES 20000
#define KADJ 4
#define NEDGE 320000
#define ETOTAL (KADJ * NEDGE)               // 1,280,000
#define IN_DIM_ 1024
#define H_IN_ 256
#define DDIM 128
#define GATE_H_ 128
#define TEMP_ 0.6f
#define M_CLAMP_ 20.0f
#define CSR_TOTAL (KADJ * N_NODES)          // 80000
#define NCOARSE 128
#define QPER (CSR_TOTAL / NCOARSE)          // 625
#define ESTRIDE 12288                       // bucket slot stride (exp fill 10000, sigma~100)
#define TILE_A 4096
#define BINA_NB ((ETOTAL + TILE_A - 1) / TILE_A)  // 313

typedef __attribute__((ext_vector_type(8))) short frag_ab;      // 8 bf16
typedef __attribute__((ext_vector_type(4))) float frag_cd;      // 4 fp32
typedef __attribute__((ext_vector_type(8))) unsigned short us8;

__device__ inline unsigned short f2bf(float f) {
    unsigned int u = __float_as_uint(f);
    u += 0x7FFFu + ((u >> 16) & 1);   // RNE
    return (unsigned short)(u >> 16);
}
__device__ inline float bflo(unsigned int p) { return __uint_as_float(p << 16); }
__device__ inline float bfhi(unsigned int p) { return __uint_as_float(p & 0xffff0000u); }

// async 16B global->LDS (wave-uniform LDS base + lane*16)
__device__ __forceinline__ void gld16(const unsigned short* g, unsigned short* l) {
    __builtin_amdgcn_global_load_lds(
        (const __attribute__((address_space(1))) void*)g,
        (__attribute__((address_space(3))) void*)l, 16, 0, 0);
}

// ---- X fp32 -> bf16 streaming cast ----
__global__ __launch_bounds__(256) void cast_bf16_kernel(
    const float* __restrict__ X, unsigned short* __restrict__ Xb, int n)
{
    int i = (blockIdx.x * 256 + threadIdx.x) * 8;
    if (i >= n) return;
    float4 a = *(const float4*)(X + i), b = *(const float4*)(X + i + 4);
    us8 o;
    o[0] = f2bf(a.x); o[1] = f2bf(a.y); o[2] = f2bf(a.z); o[3] = f2bf(a.w);
    o[4] = f2bf(b.x); o[5] = f2bf(b.y); o[6] = f2bf(b.z); o[7] = f2bf(b.w);
    *(us8*)(Xb + i) = o;
}

// ============== async bf16 MFMA GEMM: C = [relu](A[M,K]_bf16 @ (Bt[N,K]_bf16)^T + bias) =========
__global__ __launch_bounds__(256) void gemm_async_kernel(
    const unsigned short* __restrict__ A, const unsigned short* __restrict__ Bt,
    const float* __restrict__ bias, float* __restrict__ Cf, unsigned short* __restrict__ Cb,
    int M, int N, int K, int do_relu)
{
    __shared__ unsigned short sA[128 * 64];
    __shared__ unsigned short sB[128 * 64];
    int tid = threadIdx.x;
    int tileM = blockIdx.y * 128, tileN = blockIdx.x * 128;
    int w = tid >> 6, lane = tid & 63;
    int wr = (w & 1) * 64, wc = (w >> 1) * 64;
    int fm = lane & 15, fq = lane >> 4;
    int crow = lane >> 3;              // row within 8-row chunk
    int gsw = (lane & 7) ^ crow;       // global granule this lane fetches

    frag_cd acc[4][4] = {};

    for (int k0 = 0; k0 < K; k0 += 64) {
#pragma unroll
        for (int t = 0; t < 4; t++) {
            int chunk = w * 4 + t;
            int row = chunk * 8 + crow;
            const unsigned short* ga = A + (size_t)(tileM + row) * K + k0 + gsw * 8;
            if (tileM + row < M) gld16(ga, &sA[chunk * 512]);
            const unsigned short* gb = Bt + (size_t)(tileN + row) * K + k0 + gsw * 8;
            gld16(gb, &sB[chunk * 512]);
        }
        __syncthreads();
#pragma unroll
        for (int s = 0; s < 2; s++) {
            int sw = ((s * 4 + fq) ^ (fm & 7)) * 8;
            frag_ab af[4], bf[4];
#pragma unroll
            for (int i = 0; i < 4; i++) af[i] = *(const frag_ab*)&sA[(wr + i * 16 + fm) * 64 + sw];
#pragma unroll
            for (int j = 0; j < 4; j++) bf[j] = *(const frag_ab*)&sB[(wc + j * 16 + fm) * 64 + sw];
#pragma unroll
            for (int i = 0; i < 4; i++)
#pragma unroll
                for (int j = 0; j < 4; j++)
                    acc[i][j] = __builtin_amdgcn_mfma_f32_16x16x32_bf16(af[i], bf[j], acc[i][j], 0, 0, 0);
        }
        __syncthreads();
    }
#pragma unroll
    for (int i = 0; i < 4; i++) {
        int row = tileM + wr + i * 16 + fq * 4;
#pragma unroll
        for (int r = 0; r < 4; r++) {
            if (row + r < M) {
#pragma unroll
                for (int j = 0; j < 4; j++) {
                    int col = tileN + wc + j * 16 + fm;
                    float v = acc[i][j][r];
                    if (bias) v += bias[col];
                    if (do_relu) v = fmaxf(v, 0.f);
                    if (Cf) Cf[(size_t)(row + r) * N + col] = v;
                    if (Cb) Cb[(size_t)(row + r) * N + col] = f2bf(v);
                }
            }
        }
    }
}

// ============== gate GEMM: scores[q] = relu(Mb[q]@Wg1m + GH[q>>2] + logdeg[q]*wld) . Wg2 + bg2 ===
__global__ __launch_bounds__(256) void gate_gemm_kernel(
    const unsigned short* __restrict__ Mb, const unsigned short* __restrict__ Bt,
    const float* __restrict__ GH, const float* __restrict__ logdeg,
    const float* __restrict__ wld, const float* __restrict__ Wg2,
    const float* __restrict__ bg2, float* __restrict__ scores)
{
    __shared__ unsigned short sA[128 * 64];
    __shared__ unsigned short sB[128 * 64];
    __shared__ float sred[2][128];
    int tid = threadIdx.x;
    int tile0 = blockIdx.x * 128;
    int w = tid >> 6, lane = tid & 63;
    int wr = (w & 1) * 64, wc = (w >> 1) * 64;
    int fm = lane & 15, fq = lane >> 4;
    int crow = lane >> 3;
    int gsw = (lane & 7) ^ crow;

    frag_cd acc[4][4] = {};

    for (int k0 = 0; k0 < DDIM; k0 += 64) {
#pragma unroll
        for (int t = 0; t < 4; t++) {
            int chunk = w * 4 + t;
            int row = chunk * 8 + crow;
            gld16(Mb + (size_t)(tile0 + row) * DDIM + k0 + gsw * 8, &sA[chunk * 512]);
            gld16(Bt + (size_t)row * DDIM + k0 + gsw * 8, &sB[chunk * 512]);
        }
        __syncthreads();
#pragma unroll
        for (int s = 0; s < 2; s++) {
            int sw = ((s * 4 + fq) ^ (fm & 7)) * 8;
            frag_ab af[4], bf[4];
#pragma unroll
            for (int i = 0; i < 4; i++) af[i] = *(const frag_ab*)&sA[(wr + i * 16 + fm) * 64 + sw];
#pragma unroll
            for (int j = 0; j < 4; j++) bf[j] = *(const frag_ab*)&sB[(wc + j * 16 + fm) * 64 + sw];
#pragma unroll
            for (int i = 0; i < 4; i++)
#pragma unroll
                for (int j = 0; j < 4; j++)
                    acc[i][j] = __builtin_amdgcn_mfma_f32_16x16x32_bf16(af[i], bf[j], acc[i][j], 0, 0, 0);
        }
        __syncthreads();
    }
    float wg2v[4], wldv[4];
#pragma unroll
    for (int j = 0; j < 4; j++) {
        int c = wc + j * 16 + fm;
        wg2v[j] = Wg2[c];
        wldv[j] = wld[c];
    }
    float part[4][4];
#pragma unroll
    for (int i = 0; i < 4; i++) {
#pragma unroll
        for (int r = 0; r < 4; r++) {
            int q = tile0 + wr + i * 16 + fq * 4 + r;
            int n = q >> 2;
            float ld = logdeg[q];
            float p = 0.f;
#pragma unroll
            for (int j = 0; j < 4; j++) {
                int c = wc + j * 16 + fm;
                float v = acc[i][j][r] + GH[(size_t)n * GATE_H_ + c] + ld * wldv[j];
                p += fmaxf(v, 0.f) * wg2v[j];
            }
            part[i][r] = p;
        }
    }
#pragma unroll
    for (int m = 1; m < 16; m <<= 1)
#pragma unroll
        for (int i = 0; i < 4; i++)
#pragma unroll
            for (int r = 0; r < 4; r++)
                part[i][r] += __shfl_xor(part[i][r], m, 64);
    if (fm == 0) {
#pragma unroll
        for (int i = 0; i < 4; i++)
#pragma unroll
            for (int r = 0; r < 4; r++)
                sred[w >> 1][wr + i * 16 + fq * 4 + r] = part[i][r];
    }
    __syncthreads();
    if (tid < 128) scores[tile0 + tid] = sred[0][tid] + sred[1][tid] + bg2[0];
}

// ============== all weight transposes in ONE launch ==========
struct TD { const float* src; unsigned short* dst; int K; int N; };
struct TD10 { TD d[10]; };

__global__ __launch_bounds__(256) void transpose_all_kernel(TD10 descs)
{
    TD t = descs.d[blockIdx.z];
    int n0 = blockIdx.x * 32, k0 = blockIdx.y * 32;
    if (n0 >= t.N || k0 >= t.K) return;
    __shared__ float tile[32][33];
    int tx = threadIdx.x & 31, ty4 = (threadIdx.x >> 5) * 4;
#pragma unroll
    for (int i = 0; i < 4; i++)
        tile[ty4 + i][tx] = t.src[(size_t)(k0 + ty4 + i) * t.N + n0 + tx];
    __syncthreads();
#pragma unroll
    for (int i = 0; i < 4; i++)
        t.dst[(size_t)(n0 + ty4 + i) * t.K + k0 + tx] = f2bf(tile[tx][ty4 + i]);
}

// ================= CSR build: fixed-stride buckets, NO global fine histogram ==========
// binA2: per 4096-edge tile, LDS coarse hist (128 buckets), bucket-ordered staging,
// allocation via 128 coarse counters only (bcnt).
__global__ __launch_bounds__(256) void binA2_kernel(
    const int* __restrict__ rows, const int* __restrict__ cols,
    int* __restrict__ bcnt, uint2* __restrict__ staging)
{
    __shared__ int hist[NCOARSE], hscan[NCOARSE], lcur[NCOARSE], gbase[NCOARSE];
    __shared__ uint2 pairs[TILE_A];
    int tid = threadIdx.x;
    int base = blockIdx.x * TILE_A;
    int cnt_t = min(TILE_A, ETOTAL - base);

    for (int i = tid; i < NCOARSE; i += 256) hist[i] = 0;
    __syncthreads();

    unsigned int q[16], c[16];
    bool valid[16];
#pragma unroll
    for (int i = 0; i < 16; i++) {
        int loc = i * 256 + tid;
        valid[i] = loc < cnt_t;
        if (valid[i]) {
            int e = base + loc;
            int k = e / NEDGE;
            unsigned int qq = (unsigned int)(k * N_NODES + rows[e]);
            q[i] = qq;
            c[i] = (unsigned int)cols[e];
            atomicAdd(&hist[qq / QPER], 1);
        }
    }
    __syncthreads();
    if (tid < NCOARSE) hscan[tid] = hist[tid];
    __syncthreads();
    for (int d = 1; d < NCOARSE; d <<= 1) {
        int v = (tid >= d && tid < NCOARSE) ? hscan[tid - d] : 0;
        __syncthreads();
        if (tid < NCOARSE) hscan[tid] += v;
        __syncthreads();
    }
    if (tid < NCOARSE) {
        int ex = hscan[tid] - hist[tid];
        hscan[tid] = ex;
        lcur[tid] = ex;
        gbase[tid] = hist[tid] ? (tid * ESTRIDE + atomicAdd(&bcnt[tid], hist[tid])) : 0;
    }
    __syncthreads();
#pragma unroll
    for (int i = 0; i < 16; i++) {
        if (valid[i]) {
            int b = q[i] / QPER;
            int p = atomicAdd(&lcur[b], 1);
            pairs[p] = make_uint2(q[i], c[i]);
        }
    }
    __syncthreads();
    for (int i = tid; i < cnt_t; i += 256) {
        uint2 pr = pairs[i];
        int b = pr.x / QPER;
        staging[gbase[b] + (i - hscan[b])] = pr;
    }
}

// binB2: block b owns q in [b*QPER,(b+1)*QPER). Fine count + scan in LDS, writes
// offs/ends and places edges into its private edst region (bucket-strided).
__global__ __launch_bounds__(256) void binB2_kernel(
    const uint2* __restrict__ staging, const int* __restrict__ bcnt,
    int* __restrict__ offs, int* __restrict__ ends, int* __restrict__ edst)
{
    __shared__ int cntS[QPER], sofs[QPER], lcur[QPER];
    __shared__ int psum[256];
    int tid = threadIdx.x, b = blockIdx.x;
    int q0 = b * QPER, base = b * ESTRIDE;
    int fill = bcnt[b];
    for (int i = tid; i < QPER; i += 256) cntS[i] = 0;
    __syncthreads();
    for (int i = tid; i < fill; i += 256)
        atomicAdd(&cntS[staging[base + i].x - q0], 1);
    __syncthreads();
    // exclusive scan of cntS[0..QPER) via per-thread chunks (CH=3: 256*3 >= 625)
    const int CH = 3;
    int lo = tid * CH, hi = min(lo + CH, QPER);
    int s = 0;
    for (int i = lo; i < hi; i++) s += cntS[i];
    psum[tid] = s;
    __syncthreads();
    for (int d = 1; d < 256; d <<= 1) {
        int v = (tid >= d) ? psum[tid - d] : 0;
        __syncthreads();
        psum[tid] += v;
        __syncthreads();
    }
    int run = (tid == 0) ? 0 : psum[tid - 1];
    for (int i = lo; i < hi; i++) {
        sofs[i] = run;
        lcur[i] = run;
        run += cntS[i];
    }
    __syncthreads();
    for (int i = tid; i < QPER; i += 256) {
        offs[q0 + i] = base + sofs[i];
        ends[q0 + i] = base + sofs[i] + cntS[i];
    }
    for (int i = tid; i < fill; i += 256) {
        uint2 p = staging[base + i];
        int pos = atomicAdd(&lcur[p.x - q0], 1);
        edst[base + pos] = (int)p.y;
    }
}

// ---------------- gather: Mb[q,:] = bf16(clip(sum Zb[col_e,:])) ----------
__global__ __launch_bounds__(256) void gather_kernel(
    const int* __restrict__ offs, const int* __restrict__ ends,
    const int* __restrict__ edst,
    const unsigned short* __restrict__ Zb, unsigned short* __restrict__ Mb)
{
    int q = blockIdx.x * 4 + (threadIdx.x >> 6);   // q = k*N + r
    int lane = threadIdx.x & 63;
    int k = q / N_NODES;
    int r = q - k * N_NODES;
    int start = offs[q];
    int end = ends[q];
    float ax = 0.f, ay = 0.f;
    int i = start;
    for (; i + 3 < end; i += 4) {
        int c0 = edst[i], c1 = edst[i + 1], c2 = edst[i + 2], c3 = edst[i + 3];
        unsigned int p0 = *(const unsigned int*)(Zb + (size_t)c0 * DDIM + lane * 2);
        unsigned int p1 = *(const unsigned int*)(Zb + (size_t)c1 * DDIM + lane * 2);
        unsigned int p2 = *(const unsigned int*)(Zb + (size_t)c2 * DDIM + lane * 2);
        unsigned int p3 = *(const unsigned int*)(Zb + (size_t)c3 * DDIM + lane * 2);
        ax += bflo(p0) + bflo(p1) + bflo(p2) + bflo(p3);
        ay += bfhi(p0) + bfhi(p1) + bfhi(p2) + bfhi(p3);
    }
    for (; i < end; i++) {
        unsigned int p = *(const unsigned int*)(Zb + (size_t)edst[i] * DDIM + lane * 2);
        ax += bflo(p); ay += bfhi(p);
    }
    ax = fminf(fmaxf(ax, -M_CLAMP_), M_CLAMP_);
    ay = fminf(fmaxf(ay, -M_CLAMP_), M_CLAMP_);
    unsigned int pk = (unsigned int)f2bf(ax) | ((unsigned int)f2bf(ay) << 16);
    *(unsigned int*)(Mb + ((size_t)r * KADJ + k) * DDIM + lane * 2) = pk;
}

// ------- fused alpha + Y: Y = H + sum_k alpha*Mb; 2 elems/thread -------
__global__ __launch_bounds__(256) void fuse_kernel(
    const unsigned short* __restrict__ Mb, const float* __restrict__ scores,
    const float* __restrict__ mask, const float* __restrict__ H,
    float* __restrict__ Y, float* __restrict__ alpha_out, int N)
{
    int gid = blockIdx.x * 256 + threadIdx.x;
    int n = gid >> 6, dd = (gid & 63) * 2;
    if (n >= N) return;
    float a[KADJ];
    float mx = -1e30f;
#pragma unroll
    for (int k = 0; k < KADJ; k++) {
        a[k] = scores[(size_t)n * KADJ + k] * (1.0f / TEMP_);
        mx = fmaxf(mx, a[k]);
    }
    float sum = 0.f;
#pragma unroll
    for (int k = 0; k < KADJ; k++) { a[k] = expf(a[k] - mx); sum += a[k]; }
#pragma unroll
    for (int k = 0; k < KADJ; k++) a[k] = (a[k] / sum) * mask[(size_t)n * KADJ + k];
    float s2 = 0.f;
#pragma unroll
    for (int k = 0; k < KADJ; k++) s2 += a[k];
    float inv = 1.f / fmaxf(s2, 1e-12f);
#pragma unroll
    for (int k = 0; k < KADJ; k++) a[k] = fmaxf(a[k] * inv, 1e-8f);
    s2 = 0.f;
#pragma unroll
    for (int k = 0; k < KADJ; k++) s2 += a[k];
    inv = 1.f / fmaxf(s2, 1e-12f);
#pragma unroll
    for (int k = 0; k < KADJ; k++) a[k] *= inv;

    float2 h = *(const float2*)(H + (size_t)n * DDIM + dd);
    float yx = h.x, yy = h.y;
#pragma unroll
    for (int k = 0; k < KADJ; k++) {
        unsigned int u = *(const unsigned int*)(Mb + ((size_t)n * KADJ + k) * DDIM + dd);
        yx += a[k] * bflo(u);
        yy += a[k] * bfhi(u);
    }
    *(float2*)(Y + (size_t)n * DDIM + dd) = make_float2(yx, yy);
    int j = gid & 63;
    if (j < KADJ) alpha_out[(size_t)n * KADJ + j] = a[j];
}

// ---------------- pairnorm reduction ----------------
__global__ __launch_bounds__(256) void reduce_kernel(
    const float* __restrict__ Y, float* __restrict__ red, int N)
{
    int tid = threadIdx.x;
    int d = tid & 127;
    int half = tid >> 7;
    float cs = 0.f, sq = 0.f;
    for (int n = blockIdx.x * 2 + half; n < N; n += gridDim.x * 2) {
        float v = Y[(size_t)n * DDIM + d];
        cs += v; sq += v * v;
    }
    __shared__ float scs[256], ssq[256];
    scs[tid] = cs; ssq[tid] = sq;
    __syncthreads();
    if (tid < 128) scs[tid] += scs[tid + 128];
    for (int s = 128; s > 0; s >>= 1) {
        if (tid < s) ssq[tid] += ssq[tid + s];
        __syncthreads();
    }
    if (tid < 128) atomicAdd(&red[tid], scs[tid]);
    if (tid == 0) atomicAdd(&red[128], ssq[0]);
}

// ---------------- pairnorm apply: writes H fp32 + Hb bf16 ----------
__global__ __launch_bounds__(256) void pairnorm_kernel(
    const float* __restrict__ Y, const float* __restrict__ red,
    float* __restrict__ Hout, unsigned short* __restrict__ Hb, int N)
{
    int tid = threadIdx.x;
    int d = tid & 127;
    float invN = 1.0f / (float)N;
    float mu = red[d] * invN;
    __shared__ float smu2[128];
    if (tid < 128) smu2[tid] = mu * mu;
    __syncthreads();
    for (int s = 64; s > 0; s >>= 1) {
        if (tid < s) smu2[tid] += smu2[tid + s];
        __syncthreads();
    }
    float summu2 = smu2[0];
    float var = red[128] * invN - summu2;
    float norm = sqrtf(fmaxf(var, 0.f)) + 1e-6f;
    float inv = 1.0f / norm;
    int n = blockIdx.x * 2 + (tid >> 7);
    if (n < N) {
        float v = (Y[(size_t)n * DDIM + d] - mu) * inv;
        v = fmaxf(v, 0.f);
        Hout[(size_t)n * DDIM + d] = v;
        Hb[(size_t)n * DDIM + d] = f2bf(v);
    }
}

// ---------------- logits ----------------
__global__ __launch_bounds__(256) void logits_kernel(
    const float* __restrict__ h, const float* __restrict__ Wh2,
    const float* __restrict__ bh2, float* __restrict__ out, int N)
{
    int gid = blockIdx.x * 256 + threadIdx.x;
    int n = gid >> 6;
    int lane = gid & 63;
    if (n >= N) return;
    float2 hv = *reinterpret_cast<const float2*>(h + (size_t)n * DDIM + lane * 2);
    float2 wv = *reinterpret_cast<const float2*>(Wh2 + lane * 2);
    float v = hv.x * wv.x + hv.y * wv.y;
#pragma unroll
    for (int off = 32; off > 0; off >>= 1) v += __shfl_down(v, off);
    if (lane == 0) out[n] = v + bh2[0];
}

extern "C" void kernel_launch(void* const* d_in, const int* in_sizes, int n_in,
                              void* d_out, int out_size, void* d_ws, size_t ws_size,
                              hipStream_t stream)
{
    const float* X      = (const float*)d_in[0];
    const int*   rows   = (const int*)d_in[1];
    const int*   cols   = (const int*)d_in[2];
    const float* mask   = (const float*)d_in[3];
    const float* logdeg = (const float*)d_in[4];
    const float* W_in0  = (const float*)d_in[5];
    const float* b_in0  = (const float*)d_in[6];
    const float* W_in1  = (const float*)d_in[7];
    const float* b_in1  = (const float*)d_in[8];
    const float* W_in2  = (const float*)d_in[9];
    const float* b_in2  = (const float*)d_in[10];
    const float* Wmsg[2] = {(const float*)d_in[11], (const float*)d_in[16]};
    const float* Wg1[2]  = {(const float*)d_in[12], (const float*)d_in[17]};
    const float* bg1[2]  = {(const float*)d_in[13], (const float*)d_in[18]};
    const float* Wg2[2]  = {(const float*)d_in[14], (const float*)d_in[19]};
    const float* bg2[2]  = {(const float*)d_in[15], (const float*)d_in[20]};
    const float* Wh1 = (const float*)d_in[21];
    const float* bh1 = (const float*)d_in[22];
    const float* Wh2 = (const float*)d_in[23];
    const float* bh2 = (const float*)d_in[24];

    // workspace layout (float slots), ~85 MB:
    // [0,10.24M): Xb (encoder) | loop: Mb bf16 (5.12M) + Ybuf/hhead (@5.12M) + GH (@7.68M)
    // [10.24M,15.36M): CSR staging (3.15M, build-only) -> H0b (@10.24M), H1b (@12.8M) -> Zb (@12.8M)
    float* ws = (float*)d_ws;
    unsigned short* Xb  = (unsigned short*)ws;
    unsigned short* Mb  = (unsigned short*)ws;
    float* Ybuf  = ws + 5120000;
    float* hhead = ws + 5120000;
    float* GH    = ws + 7680000;
    uint2* staging = (uint2*)(ws + 10240000);       // NCOARSE*ESTRIDE*2 = 3,145,728 slots
    unsigned short* H0b = (unsigned short*)(ws + 10240000);
    unsigned short* H1b = (unsigned short*)(ws + 12800000);
    unsigned short* Zb  = (unsigned short*)(ws + 12800000);
    float* H     = ws + 15360000;                   // 2.56M
    unsigned short* Hb = (unsigned short*)(ws + 17920000);  // 1.28M slots
    float* scores = ws + 19200000;                  // 80000
    int*   offs   = (int*)(ws + 19280000);          // 80000
    int*   ends   = (int*)(ws + 19360000);          // 80000
    int*   edst   = (int*)(ws + 19440000);          // NCOARSE*ESTRIDE = 1,572,864
    float* red    = ws + 21012864;                  // 256
    int*   bcnt   = (int*)(ws + 21013120);          // 128
    unsigned short* w0t  = (unsigned short*)(ws + 21013248);  // 131072 slots
    unsigned short* w1t  = (unsigned short*)(ws + 21144320);  // 32768
    unsigned short* w2t  = (unsigned short*)(ws + 21177088);  // 16384
    unsigned short* wmt[2]  = {(unsigned short*)(ws + 21193472), (unsigned short*)(ws + 21201664)};
    unsigned short* wgt[2]  = {(unsigned short*)(ws + 21209856), (unsigned short*)(ws + 21218048)};
    unsigned short* wgmt[2] = {(unsigned short*)(ws + 21226240), (unsigned short*)(ws + 21234432)};
    unsigned short* wh1t = (unsigned short*)(ws + 21242624);
    float* logits = (float*)d_out;
    float* alpha_out = (float*)d_out + N_NODES;

    dim3 blk(256);
    int gM = (N_NODES + 127) / 128;     // 157

    // ---- CSR build: coarse-bucket staging + owner-block fine placement ----
    (void)hipMemsetAsync(bcnt, 0, NCOARSE * sizeof(int), stream);
    binA2_kernel<<<BINA_NB, blk, 0, stream>>>(rows, cols, bcnt, staging);
    binB2_kernel<<<NCOARSE, blk, 0, stream>>>(staging, bcnt, offs, ends, edst);

    // ---- weight transposes + X cast ----
    TD10 descs;
    descs.d[0] = {W_in0, w0t, IN_DIM_, H_IN_};
    descs.d[1] = {W_in1, w1t, H_IN_, H_IN_};
    descs.d[2] = {W_in2, w2t, H_IN_, DDIM};
    descs.d[3] = {Wmsg[0], wmt[0], DDIM, DDIM};
    descs.d[4] = {Wmsg[1], wmt[1], DDIM, DDIM};
    descs.d[5] = {Wg1[0], wgt[0], DDIM, GATE_H_};
    descs.d[6] = {Wg1[1], wgt[1], DDIM, GATE_H_};
    descs.d[7] = {Wg1[0] + DDIM * GATE_H_, wgmt[0], DDIM, GATE_H_};
    descs.d[8] = {Wg1[1] + DDIM * GATE_H_, wgmt[1], DDIM, GATE_H_};
    descs.d[9] = {Wh1, wh1t, DDIM, DDIM};
    transpose_all_kernel<<<dim3(8, 32, 10), blk, 0, stream>>>(descs);
    cast_bf16_kernel<<<N_NODES * IN_DIM_ / 8 / 256, blk, 0, stream>>>(X, Xb, N_NODES * IN_DIM_);

    // ---- encoder ----
    gemm_async_kernel<<<dim3(2, gM), blk, 0, stream>>>(Xb, w0t, b_in0, nullptr, H0b, N_NODES, H_IN_, IN_DIM_, 1);
    gemm_async_kernel<<<dim3(2, gM), blk, 0, stream>>>(H0b, w1t, b_in1, nullptr, H1b, N_NODES, H_IN_, H_IN_, 1);
    gemm_async_kernel<<<dim3(1, gM), blk, 0, stream>>>(H1b, w2t, b_in2, H, Hb, N_NODES, DDIM, H_IN_, 1);

    for (int b = 0; b < 2; b++) {
        gemm_async_kernel<<<dim3(1, gM), blk, 0, stream>>>(Hb, wmt[b], nullptr, nullptr, Zb, N_NODES, DDIM, DDIM, 0);
        gather_kernel<<<CSR_TOTAL / 4, blk, 0, stream>>>(offs, ends, edst, Zb, Mb);
        gemm_async_kernel<<<dim3(1, gM), blk, 0, stream>>>(Hb, wgt[b], bg1[b], GH, nullptr, N_NODES, GATE_H_, DDIM, 0);
        gate_gemm_kernel<<<CSR_TOTAL / 128, blk, 0, stream>>>(Mb, wgmt[b], GH, logdeg,
                                                              Wg1[b] + 256 * GATE_H_, Wg2[b], bg2[b], scores);
        float* alph = alpha_out + (size_t)b * N_NODES * KADJ;
        fuse_kernel<<<(N_NODES * 64) / 256, blk, 0, stream>>>(Mb, scores, mask, H, Ybuf, alph, N_NODES);
        (void)hipMemsetAsync(red, 0, 129 * sizeof(float), stream);
        reduce_kernel<<<512, blk, 0, stream>>>(Ybuf, red, N_NODES);
        pairnorm_kernel<<<(N_NODES + 1) / 2, blk, 0, stream>>>(Ybuf, red, H, Hb, N_NODES);
    }

    // head
    gemm_async_kernel<<<dim3(1, gM), blk, 0, stream>>>(Hb, wh1t, bh1, hhead, nullptr, N_NODES, DDIM, DDIM, 1);
    logits_kernel<<<(N_NODES * 64 + 255) / 256, blk, 0, stream>>>(hhead, Wh2, bh2, logits, N_NODES);
}

// Round 9
// 548.249 us; speedup vs baseline: 9.0641x; 1.0354x over previous
//
#include <hip/hip_runtime.h>
#include <hip/hip_bf16.h>

#define N_NODES 20000
#define KADJ 4
#define NEDGE 320000
#define ETOTAL (KADJ * NEDGE)               // 1,280,000
#define IN_DIM_ 1024
#define H_IN_ 256
#define DDIM 128
#define GATE_H_ 128
#define TEMP_ 0.6f
#define M_CLAMP_ 20.0f
#define CSR_TOTAL (KADJ * N_NODES)          // 80000
#define NCOARSE 128
#define QPER (CSR_TOTAL / NCOARSE)          // 625
#define ESTRIDE 12288                       // bucket slot stride (exp fill 10000, sigma~100)
#define TILE_A 4096
#define BINA_NB ((ETOTAL + TILE_A - 1) / TILE_A)  // 313

typedef __attribute__((ext_vector_type(8))) short frag_ab;      // 8 bf16
typedef __attribute__((ext_vector_type(4))) float frag_cd;      // 4 fp32
typedef __attribute__((ext_vector_type(8))) unsigned short us8;

__device__ inline unsigned short f2bf(float f) {
    unsigned int u = __float_as_uint(f);
    u += 0x7FFFu + ((u >> 16) & 1);   // RNE
    return (unsigned short)(u >> 16);
}
__device__ inline float bflo(unsigned int p) { return __uint_as_float(p << 16); }
__device__ inline float bfhi(unsigned int p) { return __uint_as_float(p & 0xffff0000u); }

// async 16B global->LDS (wave-uniform LDS base + lane*16)
__device__ __forceinline__ void gld16(const unsigned short* g, unsigned short* l) {
    __builtin_amdgcn_global_load_lds(
        (const __attribute__((address_space(1))) void*)g,
        (__attribute__((address_space(3))) void*)l, 16, 0, 0);
}

// ---- X fp32 -> bf16 streaming cast ----
__global__ __launch_bounds__(256) void cast_bf16_kernel(
    const float* __restrict__ X, unsigned short* __restrict__ Xb, int n)
{
    int i = (blockIdx.x * 256 + threadIdx.x) * 8;
    if (i >= n) return;
    float4 a = *(const float4*)(X + i), b = *(const float4*)(X + i + 4);
    us8 o;
    o[0] = f2bf(a.x); o[1] = f2bf(a.y); o[2] = f2bf(a.z); o[3] = f2bf(a.w);
    o[4] = f2bf(b.x); o[5] = f2bf(b.y); o[6] = f2bf(b.z); o[7] = f2bf(b.w);
    *(us8*)(Xb + i) = o;
}

// ============== async bf16 MFMA GEMM: C = [relu](A[M,K]_bf16 @ (Bt[N,K]_bf16)^T + bias) =========
__global__ __launch_bounds__(256) void gemm_async_kernel(
    const unsigned short* __restrict__ A, const unsigned short* __restrict__ Bt,
    const float* __restrict__ bias, float* __restrict__ Cf, unsigned short* __restrict__ Cb,
    int M, int N, int K, int do_relu)
{
    __shared__ unsigned short sA[128 * 64];
    __shared__ unsigned short sB[128 * 64];
    int tid = threadIdx.x;
    int tileM = blockIdx.y * 128, tileN = blockIdx.x * 128;
    int w = tid >> 6, lane = tid & 63;
    int wr = (w & 1) * 64, wc = (w >> 1) * 64;
    int fm = lane & 15, fq = lane >> 4;
    int crow = lane >> 3;              // row within 8-row chunk
    int gsw = (lane & 7) ^ crow;       // global granule this lane fetches

    frag_cd acc[4][4] = {};

    for (int k0 = 0; k0 < K; k0 += 64) {
#pragma unroll
        for (int t = 0; t < 4; t++) {
            int chunk = w * 4 + t;
            int row = chunk * 8 + crow;
            const unsigned short* ga = A + (size_t)(tileM + row) * K + k0 + gsw * 8;
            if (tileM + row < M) gld16(ga, &sA[chunk * 512]);
            const unsigned short* gb = Bt + (size_t)(tileN + row) * K + k0 + gsw * 8;
            gld16(gb, &sB[chunk * 512]);
        }
        __syncthreads();
#pragma unroll
        for (int s = 0; s < 2; s++) {
            int sw = ((s * 4 + fq) ^ (fm & 7)) * 8;
            frag_ab af[4], bf[4];
#pragma unroll
            for (int i = 0; i < 4; i++) af[i] = *(const frag_ab*)&sA[(wr + i * 16 + fm) * 64 + sw];
#pragma unroll
            for (int j = 0; j < 4; j++) bf[j] = *(const frag_ab*)&sB[(wc + j * 16 + fm) * 64 + sw];
#pragma unroll
            for (int i = 0; i < 4; i++)
#pragma unroll
                for (int j = 0; j < 4; j++)
                    acc[i][j] = __builtin_amdgcn_mfma_f32_16x16x32_bf16(af[i], bf[j], acc[i][j], 0, 0, 0);
        }
        __syncthreads();
    }
#pragma unroll
    for (int i = 0; i < 4; i++) {
        int row = tileM + wr + i * 16 + fq * 4;
#pragma unroll
        for (int r = 0; r < 4; r++) {
            if (row + r < M) {
#pragma unroll
                for (int j = 0; j < 4; j++) {
                    int col = tileN + wc + j * 16 + fm;
                    float v = acc[i][j][r];
                    if (bias) v += bias[col];
                    if (do_relu) v = fmaxf(v, 0.f);
                    if (Cf) Cf[(size_t)(row + r) * N + col] = v;
                    if (Cb) Cb[(size_t)(row + r) * N + col] = f2bf(v);
                }
            }
        }
    }
}

// ============== fused Z+GH GEMM: A=Hb[M,128], Bt=wzg[256][128] ==============
// blockIdx.x==0: cols 0-127 = Wmsg^T -> Zb bf16 (no bias/relu)
// blockIdx.x==1: cols 128-255 = Wg1h^T -> GH fp32 (+bg1, no relu)
__global__ __launch_bounds__(256) void zg_gemm_kernel(
    const unsigned short* __restrict__ A, const unsigned short* __restrict__ Bt,
    const float* __restrict__ bg1, unsigned short* __restrict__ Zb,
    float* __restrict__ GH, int M)
{
    __shared__ unsigned short sA[128 * 64];
    __shared__ unsigned short sB[128 * 64];
    int tid = threadIdx.x;
    int tileM = blockIdx.y * 128, tileN = blockIdx.x * 128;
    int w = tid >> 6, lane = tid & 63;
    int wr = (w & 1) * 64, wc = (w >> 1) * 64;
    int fm = lane & 15, fq = lane >> 4;
    int crow = lane >> 3;
    int gsw = (lane & 7) ^ crow;

    frag_cd acc[4][4] = {};

    for (int k0 = 0; k0 < DDIM; k0 += 64) {
#pragma unroll
        for (int t = 0; t < 4; t++) {
            int chunk = w * 4 + t;
            int row = chunk * 8 + crow;
            if (tileM + row < M) gld16(A + (size_t)(tileM + row) * DDIM + k0 + gsw * 8, &sA[chunk * 512]);
            gld16(Bt + (size_t)(tileN + row) * DDIM + k0 + gsw * 8, &sB[chunk * 512]);
        }
        __syncthreads();
#pragma unroll
        for (int s = 0; s < 2; s++) {
            int sw = ((s * 4 + fq) ^ (fm & 7)) * 8;
            frag_ab af[4], bf[4];
#pragma unroll
            for (int i = 0; i < 4; i++) af[i] = *(const frag_ab*)&sA[(wr + i * 16 + fm) * 64 + sw];
#pragma unroll
            for (int j = 0; j < 4; j++) bf[j] = *(const frag_ab*)&sB[(wc + j * 16 + fm) * 64 + sw];
#pragma unroll
            for (int i = 0; i < 4; i++)
#pragma unroll
                for (int j = 0; j < 4; j++)
                    acc[i][j] = __builtin_amdgcn_mfma_f32_16x16x32_bf16(af[i], bf[j], acc[i][j], 0, 0, 0);
        }
        __syncthreads();
    }
    int isZ = (blockIdx.x == 0);
#pragma unroll
    for (int i = 0; i < 4; i++) {
        int row = tileM + wr + i * 16 + fq * 4;
#pragma unroll
        for (int r = 0; r < 4; r++) {
            if (row + r < M) {
#pragma unroll
                for (int j = 0; j < 4; j++) {
                    int col = wc + j * 16 + fm;    // local 0..127
                    float v = acc[i][j][r];
                    if (isZ) Zb[(size_t)(row + r) * DDIM + col] = f2bf(v);
                    else     GH[(size_t)(row + r) * GATE_H_ + col] = v + bg1[col];
                }
            }
        }
    }
}

// ============== head GEMM + logits epilogue: logits = relu(Hb@Wh1+bh1) . Wh2 + bh2 ========
__global__ __launch_bounds__(256) void head_gemm_kernel(
    const unsigned short* __restrict__ A, const unsigned short* __restrict__ Bt,
    const float* __restrict__ bh1, const float* __restrict__ Wh2,
    const float* __restrict__ bh2, float* __restrict__ logits, int M)
{
    __shared__ unsigned short sA[128 * 64];
    __shared__ unsigned short sB[128 * 64];
    __shared__ float sred[2][128];
    int tid = threadIdx.x;
    int tileM = blockIdx.x * 128;
    int w = tid >> 6, lane = tid & 63;
    int wr = (w & 1) * 64, wc = (w >> 1) * 64;
    int fm = lane & 15, fq = lane >> 4;
    int crow = lane >> 3;
    int gsw = (lane & 7) ^ crow;

    frag_cd acc[4][4] = {};

    for (int k0 = 0; k0 < DDIM; k0 += 64) {
#pragma unroll
        for (int t = 0; t < 4; t++) {
            int chunk = w * 4 + t;
            int row = chunk * 8 + crow;
            if (tileM + row < M) gld16(A + (size_t)(tileM + row) * DDIM + k0 + gsw * 8, &sA[chunk * 512]);
            gld16(Bt + (size_t)row * DDIM + k0 + gsw * 8, &sB[chunk * 512]);
        }
        __syncthreads();
#pragma unroll
        for (int s = 0; s < 2; s++) {
            int sw = ((s * 4 + fq) ^ (fm & 7)) * 8;
            frag_ab af[4], bf[4];
#pragma unroll
            for (int i = 0; i < 4; i++) af[i] = *(const frag_ab*)&sA[(wr + i * 16 + fm) * 64 + sw];
#pragma unroll
            for (int j = 0; j < 4; j++) bf[j] = *(const frag_ab*)&sB[(wc + j * 16 + fm) * 64 + sw];
#pragma unroll
            for (int i = 0; i < 4; i++)
#pragma unroll
                for (int j = 0; j < 4; j++)
                    acc[i][j] = __builtin_amdgcn_mfma_f32_16x16x32_bf16(af[i], bf[j], acc[i][j], 0, 0, 0);
        }
        __syncthreads();
    }
    float wv[4], bh[4];
#pragma unroll
    for (int j = 0; j < 4; j++) {
        int c = wc + j * 16 + fm;
        wv[j] = Wh2[c];
        bh[j] = bh1[c];
    }
    float part[4][4];
#pragma unroll
    for (int i = 0; i < 4; i++) {
#pragma unroll
        for (int r = 0; r < 4; r++) {
            float p = 0.f;
#pragma unroll
            for (int j = 0; j < 4; j++) {
                float v = fmaxf(acc[i][j][r] + bh[j], 0.f);
                p += v * wv[j];
            }
            part[i][r] = p;
        }
    }
#pragma unroll
    for (int m = 1; m < 16; m <<= 1)
#pragma unroll
        for (int i = 0; i < 4; i++)
#pragma unroll
            for (int r = 0; r < 4; r++)
                part[i][r] += __shfl_xor(part[i][r], m, 64);
    if (fm == 0) {
#pragma unroll
        for (int i = 0; i < 4; i++)
#pragma unroll
            for (int r = 0; r < 4; r++)
                sred[w >> 1][wr + i * 16 + fq * 4 + r] = part[i][r];
    }
    __syncthreads();
    if (tid < 128 && tileM + tid < M)
        logits[tileM + tid] = sred[0][tid] + sred[1][tid] + bh2[0];
}

// ============== gate GEMM: scores[q] = relu(Mb[q]@Wg1m + GH[q>>2] + logdeg[q]*wld) . Wg2 + bg2 ===
__global__ __launch_bounds__(256) void gate_gemm_kernel(
    const unsigned short* __restrict__ Mb, const unsigned short* __restrict__ Bt,
    const float* __restrict__ GH, const float* __restrict__ logdeg,
    const float* __restrict__ wld, const float* __restrict__ Wg2,
    const float* __restrict__ bg2, float* __restrict__ scores)
{
    __shared__ unsigned short sA[128 * 64];
    __shared__ unsigned short sB[128 * 64];
    __shared__ float sred[2][128];
    int tid = threadIdx.x;
    int tile0 = blockIdx.x * 128;
    int w = tid >> 6, lane = tid & 63;
    int wr = (w & 1) * 64, wc = (w >> 1) * 64;
    int fm = lane & 15, fq = lane >> 4;
    int crow = lane >> 3;
    int gsw = (lane & 7) ^ crow;

    frag_cd acc[4][4] = {};

    for (int k0 = 0; k0 < DDIM; k0 += 64) {
#pragma unroll
        for (int t = 0; t < 4; t++) {
            int chunk = w * 4 + t;
            int row = chunk * 8 + crow;
            gld16(Mb + (size_t)(tile0 + row) * DDIM + k0 + gsw * 8, &sA[chunk * 512]);
            gld16(Bt + (size_t)row * DDIM + k0 + gsw * 8, &sB[chunk * 512]);
        }
        __syncthreads();
#pragma unroll
        for (int s = 0; s < 2; s++) {
            int sw = ((s * 4 + fq) ^ (fm & 7)) * 8;
            frag_ab af[4], bf[4];
#pragma unroll
            for (int i = 0; i < 4; i++) af[i] = *(const frag_ab*)&sA[(wr + i * 16 + fm) * 64 + sw];
#pragma unroll
            for (int j = 0; j < 4; j++) bf[j] = *(const frag_ab*)&sB[(wc + j * 16 + fm) * 64 + sw];
#pragma unroll
            for (int i = 0; i < 4; i++)
#pragma unroll
                for (int j = 0; j < 4; j++)
                    acc[i][j] = __builtin_amdgcn_mfma_f32_16x16x32_bf16(af[i], bf[j], acc[i][j], 0, 0, 0);
        }
        __syncthreads();
    }
    float wg2v[4], wldv[4];
#pragma unroll
    for (int j = 0; j < 4; j++) {
        int c = wc + j * 16 + fm;
        wg2v[j] = Wg2[c];
        wldv[j] = wld[c];
    }
    float part[4][4];
#pragma unroll
    for (int i = 0; i < 4; i++) {
#pragma unroll
        for (int r = 0; r < 4; r++) {
            int q = tile0 + wr + i * 16 + fq * 4 + r;
            int n = q >> 2;
            float ld = logdeg[q];
            float p = 0.f;
#pragma unroll
            for (int j = 0; j < 4; j++) {
                int c = wc + j * 16 + fm;
                float v = acc[i][j][r] + GH[(size_t)n * GATE_H_ + c] + ld * wldv[j];
                p += fmaxf(v, 0.f) * wg2v[j];
            }
            part[i][r] = p;
        }
    }
#pragma unroll
    for (int m = 1; m < 16; m <<= 1)
#pragma unroll
        for (int i = 0; i < 4; i++)
#pragma unroll
            for (int r = 0; r < 4; r++)
                part[i][r] += __shfl_xor(part[i][r], m, 64);
    if (fm == 0) {
#pragma unroll
        for (int i = 0; i < 4; i++)
#pragma unroll
            for (int r = 0; r < 4; r++)
                sred[w >> 1][wr + i * 16 + fq * 4 + r] = part[i][r];
    }
    __syncthreads();
    if (tid < 128) scores[tile0 + tid] = sred[0][tid] + sred[1][tid] + bg2[0];
}

// ============== all weight transposes in ONE launch ==========
struct TD { const float* src; unsigned short* dst; int K; int N; };
struct TD10 { TD d[10]; };

__global__ __launch_bounds__(256) void transpose_all_kernel(TD10 descs)
{
    TD t = descs.d[blockIdx.z];
    int n0 = blockIdx.x * 32, k0 = blockIdx.y * 32;
    if (n0 >= t.N || k0 >= t.K) return;
    __shared__ float tile[32][33];
    int tx = threadIdx.x & 31, ty4 = (threadIdx.x >> 5) * 4;
#pragma unroll
    for (int i = 0; i < 4; i++)
        tile[ty4 + i][tx] = t.src[(size_t)(k0 + ty4 + i) * t.N + n0 + tx];
    __syncthreads();
#pragma unroll
    for (int i = 0; i < 4; i++)
        t.dst[(size_t)(n0 + ty4 + i) * t.K + k0 + tx] = f2bf(tile[tx][ty4 + i]);
}

// ================= CSR build: fixed-stride buckets ==========
__global__ __launch_bounds__(256) void binA2_kernel(
    const int* __restrict__ rows, const int* __restrict__ cols,
    int* __restrict__ bcnt, uint2* __restrict__ staging)
{
    __shared__ int hist[NCOARSE], hscan[NCOARSE], lcur[NCOARSE], gbase[NCOARSE];
    __shared__ uint2 pairs[TILE_A];
    int tid = threadIdx.x;
    int base = blockIdx.x * TILE_A;
    int cnt_t = min(TILE_A, ETOTAL - base);

    for (int i = tid; i < NCOARSE; i += 256) hist[i] = 0;
    __syncthreads();

    unsigned int q[16], c[16];
    bool valid[16];
#pragma unroll
    for (int i = 0; i < 16; i++) {
        int loc = i * 256 + tid;
        valid[i] = loc < cnt_t;
        if (valid[i]) {
            int e = base + loc;
            int k = e / NEDGE;
            unsigned int qq = (unsigned int)(k * N_NODES + rows[e]);
            q[i] = qq;
            c[i] = (unsigned int)cols[e];
            atomicAdd(&hist[qq / QPER], 1);
        }
    }
    __syncthreads();
    if (tid < NCOARSE) hscan[tid] = hist[tid];
    __syncthreads();
    for (int d = 1; d < NCOARSE; d <<= 1) {
        int v = (tid >= d && tid < NCOARSE) ? hscan[tid - d] : 0;
        __syncthreads();
        if (tid < NCOARSE) hscan[tid] += v;
        __syncthreads();
    }
    if (tid < NCOARSE) {
        int ex = hscan[tid] - hist[tid];
        hscan[tid] = ex;
        lcur[tid] = ex;
        gbase[tid] = hist[tid] ? (tid * ESTRIDE + atomicAdd(&bcnt[tid], hist[tid])) : 0;
    }
    __syncthreads();
#pragma unroll
    for (int i = 0; i < 16; i++) {
        if (valid[i]) {
            int b = q[i] / QPER;
            int p = atomicAdd(&lcur[b], 1);
            pairs[p] = make_uint2(q[i], c[i]);
        }
    }
    __syncthreads();
    for (int i = tid; i < cnt_t; i += 256) {
        uint2 pr = pairs[i];
        int b = pr.x / QPER;
        staging[gbase[b] + (i - hscan[b])] = pr;
    }
}

__global__ __launch_bounds__(256) void binB2_kernel(
    const uint2* __restrict__ staging, const int* __restrict__ bcnt,
    int* __restrict__ offs, int* __restrict__ ends, int* __restrict__ edst)
{
    __shared__ int cntS[QPER], sofs[QPER], lcur[QPER];
    __shared__ int psum[256];
    int tid = threadIdx.x, b = blockIdx.x;
    int q0 = b * QPER, base = b * ESTRIDE;
    int fill = bcnt[b];
    for (int i = tid; i < QPER; i += 256) cntS[i] = 0;
    __syncthreads();
    for (int i = tid; i < fill; i += 256)
        atomicAdd(&cntS[staging[base + i].x - q0], 1);
    __syncthreads();
    const int CH = 3;
    int lo = tid * CH, hi = min(lo + CH, QPER);
    int s = 0;
    for (int i = lo; i < hi; i++) s += cntS[i];
    psum[tid] = s;
    __syncthreads();
    for (int d = 1; d < 256; d <<= 1) {
        int v = (tid >= d) ? psum[tid - d] : 0;
        __syncthreads();
        psum[tid] += v;
        __syncthreads();
    }
    int run = (tid == 0) ? 0 : psum[tid - 1];
    for (int i = lo; i < hi; i++) {
        sofs[i] = run;
        lcur[i] = run;
        run += cntS[i];
    }
    __syncthreads();
    for (int i = tid; i < QPER; i += 256) {
        offs[q0 + i] = base + sofs[i];
        ends[q0 + i] = base + sofs[i] + cntS[i];
    }
    for (int i = tid; i < fill; i += 256) {
        uint2 p = staging[base + i];
        int pos = atomicAdd(&lcur[p.x - q0], 1);
        edst[base + pos] = (int)p.y;
    }
}

// ---------------- gather: Mb[q,:] = bf16(clip(sum Zb[col_e,:])) ----------
__global__ __launch_bounds__(256) void gather_kernel(
    const int* __restrict__ offs, const int* __restrict__ ends,
    const int* __restrict__ edst,
    const unsigned short* __restrict__ Zb, unsigned short* __restrict__ Mb)
{
    int q = blockIdx.x * 4 + (threadIdx.x >> 6);   // q = k*N + r
    int lane = threadIdx.x & 63;
    int k = q / N_NODES;
    int r = q - k * N_NODES;
    int start = offs[q];
    int end = ends[q];
    float ax = 0.f, ay = 0.f;
    int i = start;
    for (; i + 3 < end; i += 4) {
        int c0 = edst[i], c1 = edst[i + 1], c2 = edst[i + 2], c3 = edst[i + 3];
        unsigned int p0 = *(const unsigned int*)(Zb + (size_t)c0 * DDIM + lane * 2);
        unsigned int p1 = *(const unsigned int*)(Zb + (size_t)c1 * DDIM + lane * 2);
        unsigned int p2 = *(const unsigned int*)(Zb + (size_t)c2 * DDIM + lane * 2);
        unsigned int p3 = *(const unsigned int*)(Zb + (size_t)c3 * DDIM + lane * 2);
        ax += bflo(p0) + bflo(p1) + bflo(p2) + bflo(p3);
        ay += bfhi(p0) + bfhi(p1) + bfhi(p2) + bfhi(p3);
    }
    for (; i < end; i++) {
        unsigned int p = *(const unsigned int*)(Zb + (size_t)edst[i] * DDIM + lane * 2);
        ax += bflo(p); ay += bfhi(p);
    }
    ax = fminf(fmaxf(ax, -M_CLAMP_), M_CLAMP_);
    ay = fminf(fmaxf(ay, -M_CLAMP_), M_CLAMP_);
    unsigned int pk = (unsigned int)f2bf(ax) | ((unsigned int)f2bf(ay) << 16);
    *(unsigned int*)(Mb + ((size_t)r * KADJ + k) * DDIM + lane * 2) = pk;
}

// ------- fused alpha + Y + pairnorm partial reduction (grid-stride, 512 blocks) -------
__global__ __launch_bounds__(256) void fuse_kernel(
    const unsigned short* __restrict__ Mb, const float* __restrict__ scores,
    const float* __restrict__ mask, const float* __restrict__ H,
    float* __restrict__ Y, float* __restrict__ alpha_out, float* __restrict__ red, int N)
{
    int tid = threadIdx.x;
    int sub = tid >> 6;              // node within 4-node tile
    int j = tid & 63;
    int dd = j * 2;                  // this thread's fixed d pair
    float csx = 0.f, csy = 0.f, sq = 0.f;

    for (int t = blockIdx.x; t < N / 4; t += gridDim.x) {
        int n = t * 4 + sub;
        float a[KADJ];
        float mx = -1e30f;
#pragma unroll
        for (int k = 0; k < KADJ; k++) {
            a[k] = scores[(size_t)n * KADJ + k] * (1.0f / TEMP_);
            mx = fmaxf(mx, a[k]);
        }
        float sum = 0.f;
#pragma unroll
        for (int k = 0; k < KADJ; k++) { a[k] = expf(a[k] - mx); sum += a[k]; }
#pragma unroll
        for (int k = 0; k < KADJ; k++) a[k] = (a[k] / sum) * mask[(size_t)n * KADJ + k];
        float s2 = 0.f;
#pragma unroll
        for (int k = 0; k < KADJ; k++) s2 += a[k];
        float inv = 1.f / fmaxf(s2, 1e-12f);
#pragma unroll
        for (int k = 0; k < KADJ; k++) a[k] = fmaxf(a[k] * inv, 1e-8f);
        s2 = 0.f;
#pragma unroll
        for (int k = 0; k < KADJ; k++) s2 += a[k];
        inv = 1.f / fmaxf(s2, 1e-12f);
#pragma unroll
        for (int k = 0; k < KADJ; k++) a[k] *= inv;

        float2 h = *(const float2*)(H + (size_t)n * DDIM + dd);
        float yx = h.x, yy = h.y;
#pragma unroll
        for (int k = 0; k < KADJ; k++) {
            unsigned int u = *(const unsigned int*)(Mb + ((size_t)n * KADJ + k) * DDIM + dd);
            yx += a[k] * bflo(u);
            yy += a[k] * bfhi(u);
        }
        *(float2*)(Y + (size_t)n * DDIM + dd) = make_float2(yx, yy);
        if (j < KADJ) alpha_out[(size_t)n * KADJ + j] = a[j];
        csx += yx; csy += yy;
        sq += yx * yx + yy * yy;
    }

    __shared__ float sx[256], sy[256], sq_[256];
    sx[tid] = csx; sy[tid] = csy; sq_[tid] = sq;
    __syncthreads();
    if (tid < 64) {
        float ax = sx[tid] + sx[tid + 64] + sx[tid + 128] + sx[tid + 192];
        float ay = sy[tid] + sy[tid + 64] + sy[tid + 128] + sy[tid + 192];
        atomicAdd(&red[tid * 2], ax);
        atomicAdd(&red[tid * 2 + 1], ay);
    }
    for (int s = 128; s > 0; s >>= 1) {
        if (tid < s) sq_[tid] += sq_[tid + s];
        __syncthreads();
    }
    if (tid == 0) atomicAdd(&red[128], sq_[0]);
}

// ---------------- pairnorm apply: writes H fp32 + Hb bf16 ----------
__global__ __launch_bounds__(256) void pairnorm_kernel(
    const float* __restrict__ Y, const float* __restrict__ red,
    float* __restrict__ Hout, unsigned short* __restrict__ Hb, int N)
{
    int tid = threadIdx.x;
    int d = tid & 127;
    float invN = 1.0f / (float)N;
    float mu = red[d] * invN;
    __shared__ float smu2[128];
    if (tid < 128) smu2[tid] = mu * mu;
    __syncthreads();
    for (int s = 64; s > 0; s >>= 1) {
        if (tid < s) smu2[tid] += smu2[tid + s];
        __syncthreads();
    }
    float summu2 = smu2[0];
    float var = red[128] * invN - summu2;
    float norm = sqrtf(fmaxf(var, 0.f)) + 1e-6f;
    float inv = 1.0f / norm;
    int n = blockIdx.x * 2 + (tid >> 7);
    if (n < N) {
        float v = (Y[(size_t)n * DDIM + d] - mu) * inv;
        v = fmaxf(v, 0.f);
        Hout[(size_t)n * DDIM + d] = v;
        Hb[(size_t)n * DDIM + d] = f2bf(v);
    }
}

extern "C" void kernel_launch(void* const* d_in, const int* in_sizes, int n_in,
                              void* d_out, int out_size, void* d_ws, size_t ws_size,
                              hipStream_t stream)
{
    const float* X      = (const float*)d_in[0];
    const int*   rows   = (const int*)d_in[1];
    const int*   cols   = (const int*)d_in[2];
    const float* mask   = (const float*)d_in[3];
    const float* logdeg = (const float*)d_in[4];
    const float* W_in0  = (const float*)d_in[5];
    const float* b_in0  = (const float*)d_in[6];
    const float* W_in1  = (const float*)d_in[7];
    const float* b_in1  = (const float*)d_in[8];
    const float* W_in2  = (const float*)d_in[9];
    const float* b_in2  = (const float*)d_in[10];
    const float* Wmsg[2] = {(const float*)d_in[11], (const float*)d_in[16]};
    const float* Wg1[2]  = {(const float*)d_in[12], (const float*)d_in[17]};
    const float* bg1[2]  = {(const float*)d_in[13], (const float*)d_in[18]};
    const float* Wg2[2]  = {(const float*)d_in[14], (const float*)d_in[19]};
    const float* bg2[2]  = {(const float*)d_in[15], (const float*)d_in[20]};
    const float* Wh1 = (const float*)d_in[21];
    const float* bh1 = (const float*)d_in[22];
    const float* Wh2 = (const float*)d_in[23];
    const float* bh2 = (const float*)d_in[24];

    // workspace layout (float slots), ~85 MB
    float* ws = (float*)d_ws;
    unsigned short* Xb  = (unsigned short*)ws;
    unsigned short* Mb  = (unsigned short*)ws;
    float* Ybuf  = ws + 5120000;
    float* GH    = ws + 7680000;
    uint2* staging = (uint2*)(ws + 10240000);       // NCOARSE*ESTRIDE*2 = 3,145,728 slots
    unsigned short* H0b = (unsigned short*)(ws + 10240000);
    unsigned short* H1b = (unsigned short*)(ws + 12800000);
    unsigned short* Zb  = (unsigned short*)(ws + 12800000);
    float* H     = ws + 15360000;                   // 2.56M
    unsigned short* Hb = (unsigned short*)(ws + 17920000);  // 1.28M slots
    float* scores = ws + 19200000;                  // 80000
    int*   offs   = (int*)(ws + 19280000);          // 80000
    int*   ends   = (int*)(ws + 19360000);          // 80000
    int*   edst   = (int*)(ws + 19440000);          // NCOARSE*ESTRIDE = 1,572,864
    float* red    = ws + 21012864;                  // 256
    int*   bcnt   = (int*)(ws + 21013120);          // 128
    unsigned short* w0t  = (unsigned short*)(ws + 21013248);  // 131072 slots
    unsigned short* w1t  = (unsigned short*)(ws + 21144320);  // 32768
    unsigned short* w2t  = (unsigned short*)(ws + 21177088);  // 16384
    unsigned short* wzg[2]  = {(unsigned short*)(ws + 21193472), (unsigned short*)(ws + 21209856)};  // 256x128 each
    unsigned short* wgmt[2] = {(unsigned short*)(ws + 21226240), (unsigned short*)(ws + 21234432)};
    unsigned short* wh1t = (unsigned short*)(ws + 21242624);
    float* logits = (float*)d_out;
    float* alpha_out = (float*)d_out + N_NODES;

    dim3 blk(256);
    int gM = (N_NODES + 127) / 128;     // 157

    // ---- CSR build ----
    (void)hipMemsetAsync(bcnt, 0, NCOARSE * sizeof(int), stream);
    binA2_kernel<<<BINA_NB, blk, 0, stream>>>(rows, cols, bcnt, staging);
    binB2_kernel<<<NCOARSE, blk, 0, stream>>>(staging, bcnt, offs, ends, edst);

    // ---- weight transposes + X cast ----
    TD10 descs;
    descs.d[0] = {W_in0, w0t, IN_DIM_, H_IN_};
    descs.d[1] = {W_in1, w1t, H_IN_, H_IN_};
    descs.d[2] = {W_in2, w2t, H_IN_, DDIM};
    descs.d[3] = {Wmsg[0], wzg[0], DDIM, DDIM};                           // rows 0-127 of wzg0
    descs.d[4] = {Wg1[0], wzg[0] + DDIM * DDIM, DDIM, GATE_H_};           // rows 128-255 of wzg0
    descs.d[5] = {Wmsg[1], wzg[1], DDIM, DDIM};
    descs.d[6] = {Wg1[1], wzg[1] + DDIM * DDIM, DDIM, GATE_H_};
    descs.d[7] = {Wg1[0] + DDIM * GATE_H_, wgmt[0], DDIM, GATE_H_};
    descs.d[8] = {Wg1[1] + DDIM * GATE_H_, wgmt[1], DDIM, GATE_H_};
    descs.d[9] = {Wh1, wh1t, DDIM, DDIM};
    transpose_all_kernel<<<dim3(8, 32, 10), blk, 0, stream>>>(descs);
    cast_bf16_kernel<<<N_NODES * IN_DIM_ / 8 / 256, blk, 0, stream>>>(X, Xb, N_NODES * IN_DIM_);

    // ---- encoder ----
    gemm_async_kernel<<<dim3(2, gM), blk, 0, stream>>>(Xb, w0t, b_in0, nullptr, H0b, N_NODES, H_IN_, IN_DIM_, 1);
    gemm_async_kernel<<<dim3(2, gM), blk, 0, stream>>>(H0b, w1t, b_in1, nullptr, H1b, N_NODES, H_IN_, H_IN_, 1);
    gemm_async_kernel<<<dim3(1, gM), blk, 0, stream>>>(H1b, w2t, b_in2, H, Hb, N_NODES, DDIM, H_IN_, 1);

    for (int b = 0; b < 2; b++) {
        // fused Z + GH GEMM
        zg_gemm_kernel<<<dim3(2, gM), blk, 0, stream>>>(Hb, wzg[b], bg1[b], Zb, GH, N_NODES);
        gather_kernel<<<CSR_TOTAL / 4, blk, 0, stream>>>(offs, ends, edst, Zb, Mb);
        gate_gemm_kernel<<<CSR_TOTAL / 128, blk, 0, stream>>>(Mb, wgmt[b], GH, logdeg,
                                                              Wg1[b] + 256 * GATE_H_, Wg2[b], bg2[b], scores);
        float* alph = alpha_out + (size_t)b * N_NODES * KADJ;
        (void)hipMemsetAsync(red, 0, 129 * sizeof(float), stream);
        fuse_kernel<<<512, blk, 0, stream>>>(Mb, scores, mask, H, Ybuf, alph, red, N_NODES);
        pairnorm_kernel<<<(N_NODES + 1) / 2, blk, 0, stream>>>(Ybuf, red, H, Hb, N_NODES);
    }

    // head (+ fused logits)
    head_gemm_kernel<<<gM, blk, 0, stream>>>(Hb, wh1t, bh1, Wh2, bh2, logits, N_NODES);
}